// Round 2
// baseline (3478.899 us; speedup 1.0000x reference)
//
#include <hip/hip_runtime.h>
#include <hip/hip_bf16.h>
#include <cstdint>
#include <cstddef>

// Problem constants
static constexpr int B   = 1024;
static constexpr int N   = 64;
static constexpr int BN  = B * N;      // 65536 nodes
static constexpr int EPG = 192;
static constexpr int E   = B * EPG;    // 196608 edges

typedef __hip_bfloat16 bf16;

__device__ __forceinline__ float toF(float v) { return v; }
__device__ __forceinline__ float toF(bf16 v) { return __bfloat162float(v); }
__device__ __forceinline__ void storeC(float* p, float v) { *p = v; }
__device__ __forceinline__ void storeC(bf16* p, float v) { *p = __float2bfloat16(v); }

// ---------------------------------------------------------------------------
// Generic tiled GEMM: C[M,N] = A[M,K] @ Bm[K,N] (+bias) (relu) (FiLM)
// A: fp32 or bf16 (row-major, lda). Bm: fp32 or bf16 row-major K x N (ldb).
// FiLM: v = v*(1+S[row*films+col]) + T[row*films+col], applied AFTER relu.
// ---------------------------------------------------------------------------
template<typename AT, typename BT, typename CT, bool RELU, bool FILM>
__global__ __launch_bounds__(256) void gemm_kernel(
    const AT* __restrict__ A, int lda,
    const BT* __restrict__ Bm, int ldb,
    const float* __restrict__ bias,            // may be null
    CT* __restrict__ C, int ldc,
    const float* __restrict__ filmS, const float* __restrict__ filmT, int films,
    int M, int N_, int K)
{
    __shared__ float As[16][65];   // padded
    __shared__ float Bs[16][64];

    const int m0 = blockIdx.x * 64;
    const int n0 = blockIdx.y * 64;
    const int tid = threadIdx.x;
    const int tx = tid & 15, ty = tid >> 4;

    float acc[4][4] = {};

    for (int k0 = 0; k0 < K; k0 += 16) {
        // load A tile (64 rows x 16 k), store transposed As[k][m]
        #pragma unroll
        for (int s = 0; s < 4; ++s) {
            int e = tid + 256 * s;
            int m = e >> 4, k = e & 15;
            int kk = k0 + k;
            float v = 0.f;
            if (kk < K) v = toF(A[(size_t)(m0 + m) * lda + kk]);
            As[k][m] = v;
        }
        // load B tile (16 k x 64 n)
        #pragma unroll
        for (int s = 0; s < 4; ++s) {
            int e = tid + 256 * s;
            int k = e >> 6, n = e & 63;
            int kk = k0 + k, nn = n0 + n;
            float v = 0.f;
            if (kk < K && nn < N_) v = toF(Bm[(size_t)kk * ldb + nn]);
            Bs[k][n] = v;
        }
        __syncthreads();
        #pragma unroll
        for (int k = 0; k < 16; ++k) {
            float a[4], b[4];
            #pragma unroll
            for (int i = 0; i < 4; ++i) a[i] = As[k][ty + 16 * i];
            #pragma unroll
            for (int j = 0; j < 4; ++j) b[j] = Bs[k][tx + 16 * j];
            #pragma unroll
            for (int i = 0; i < 4; ++i)
                #pragma unroll
                for (int j = 0; j < 4; ++j)
                    acc[i][j] += a[i] * b[j];
        }
        __syncthreads();
    }

    #pragma unroll
    for (int i = 0; i < 4; ++i) {
        int row = m0 + ty + 16 * i;   // M is always a multiple of 64 here
        #pragma unroll
        for (int j = 0; j < 4; ++j) {
            int col = n0 + tx + 16 * j;
            if (col < N_) {
                float v = acc[i][j];
                if (bias) v += bias[col];
                if (RELU) v = fmaxf(v, 0.f);
                if (FILM) {
                    float sv = filmS[(size_t)row * films + col];
                    float tv = filmT[(size_t)row * films + col];
                    v = v * (1.f + sv) + tv;
                }
                storeC(&C[(size_t)row * ldc + col], v);
            }
        }
    }
}

template<typename AT, typename BT, typename CT, bool RELU, bool FILM>
static void run_gemm(const AT* A, int lda, const BT* Bm, int ldb, const float* bias,
                     CT* C, int ldc, const float* fS, const float* fT, int films,
                     int M, int N_, int K, hipStream_t stream)
{
    dim3 grid((M + 63) / 64, (N_ + 63) / 64);
    gemm_kernel<AT, BT, CT, RELU, FILM><<<grid, 256, 0, stream>>>(
        A, lda, Bm, ldb, bias, C, ldc, fS, fT, films, M, N_, K);
}

// ---------------------------------------------------------------------------
// Timestep embedding: TE[1024][128], TE[b][j] = cos/sin(t_b * freq[j%64])
// ---------------------------------------------------------------------------
__global__ void k_te(const float* __restrict__ ts, float* __restrict__ TE)
{
    int idx = blockIdx.x * 256 + threadIdx.x;
    if (idx >= B * 128) return;
    int b = idx >> 7, j = idx & 127;
    float t = ts[b];
    int h = j & 63;
    float freq = expf(-9.210340371976184f * (float)h / 64.f);  // ln(10000)
    float a = t * freq;
    TE[idx] = (j < 64) ? cosf(a) : sinf(a);
}

// ---------------------------------------------------------------------------
// Degree: deg[i] = (#edges with dst==i) + 1 ; store 1/deg and rsqrt(deg)
// ---------------------------------------------------------------------------
__global__ __launch_bounds__(256) void k_deg(const int* __restrict__ ei,
                                             float* __restrict__ invdeg,
                                             float* __restrict__ isq)
{
    int g = blockIdx.x;
    int tid = threadIdx.x;
    __shared__ int cnt[64];
    if (tid < 64) cnt[tid] = 0;
    __syncthreads();
    for (int e = tid; e < EPG; e += 256)
        atomicAdd(&cnt[ei[E + g * EPG + e] & 63], 1);
    __syncthreads();
    if (tid < 64) {
        float d = (float)cnt[tid] + 1.0f;
        invdeg[g * 64 + tid] = 1.f / d;
        isq[g * 64 + tid] = rsqrtf(d);
    }
}

// ---------------------------------------------------------------------------
// Node transform: X[node][0:300] = (x_in[node] @ W_tr + b_tr) * mask[node]
// X has row stride 600 (bf16)
// ---------------------------------------------------------------------------
__global__ __launch_bounds__(256) void k_xtr(const float* __restrict__ xin,
                                             const float* __restrict__ Wtr,
                                             const float* __restrict__ btr,
                                             const float* __restrict__ mask,
                                             bf16* __restrict__ X)
{
    int node = blockIdx.x;
    int tid = threadIdx.x;
    __shared__ float xr[19];
    if (tid < 19) xr[tid] = xin[node * 19 + tid];
    __syncthreads();
    float m = mask[node];
    for (int c = tid; c < 300; c += 256) {
        float acc = btr[c];
        #pragma unroll
        for (int k = 0; k < 19; ++k)
            acc += xr[k] * Wtr[k * 300 + c];
        X[(size_t)node * 600 + c] = __float2bfloat16(acc * m);
    }
}

// ---------------------------------------------------------------------------
// GCN aggregation (per graph, per 150-col chunk):
// out[i][f] = sum_{e: dst==i} h[src_e][f]*isq[src]*isq[i] + h[i][f]/deg[i] + b[f]
// Optional relu. Reads H (bf16, stride 600), writes Xout (bf16, stride 600).
// ---------------------------------------------------------------------------
template<bool RELU>
__global__ __launch_bounds__(256) void k_agg(const bf16* __restrict__ H,
                                             const int* __restrict__ ei,
                                             const float* __restrict__ invdeg,
                                             const float* __restrict__ isq,
                                             const float* __restrict__ bias,
                                             bf16* __restrict__ Xout)
{
    constexpr int CH = 150;
    int g = blockIdx.x;
    int c0 = blockIdx.y * CH;
    int tid = threadIdx.x;

    __shared__ float hs[64][CH];       // 38.4 KB
    __shared__ float lcoef[EPG];
    __shared__ int   lsrc[EPG];
    __shared__ int   cnt[64], off[65], cur[64];
    __shared__ float isq_g[64], ivd_g[64];

    if (tid < 64) {
        cnt[tid] = 0;
        isq_g[tid] = isq[g * 64 + tid];
        ivd_g[tid] = invdeg[g * 64 + tid];
    }
    __syncthreads();
    for (int e = tid; e < EPG; e += 256)
        atomicAdd(&cnt[ei[E + g * EPG + e] & 63], 1);
    __syncthreads();
    if (tid == 0) {
        int s = 0;
        for (int i = 0; i < 64; ++i) { off[i] = s; s += cnt[i]; }
        off[64] = s;
    }
    __syncthreads();
    if (tid < 64) cur[tid] = off[tid];
    __syncthreads();
    for (int e = tid; e < EPG; e += 256) {
        int ls = ei[g * EPG + e] & 63;
        int ld = ei[E + g * EPG + e] & 63;
        int p = atomicAdd(&cur[ld], 1);
        lsrc[p] = ls;
        lcoef[p] = isq_g[ls] * isq_g[ld];
    }
    // stage H chunk
    for (int idx = tid; idx < 64 * CH; idx += 256) {
        int i = idx / CH, f = idx - i * CH;
        hs[i][f] = __bfloat162float(H[(size_t)(g * 64 + i) * 600 + c0 + f]);
    }
    __syncthreads();
    for (int idx = tid; idx < 64 * CH; idx += 256) {
        int i = idx / CH, f = idx - i * CH;
        float acc = hs[i][f] * ivd_g[i];
        int e1 = off[i + 1];
        for (int j = off[i]; j < e1; ++j)
            acc += hs[lsrc[j]][f] * lcoef[j];
        acc += bias[c0 + f];
        if (RELU) acc = fmaxf(acc, 0.f);
        Xout[(size_t)(g * 64 + i) * 600 + c0 + f] = __float2bfloat16(acc);
    }
}

// ---------------------------------------------------------------------------
// Global mean pool: G0[g][c] = mean over 64 nodes of X (bf16, stride 600)
// ---------------------------------------------------------------------------
__global__ __launch_bounds__(256) void k_pool(const bf16* __restrict__ X,
                                              float* __restrict__ G0)
{
    int g = blockIdx.x;
    int tid = threadIdx.x;
    for (int c = tid; c < 600; c += 256) {
        float s = 0.f;
        #pragma unroll 4
        for (int i = 0; i < 64; ++i)
            s += __bfloat162float(X[(size_t)(g * 64 + i) * 600 + c]);
        G0[g * 600 + c] = s * (1.f / 64.f);
    }
}

// ---------------------------------------------------------------------------
// LayerNorm over 300 dims + affine, write fp32 to d_out
// ---------------------------------------------------------------------------
__global__ __launch_bounds__(256) void k_ln(const float* __restrict__ G,
                                            const float* __restrict__ lg,
                                            const float* __restrict__ lb,
                                            float* __restrict__ out)
{
    int r = blockIdx.x;
    int tid = threadIdx.x;
    __shared__ float red[4];
    __shared__ float smu, svar;

    float v0 = (tid < 300) ? G[r * 300 + tid] : 0.f;
    float v1 = (tid + 256 < 300) ? G[r * 300 + tid + 256] : 0.f;
    float s = v0 + v1;
    #pragma unroll
    for (int o = 32; o > 0; o >>= 1) s += __shfl_down(s, o, 64);
    if ((tid & 63) == 0) red[tid >> 6] = s;
    __syncthreads();
    if (tid == 0) smu = (red[0] + red[1] + red[2] + red[3]) * (1.f / 300.f);
    __syncthreads();
    float mu = smu;
    float d0 = (tid < 300) ? v0 - mu : 0.f;
    float d1 = (tid + 256 < 300) ? v1 - mu : 0.f;
    s = d0 * d0 + d1 * d1;
    #pragma unroll
    for (int o = 32; o > 0; o >>= 1) s += __shfl_down(s, o, 64);
    if ((tid & 63) == 0) red[tid >> 6] = s;
    __syncthreads();
    if (tid == 0) svar = (red[0] + red[1] + red[2] + red[3]) * (1.f / 300.f);
    __syncthreads();
    float rstd = rsqrtf(svar + 1e-5f);
    if (tid < 300)
        out[r * 300 + tid] = d0 * rstd * lg[tid] + lb[tid];
    if (tid + 256 < 300)
        out[r * 300 + tid + 256] = d1 * rstd * lg[tid + 256] + lb[tid + 256];
}

// text_features passthrough copy (fp32 -> fp32, 16B vectors)
__global__ void k_copy(const uint4* __restrict__ src, uint4* __restrict__ dst, int n)
{
    int i = blockIdx.x * 256 + threadIdx.x;
    if (i < n) dst[i] = src[i];
}

// ---------------------------------------------------------------------------
extern "C" void kernel_launch(void* const* d_in, const int* in_sizes, int n_in,
                              void* d_out, int out_size, void* d_ws, size_t ws_size,
                              hipStream_t stream)
{
    const float* x_in  = (const float*)d_in[0];
    const int*   ei    = (const int*)d_in[1];
    // d_in[2] = mol_batch_batch (layout is implicit: node i -> graph i/64)
    const float* text  = (const float*)d_in[3];
    const float* tst   = (const float*)d_in[4];
    const float* mask  = (const float*)d_in[5];
    const float* W_tr  = (const float*)d_in[6];
    const float* b_tr  = (const float*)d_in[7];
    const float* W_c1  = (const float*)d_in[8];
    const float* b_c1  = (const float*)d_in[9];
    const float* W_c2  = (const float*)d_in[10];
    const float* b_c2  = (const float*)d_in[11];
    const float* W_c3  = (const float*)d_in[12];
    const float* b_c3  = (const float*)d_in[13];
    const float* W_h1  = (const float*)d_in[14];
    const float* b_h1  = (const float*)d_in[15];
    const float* W_h2  = (const float*)d_in[16];
    const float* b_h2  = (const float*)d_in[17];
    const float* W_h3  = (const float*)d_in[18];
    const float* b_h3  = (const float*)d_in[19];
    const float* ln_g  = (const float*)d_in[20];
    const float* ln_b  = (const float*)d_in[21];
    const float* W_t1  = (const float*)d_in[22];
    const float* b_t1  = (const float*)d_in[23];
    const float* W_t2  = (const float*)d_in[24];
    const float* b_t2  = (const float*)d_in[25];
    const float* W_e   = (const float*)d_in[26];
    const float* b_e   = (const float*)d_in[27];

    // workspace carve (256B aligned); keep total under ~184 MB (round-0 proven)
    char* w = (char*)d_ws;
    size_t off = 0;
    auto carve = [&](size_t bytes) {
        void* p = w + off;
        off += (bytes + 255) & ~(size_t)255;
        return p;
    };
    bf16*  XA     = (bf16*) carve((size_t)BN * 600 * 2);   // 78.6 MB
    bf16*  Hb     = (bf16*) carve((size_t)BN * 600 * 2);   // 78.6 MB
    float* TE     = (float*)carve((size_t)B * 128 * 4);
    float* A1     = (float*)carve((size_t)B * 512 * 4);
    float* A2r    = (float*)carve((size_t)B * 512 * 4);
    float* EO     = (float*)carve((size_t)B * 3000 * 4);   // 12.3 MB
    float* G0     = (float*)carve((size_t)B * 600 * 4);
    float* G1     = (float*)carve((size_t)B * 600 * 4);
    float* G2     = (float*)carve((size_t)B * 600 * 4);
    float* G3     = (float*)carve((size_t)B * 300 * 4);
    float* invdeg = (float*)carve((size_t)BN * 4);
    float* isq    = (float*)carve((size_t)BN * 4);
    (void)ws_size; (void)in_sizes; (void)n_in; (void)out_size;

    float* out = (float*)d_out;

    // --- timestep embedding MLP ---
    k_te<<<(B * 128 + 255) / 256, 256, 0, stream>>>(tst, TE);
    // A1 = relu(TE @ W_t1 + b_t1)     [1024 x 512]
    run_gemm<float, float, float, true, false>(TE, 128, W_t1, 512, b_t1, A1, 512,
                                               nullptr, nullptr, 0, B, 512, 128, stream);
    // A2r = relu(A1 @ W_t2 + b_t2)    [1024 x 512] (emb only used through relu)
    run_gemm<float, float, float, true, false>(A1, 512, W_t2, 512, b_t2, A2r, 512,
                                               nullptr, nullptr, 0, B, 512, 512, stream);
    // EO = A2r @ W_e + b_e            [1024 x 3000]
    run_gemm<float, float, float, false, false>(A2r, 512, W_e, 3000, b_e, EO, 3000,
                                                nullptr, nullptr, 0, B, 3000, 512, stream);

    // --- graph path ---
    k_deg<<<B, 256, 0, stream>>>(ei, invdeg, isq);
    k_xtr<<<BN, 256, 0, stream>>>(x_in, W_tr, b_tr, mask, XA);

    // conv1: H = XA(:, :300) @ W_c1 ; XA = relu(agg(H) + b_c1)
    run_gemm<bf16, float, bf16, false, false>(XA, 600, W_c1, 600, nullptr, Hb, 600,
                                              nullptr, nullptr, 0, BN, 600, 300, stream);
    k_agg<true><<<dim3(B, 4), 256, 0, stream>>>(Hb, ei, invdeg, isq, b_c1, XA);
    // conv2
    run_gemm<bf16, float, bf16, false, false>(XA, 600, W_c2, 600, nullptr, Hb, 600,
                                              nullptr, nullptr, 0, BN, 600, 600, stream);
    k_agg<true><<<dim3(B, 4), 256, 0, stream>>>(Hb, ei, invdeg, isq, b_c2, XA);
    // conv3 (no relu)
    run_gemm<bf16, float, bf16, false, false>(XA, 600, W_c3, 600, nullptr, Hb, 600,
                                              nullptr, nullptr, 0, BN, 600, 600, stream);
    k_agg<false><<<dim3(B, 4), 256, 0, stream>>>(Hb, ei, invdeg, isq, b_c3, XA);

    // pool
    k_pool<<<B, 256, 0, stream>>>(XA, G0);

    // h-layers with FiLM from EO slices (s1@0,t1@600 | s2@1200,t2@1800 | s3@2400,t3@2700)
    run_gemm<float, float, float, true, true>(G0, 600, W_h1, 600, b_h1, G1, 600,
                                              EO + 0, EO + 600, 3000, B, 600, 600, stream);
    run_gemm<float, float, float, true, true>(G1, 600, W_h2, 600, b_h2, G2, 600,
                                              EO + 1200, EO + 1800, 3000, B, 600, 600, stream);
    run_gemm<float, float, float, false, true>(G2, 600, W_h3, 300, b_h3, G3, 300,
                                               EO + 2400, EO + 2700, 3000, B, 300, 600, stream);

    // layer norm -> out[0 : 307200]
    k_ln<<<B, 256, 0, stream>>>(G3, ln_g, ln_b, out);

    // text passthrough -> out[307200 : 614400]
    k_copy<<<(B * 300 * 4 / 16 + 255) / 256, 256, 0, stream>>>(
        (const uint4*)text, (uint4*)(out + (size_t)B * 300), B * 300 * 4 / 16);
}

// Round 3
// 1398.354 us; speedup vs baseline: 2.4879x; 2.4879x over previous
//
#include <hip/hip_runtime.h>
#include <hip/hip_bf16.h>
#include <cstdint>
#include <cstddef>

// Problem constants
static constexpr int B   = 1024;
static constexpr int N   = 64;
static constexpr int BN  = B * N;      // 65536 nodes
static constexpr int EPG = 192;
static constexpr int E   = B * EPG;    // 196608 edges
static constexpr int FP  = 608;        // padded feature dim (19*32)

typedef __hip_bfloat16 bf16;
typedef __bf16 bf16x8 __attribute__((ext_vector_type(8)));
typedef float  f32x4  __attribute__((ext_vector_type(4)));

__device__ __forceinline__ float toF(float v) { return v; }
__device__ __forceinline__ float toF(bf16 v) { return __bfloat162float(v); }
__device__ __forceinline__ void storeC(float* p, float v) { *p = v; }
__device__ __forceinline__ void storeC(bf16* p, float v) { *p = __float2bfloat16(v); }

// async global->LDS, 16B per lane; lptr must be wave-uniform (dest = base + lane*16)
__device__ __forceinline__ void llds16(const void* g, void* l) {
    __builtin_amdgcn_global_load_lds(
        (const __attribute__((address_space(1))) unsigned int*)g,
        (__attribute__((address_space(3))) unsigned int*)l,
        16, 0, 0);
}

// ---------------------------------------------------------------------------
// MFMA bf16 GEMM: C[M x Ncap] = A[M x K] @ Bt^T, Bt is N x K (pre-transposed W).
// M mult of 128, grid.y covers ceil(N/128) tiles, K mult of 32.
// 128x128 block tile, 4 waves each 64x64 (4x4 frags of 16x16x32). m97 structure.
// ---------------------------------------------------------------------------
__global__ __launch_bounds__(256) void gemm_mfma(
    const bf16* __restrict__ A, int lda,
    const bf16* __restrict__ Bt, int ldb,
    bf16* __restrict__ C, int ldc, int Ncap,
    int K)
{
    __shared__ __align__(16) __bf16 As[128 * 32];
    __shared__ __align__(16) __bf16 Bs[128 * 32];

    const int tid  = threadIdx.x;
    const int lane = tid & 63;
    const int w    = tid >> 6;            // wave 0..3
    const int wm   = (w & 1) * 64;
    const int wn   = (w >> 1) * 64;
    const int m0   = blockIdx.x * 128;
    const int n0   = blockIdx.y * 128;
    const int l15  = lane & 15;
    const int lhi  = lane >> 4;

    f32x4 acc[4][4] = {};

    for (int k0 = 0; k0 < K; k0 += 32) {
        // stage A-tile (128 rows x 32 k) and B-tile (128 n-rows x 32 k), 16B chunks
        #pragma unroll
        for (int t = 0; t < 2; ++t) {
            int ci  = t * 256 + w * 64 + lane;   // chunk 0..511
            int row = ci >> 2, kc = ci & 3;
            char* la = (char*)As + (size_t)(t * 256 + w * 64) * 16;  // wave-uniform
            char* lb = (char*)Bs + (size_t)(t * 256 + w * 64) * 16;
            llds16(A  + (size_t)(m0 + row) * lda + k0 + kc * 8, la);
            llds16(Bt + (size_t)(n0 + row) * ldb + k0 + kc * 8, lb);
        }
        asm volatile("s_waitcnt vmcnt(0)" ::: "memory");
        __syncthreads();

        bf16x8 af[4], bg[4];
        #pragma unroll
        for (int i = 0; i < 4; ++i)
            af[i] = *(bf16x8*)(As + (wm + i * 16 + l15) * 32 + lhi * 8);
        #pragma unroll
        for (int j = 0; j < 4; ++j)
            bg[j] = *(bf16x8*)(Bs + (wn + j * 16 + l15) * 32 + lhi * 8);
        #pragma unroll
        for (int i = 0; i < 4; ++i)
            #pragma unroll
            for (int j = 0; j < 4; ++j)
                acc[i][j] = __builtin_amdgcn_mfma_f32_16x16x32_bf16(
                    af[i], bg[j], acc[i][j], 0, 0, 0);
        __syncthreads();
    }

    // epilogue: D[row=(lane>>4)*4+e][col=lane&15] per frag (m89-verified layout)
    #pragma unroll
    for (int i = 0; i < 4; ++i) {
        #pragma unroll
        for (int j = 0; j < 4; ++j) {
            int col = n0 + wn + j * 16 + l15;
            if (col < Ncap) {
                #pragma unroll
                for (int e = 0; e < 4; ++e) {
                    int row = m0 + wm + i * 16 + lhi * 4 + e;
                    C[(size_t)row * ldc + col] = __float2bfloat16(acc[i][j][e]);
                }
            }
        }
    }
}

// ---------------------------------------------------------------------------
// Weight convert+transpose+pad: Wt[n][k] = W[k][n] (fp32->bf16), zero pads.
// Wt is Np x Kp (row stride Kp).
// ---------------------------------------------------------------------------
__global__ __launch_bounds__(256) void k_wt(const float* __restrict__ W,
                                            bf16* __restrict__ Wt,
                                            int Ksrc, int Nsrc, int Kp, int Np)
{
    int idx = blockIdx.x * 256 + threadIdx.x;
    if (idx >= Np * Kp) return;
    int n = idx / Kp, k = idx - n * Kp;
    float v = (n < Nsrc && k < Ksrc) ? W[(size_t)k * Nsrc + n] : 0.f;
    Wt[idx] = __float2bfloat16(v);
}

// ---------------------------------------------------------------------------
// Generic fp32 tiled GEMM (emb path + h-layers). FiLM from bf16 buffer.
// ---------------------------------------------------------------------------
template<typename CT, bool RELU, bool FILM>
__global__ __launch_bounds__(256) void gemm_kernel(
    const float* __restrict__ A, int lda,
    const float* __restrict__ Bm, int ldb,
    const float* __restrict__ bias,
    CT* __restrict__ C, int ldc,
    const bf16* __restrict__ filmS, const bf16* __restrict__ filmT, int films,
    int M, int N_, int K)
{
    __shared__ float As[16][65];
    __shared__ float Bs[16][64];

    const int m0 = blockIdx.x * 64;
    const int n0 = blockIdx.y * 64;
    const int tid = threadIdx.x;
    const int tx = tid & 15, ty = tid >> 4;

    float acc[4][4] = {};

    for (int k0 = 0; k0 < K; k0 += 16) {
        #pragma unroll
        for (int s = 0; s < 4; ++s) {
            int e = tid + 256 * s;
            int m = e >> 4, k = e & 15;
            int kk = k0 + k;
            As[k][m] = (kk < K) ? A[(size_t)(m0 + m) * lda + kk] : 0.f;
        }
        #pragma unroll
        for (int s = 0; s < 4; ++s) {
            int e = tid + 256 * s;
            int k = e >> 6, n = e & 63;
            int kk = k0 + k, nn = n0 + n;
            Bs[k][n] = (kk < K && nn < N_) ? Bm[(size_t)kk * ldb + nn] : 0.f;
        }
        __syncthreads();
        #pragma unroll
        for (int k = 0; k < 16; ++k) {
            float a[4], b[4];
            #pragma unroll
            for (int i = 0; i < 4; ++i) a[i] = As[k][ty + 16 * i];
            #pragma unroll
            for (int j = 0; j < 4; ++j) b[j] = Bs[k][tx + 16 * j];
            #pragma unroll
            for (int i = 0; i < 4; ++i)
                #pragma unroll
                for (int j = 0; j < 4; ++j)
                    acc[i][j] += a[i] * b[j];
        }
        __syncthreads();
    }

    #pragma unroll
    for (int i = 0; i < 4; ++i) {
        int row = m0 + ty + 16 * i;
        #pragma unroll
        for (int j = 0; j < 4; ++j) {
            int col = n0 + tx + 16 * j;
            if (col < N_) {
                float v = acc[i][j];
                if (bias) v += bias[col];
                if (RELU) v = fmaxf(v, 0.f);
                if (FILM) {
                    float sv = __bfloat162float(filmS[(size_t)row * films + col]);
                    float tv = __bfloat162float(filmT[(size_t)row * films + col]);
                    v = v * (1.f + sv) + tv;
                }
                storeC(&C[(size_t)row * ldc + col], v);
            }
        }
    }
}

template<typename CT, bool RELU, bool FILM>
static void run_gemm(const float* A, int lda, const float* Bm, int ldb, const float* bias,
                     CT* C, int ldc, const bf16* fS, const bf16* fT, int films,
                     int M, int N_, int K, hipStream_t stream)
{
    dim3 grid((M + 63) / 64, (N_ + 63) / 64);
    gemm_kernel<CT, RELU, FILM><<<grid, 256, 0, stream>>>(
        A, lda, Bm, ldb, bias, C, ldc, fS, fT, films, M, N_, K);
}

// ---------------------------------------------------------------------------
__global__ void k_te(const float* __restrict__ ts, float* __restrict__ TE)
{
    int idx = blockIdx.x * 256 + threadIdx.x;
    if (idx >= B * 128) return;
    int b = idx >> 7, j = idx & 127;
    float t = ts[b];
    int h = j & 63;
    float freq = expf(-9.210340371976184f * (float)h / 64.f);  // ln(10000)
    float a = t * freq;
    TE[idx] = (j < 64) ? cosf(a) : sinf(a);
}

__global__ __launch_bounds__(256) void k_deg(const int* __restrict__ ei,
                                             float* __restrict__ invdeg,
                                             float* __restrict__ isq)
{
    int g = blockIdx.x;
    int tid = threadIdx.x;
    __shared__ int cnt[64];
    if (tid < 64) cnt[tid] = 0;
    __syncthreads();
    for (int e = tid; e < EPG; e += 256)
        atomicAdd(&cnt[ei[E + g * EPG + e] & 63], 1);
    __syncthreads();
    if (tid < 64) {
        float d = (float)cnt[tid] + 1.0f;
        invdeg[g * 64 + tid] = 1.f / d;
        isq[g * 64 + tid] = rsqrtf(d);
    }
}

// Node transform: X[node][0:300] = (x_in @ W_tr + b_tr)*mask ; cols 300..FP-1 = 0
__global__ __launch_bounds__(256) void k_xtr(const float* __restrict__ xin,
                                             const float* __restrict__ Wtr,
                                             const float* __restrict__ btr,
                                             const float* __restrict__ mask,
                                             bf16* __restrict__ X)
{
    int node = blockIdx.x;
    int tid = threadIdx.x;
    __shared__ float xr[19];
    if (tid < 19) xr[tid] = xin[node * 19 + tid];
    __syncthreads();
    float m = mask[node];
    for (int c = tid; c < FP; c += 256) {
        float v = 0.f;
        if (c < 300) {
            float acc = btr[c];
            #pragma unroll
            for (int k = 0; k < 19; ++k)
                acc += xr[k] * Wtr[k * 300 + c];
            v = acc * m;
        }
        X[(size_t)node * FP + c] = __float2bfloat16(v);
    }
}

// ---------------------------------------------------------------------------
// GCN aggregation (per graph, per 152-col chunk), strides FP:
// out[i][f] = sum_{e: dst==i} h[src][f]*isq[src]*isq[i] + h[i][f]/deg[i] + b[f]
// ---------------------------------------------------------------------------
template<bool RELU>
__global__ __launch_bounds__(256) void k_agg(const bf16* __restrict__ H,
                                             const int* __restrict__ ei,
                                             const float* __restrict__ invdeg,
                                             const float* __restrict__ isq,
                                             const float* __restrict__ bias,
                                             bf16* __restrict__ Xout)
{
    constexpr int CH = 152;   // 4 chunks * 152 = 608 = FP
    int g = blockIdx.x;
    int c0 = blockIdx.y * CH;
    int tid = threadIdx.x;

    __shared__ float hs[64][CH];
    __shared__ float lcoef[EPG];
    __shared__ int   lsrc[EPG];
    __shared__ int   cnt[64], off[65], cur[64];
    __shared__ float isq_g[64], ivd_g[64];

    if (tid < 64) {
        cnt[tid] = 0;
        isq_g[tid] = isq[g * 64 + tid];
        ivd_g[tid] = invdeg[g * 64 + tid];
    }
    __syncthreads();
    for (int e = tid; e < EPG; e += 256)
        atomicAdd(&cnt[ei[E + g * EPG + e] & 63], 1);
    __syncthreads();
    if (tid == 0) {
        int s = 0;
        for (int i = 0; i < 64; ++i) { off[i] = s; s += cnt[i]; }
        off[64] = s;
    }
    __syncthreads();
    if (tid < 64) cur[tid] = off[tid];
    __syncthreads();
    for (int e = tid; e < EPG; e += 256) {
        int ls = ei[g * EPG + e] & 63;
        int ld = ei[E + g * EPG + e] & 63;
        int p = atomicAdd(&cur[ld], 1);
        lsrc[p] = ls;
        lcoef[p] = isq_g[ls] * isq_g[ld];
    }
    for (int idx = tid; idx < 64 * CH; idx += 256) {
        int i = idx / CH, f = idx - i * CH;
        hs[i][f] = __bfloat162float(H[(size_t)(g * 64 + i) * FP + c0 + f]);
    }
    __syncthreads();
    for (int idx = tid; idx < 64 * CH; idx += 256) {
        int i = idx / CH, f = idx - i * CH;
        float acc = hs[i][f] * ivd_g[i];
        int e1 = off[i + 1];
        for (int j = off[i]; j < e1; ++j)
            acc += hs[lsrc[j]][f] * lcoef[j];
        int c = c0 + f;
        acc += (c < 600) ? bias[c] : 0.f;
        if (RELU) acc = fmaxf(acc, 0.f);
        Xout[(size_t)(g * 64 + i) * FP + c] = __float2bfloat16(acc);
    }
}

// Global mean pool
__global__ __launch_bounds__(256) void k_pool(const bf16* __restrict__ X,
                                              float* __restrict__ G0)
{
    int g = blockIdx.x;
    int tid = threadIdx.x;
    for (int c = tid; c < 600; c += 256) {
        float s = 0.f;
        #pragma unroll 4
        for (int i = 0; i < 64; ++i)
            s += __bfloat162float(X[(size_t)(g * 64 + i) * FP + c]);
        G0[g * 600 + c] = s * (1.f / 64.f);
    }
}

// LayerNorm over 300 dims + affine, fp32 out
__global__ __launch_bounds__(256) void k_ln(const float* __restrict__ G,
                                            const float* __restrict__ lg,
                                            const float* __restrict__ lb,
                                            float* __restrict__ out)
{
    int r = blockIdx.x;
    int tid = threadIdx.x;
    __shared__ float red[4];
    __shared__ float smu, svar;

    float v0 = (tid < 300) ? G[r * 300 + tid] : 0.f;
    float v1 = (tid + 256 < 300) ? G[r * 300 + tid + 256] : 0.f;
    float s = v0 + v1;
    #pragma unroll
    for (int o = 32; o > 0; o >>= 1) s += __shfl_down(s, o, 64);
    if ((tid & 63) == 0) red[tid >> 6] = s;
    __syncthreads();
    if (tid == 0) smu = (red[0] + red[1] + red[2] + red[3]) * (1.f / 300.f);
    __syncthreads();
    float mu = smu;
    float d0 = (tid < 300) ? v0 - mu : 0.f;
    float d1 = (tid + 256 < 300) ? v1 - mu : 0.f;
    s = d0 * d0 + d1 * d1;
    #pragma unroll
    for (int o = 32; o > 0; o >>= 1) s += __shfl_down(s, o, 64);
    if ((tid & 63) == 0) red[tid >> 6] = s;
    __syncthreads();
    if (tid == 0) svar = (red[0] + red[1] + red[2] + red[3]) * (1.f / 300.f);
    __syncthreads();
    float rstd = rsqrtf(svar + 1e-5f);
    if (tid < 300)
        out[r * 300 + tid] = d0 * rstd * lg[tid] + lb[tid];
    if (tid + 256 < 300)
        out[r * 300 + tid + 256] = d1 * rstd * lg[tid + 256] + lb[tid + 256];
}

__global__ void k_copy(const uint4* __restrict__ src, uint4* __restrict__ dst, int n)
{
    int i = blockIdx.x * 256 + threadIdx.x;
    if (i < n) dst[i] = src[i];
}

// ---------------------------------------------------------------------------
extern "C" void kernel_launch(void* const* d_in, const int* in_sizes, int n_in,
                              void* d_out, int out_size, void* d_ws, size_t ws_size,
                              hipStream_t stream)
{
    const float* x_in  = (const float*)d_in[0];
    const int*   ei    = (const int*)d_in[1];
    const float* text  = (const float*)d_in[3];
    const float* tst   = (const float*)d_in[4];
    const float* mask  = (const float*)d_in[5];
    const float* W_tr  = (const float*)d_in[6];
    const float* b_tr  = (const float*)d_in[7];
    const float* W_c1  = (const float*)d_in[8];
    const float* b_c1  = (const float*)d_in[9];
    const float* W_c2  = (const float*)d_in[10];
    const float* b_c2  = (const float*)d_in[11];
    const float* W_c3  = (const float*)d_in[12];
    const float* b_c3  = (const float*)d_in[13];
    const float* W_h1  = (const float*)d_in[14];
    const float* b_h1  = (const float*)d_in[15];
    const float* W_h2  = (const float*)d_in[16];
    const float* b_h2  = (const float*)d_in[17];
    const float* W_h3  = (const float*)d_in[18];
    const float* b_h3  = (const float*)d_in[19];
    const float* ln_g  = (const float*)d_in[20];
    const float* ln_b  = (const float*)d_in[21];
    const float* W_t1  = (const float*)d_in[22];
    const float* b_t1  = (const float*)d_in[23];
    const float* W_t2  = (const float*)d_in[24];
    const float* b_t2  = (const float*)d_in[25];
    const float* W_e   = (const float*)d_in[26];
    const float* b_e   = (const float*)d_in[27];

    // workspace carve (256B aligned) — total ~181.3 MB (<= proven 183.4 MB)
    char* w = (char*)d_ws;
    size_t off = 0;
    auto carve = [&](size_t bytes) {
        void* p = w + off;
        off += (bytes + 255) & ~(size_t)255;
        return p;
    };
    bf16*  XA     = (bf16*) carve((size_t)BN * FP * 2);    // 79.7 MB
    bf16*  Hb     = (bf16*) carve((size_t)BN * FP * 2);    // 79.7 MB
    bf16*  Wb1    = (bf16*) carve((size_t)640 * 320 * 2);  // W_c1^T padded (640n x 320k)
    bf16*  Wb2    = (bf16*) carve((size_t)640 * FP * 2);   // W_c2^T padded (640n x 608k)
    bf16*  Wb3    = (bf16*) carve((size_t)640 * FP * 2);
    float* TE     = (float*)carve((size_t)B * 128 * 4);
    float* A1     = (float*)carve((size_t)B * 512 * 4);
    float* A2r    = (float*)carve((size_t)B * 512 * 4);
    bf16*  EO     = (bf16*) carve((size_t)B * 3000 * 2);   // 6.1 MB (bf16)
    float* G0     = (float*)carve((size_t)B * 600 * 4);
    float* G1     = (float*)carve((size_t)B * 600 * 4);
    float* G2     = (float*)carve((size_t)B * 600 * 4);
    float* G3     = (float*)carve((size_t)B * 300 * 4);
    float* invdeg = (float*)carve((size_t)BN * 4);
    float* isq    = (float*)carve((size_t)BN * 4);
    (void)ws_size; (void)in_sizes; (void)n_in; (void)out_size;

    float* out = (float*)d_out;

    // --- weight transpose/convert for conv GEMMs ---
    k_wt<<<(640 * 320 + 255) / 256, 256, 0, stream>>>(W_c1, Wb1, 300, 600, 320, 640);
    k_wt<<<(640 * FP + 255) / 256, 256, 0, stream>>>(W_c2, Wb2, 600, 600, FP, 640);
    k_wt<<<(640 * FP + 255) / 256, 256, 0, stream>>>(W_c3, Wb3, 600, 600, FP, 640);

    // --- timestep embedding MLP (fp32 vector GEMMs) ---
    k_te<<<(B * 128 + 255) / 256, 256, 0, stream>>>(tst, TE);
    run_gemm<float, true, false>(TE, 128, W_t1, 512, b_t1, A1, 512,
                                 nullptr, nullptr, 0, B, 512, 128, stream);
    run_gemm<float, true, false>(A1, 512, W_t2, 512, b_t2, A2r, 512,
                                 nullptr, nullptr, 0, B, 512, 512, stream);
    run_gemm<bf16, false, false>(A2r, 512, W_e, 3000, b_e, EO, 3000,
                                 nullptr, nullptr, 0, B, 3000, 512, stream);

    // --- graph path ---
    k_deg<<<B, 256, 0, stream>>>(ei, invdeg, isq);
    k_xtr<<<BN, 256, 0, stream>>>(x_in, W_tr, b_tr, mask, XA);

    dim3 cg(BN / 128, 5);   // 512 x 5 tiles (N covered to 640, store-guard 608)
    // conv1: K=320 (cols 300..319 of XA are zero)
    gemm_mfma<<<cg, 256, 0, stream>>>(XA, FP, Wb1, 320, Hb, FP, FP, 320);
    k_agg<true><<<dim3(B, 4), 256, 0, stream>>>(Hb, ei, invdeg, isq, b_c1, XA);
    // conv2: K=608
    gemm_mfma<<<cg, 256, 0, stream>>>(XA, FP, Wb2, FP, Hb, FP, FP, FP);
    k_agg<true><<<dim3(B, 4), 256, 0, stream>>>(Hb, ei, invdeg, isq, b_c2, XA);
    // conv3: K=608, no relu
    gemm_mfma<<<cg, 256, 0, stream>>>(XA, FP, Wb3, FP, Hb, FP, FP, FP);
    k_agg<false><<<dim3(B, 4), 256, 0, stream>>>(Hb, ei, invdeg, isq, b_c3, XA);

    // pool
    k_pool<<<B, 256, 0, stream>>>(XA, G0);

    // h-layers with FiLM from EO (bf16) slices
    run_gemm<float, true, true>(G0, 600, W_h1, 600, b_h1, G1, 600,
                                EO + 0, EO + 600, 3000, B, 600, 600, stream);
    run_gemm<float, true, true>(G1, 600, W_h2, 600, b_h2, G2, 600,
                                EO + 1200, EO + 1800, 3000, B, 600, 600, stream);
    run_gemm<float, false, true>(G2, 600, W_h3, 300, b_h3, G3, 300,
                                 EO + 2400, EO + 2700, 3000, B, 300, 600, stream);

    // layer norm -> out[0 : 307200]
    k_ln<<<B, 256, 0, stream>>>(G3, ln_g, ln_b, out);

    // text passthrough -> out[307200 : 614400]
    k_copy<<<(B * 300 * 4 / 16 + 255) / 256, 256, 0, stream>>>(
        (const uint4*)text, (uint4*)(out + (size_t)B * 300), B * 300 * 4 / 16);
}

// Round 4
// 651.616 us; speedup vs baseline: 5.3389x; 2.1460x over previous
//
#include <hip/hip_runtime.h>
#include <hip/hip_bf16.h>
#include <cstdint>
#include <cstddef>

// Problem constants
static constexpr int B   = 1024;
static constexpr int N   = 64;
static constexpr int BN  = B * N;      // 65536 nodes
static constexpr int EPG = 192;
static constexpr int E   = B * EPG;    // 196608 edges
static constexpr int FP  = 608;        // padded feature dim (mult of 32)

typedef __hip_bfloat16 bf16;
typedef __bf16 bf16x8 __attribute__((ext_vector_type(8)));
typedef float  f32x4  __attribute__((ext_vector_type(4)));

__device__ __forceinline__ void storeC(float* p, float v) { *p = v; }
__device__ __forceinline__ void storeC(bf16* p, float v) { *p = __float2bfloat16(v); }

// async global->LDS, 16B per lane; LDS dest is wave-uniform base + lane*16
__device__ __forceinline__ void llds16(const void* g, void* l) {
    __builtin_amdgcn_global_load_lds(
        (const __attribute__((address_space(1))) unsigned int*)g,
        (__attribute__((address_space(3))) unsigned int*)l,
        16, 0, 0);
}

// ===========================================================================
// MFMA GEMM with bias/ReLU/FiLM epilogue.
// C[M x Ncap] = A[M x K] @ Bt^T (+bias)(relu)(film).  Bt is Np x K rows.
// M mult of 128 (grid.x = M/128), grid.y tiles N by 128, K mult of 32.
// ===========================================================================
template<bool RELU, bool FILM, typename CT>
__global__ __launch_bounds__(256) void gemm_ep(
    const bf16* __restrict__ A, int lda,
    const bf16* __restrict__ Bt, int ldb,
    const float* __restrict__ bias,
    CT* __restrict__ C, int ldc, int Ncap,
    const bf16* __restrict__ fS, const bf16* __restrict__ fT, int fstride,
    int K)
{
    __shared__ __align__(16) __bf16 As[128 * 32];
    __shared__ __align__(16) __bf16 Bs[128 * 32];

    const int tid  = threadIdx.x;
    const int lane = tid & 63;
    const int w    = tid >> 6;
    const int wm   = (w & 1) * 64;
    const int wn   = (w >> 1) * 64;
    const int m0   = blockIdx.x * 128;
    const int n0   = blockIdx.y * 128;
    const int l15  = lane & 15;
    const int lhi  = lane >> 4;

    f32x4 acc[4][4] = {};

    for (int k0 = 0; k0 < K; k0 += 32) {
        #pragma unroll
        for (int t = 0; t < 2; ++t) {
            int ci  = t * 256 + w * 64 + lane;
            int row = ci >> 2, kc = ci & 3;
            char* la = (char*)As + (size_t)(t * 256 + w * 64) * 16;
            char* lb = (char*)Bs + (size_t)(t * 256 + w * 64) * 16;
            llds16(A  + (size_t)(m0 + row) * lda + k0 + kc * 8, la);
            llds16(Bt + (size_t)(n0 + row) * ldb + k0 + kc * 8, lb);
        }
        asm volatile("s_waitcnt vmcnt(0)" ::: "memory");
        __syncthreads();

        bf16x8 af[4], bg[4];
        #pragma unroll
        for (int i = 0; i < 4; ++i)
            af[i] = *(bf16x8*)(As + (wm + i * 16 + l15) * 32 + lhi * 8);
        #pragma unroll
        for (int j = 0; j < 4; ++j)
            bg[j] = *(bf16x8*)(Bs + (wn + j * 16 + l15) * 32 + lhi * 8);
        #pragma unroll
        for (int i = 0; i < 4; ++i)
            #pragma unroll
            for (int j = 0; j < 4; ++j)
                acc[i][j] = __builtin_amdgcn_mfma_f32_16x16x32_bf16(
                    af[i], bg[j], acc[i][j], 0, 0, 0);
        __syncthreads();
    }

    #pragma unroll
    for (int i = 0; i < 4; ++i) {
        #pragma unroll
        for (int j = 0; j < 4; ++j) {
            int col = n0 + wn + j * 16 + l15;
            if (col < Ncap) {
                float bv = bias ? bias[col] : 0.f;
                #pragma unroll
                for (int e = 0; e < 4; ++e) {
                    int row = m0 + wm + i * 16 + lhi * 4 + e;
                    float v = acc[i][j][e] + bv;
                    if (RELU) v = fmaxf(v, 0.f);
                    if (FILM) {
                        float sv = __bfloat162float(fS[(size_t)row * fstride + col]);
                        float tv = __bfloat162float(fT[(size_t)row * fstride + col]);
                        v = v * (1.f + sv) + tv;
                    }
                    storeC(&C[(size_t)row * ldc + col], v);
                }
            }
        }
    }
}

// ===========================================================================
// Fused GCN conv: per block = 128 node-rows (exactly graphs 2bx, 2bx+1) x
// 128 H-cols.  H-tile = A @ Bt^T computed by MFMA, staged in LDS, then
// aggregation (edge mixing + self/deg + bias [+relu]) applied in-block.
// POOL variant: instead of writing Xout, reduce-mean over each graph's 64
// rows and write G0 (bf16, stride FP).
// ===========================================================================
template<bool RELU, bool POOL>
__global__ __launch_bounds__(256) void conv_fused(
    const bf16* __restrict__ A, int lda, int K,
    const bf16* __restrict__ Bt, int ldb,
    const int* __restrict__ ei,
    const float* __restrict__ invdeg, const float* __restrict__ isq,
    const float* __restrict__ bias,
    bf16* __restrict__ Xout, bf16* __restrict__ G0)
{
    constexpr int TSS = 140;   // Ts stride (conflict-friendly)
    __shared__ __align__(16) char smem[128 * TSS * 2];   // 35840 B: As+Bs / Ts / Rs
    __shared__ int   e_lsrc[2 * EPG];
    __shared__ float e_lcoef[2 * EPG];
    __shared__ int   e_off[129];
    __shared__ int   e_cnt[128];
    __shared__ int   e_cur[128];
    __shared__ float e_ivd[128];
    __shared__ float e_isq[128];
    __shared__ float e_bias[128];

    __bf16* As = (__bf16*)smem;
    __bf16* Bs = (__bf16*)(smem + 8192);
    __bf16* Ts = (__bf16*)smem;
    float*  Rs = (float*)smem;

    const int tid  = threadIdx.x;
    const int lane = tid & 63;
    const int w    = tid >> 6;
    const int wm   = (w & 1) * 64;
    const int wn   = (w >> 1) * 64;
    const int m0   = blockIdx.x * 128;
    const int n0   = blockIdx.y * 128;
    const int l15  = lane & 15;
    const int lhi  = lane >> 4;
    const int g0   = m0 >> 6;          // first of the 2 graphs in this block

    // ---- build per-block CSR of edges (both graphs), coefs, bias ----
    if (tid < 128) {
        e_cnt[tid]  = 0;
        e_ivd[tid]  = invdeg[m0 + tid];
        e_isq[tid]  = isq[m0 + tid];
        e_bias[tid] = (n0 + tid < 600) ? bias[n0 + tid] : 0.f;
    }
    __syncthreads();
    for (int e = tid; e < 2 * EPG; e += 256) {
        int g  = (e >= EPG);
        int eg = (g0 + g) * EPG + (e - g * EPG);
        int ld = (ei[E + eg] & 63) + g * 64;
        atomicAdd(&e_cnt[ld], 1);
    }
    __syncthreads();
    if (tid < 2) {
        int base = tid * EPG;          // each graph contributes exactly EPG edges
        for (int r = tid * 64; r < tid * 64 + 64; ++r) { e_off[r] = base; base += e_cnt[r]; }
        if (tid == 1) e_off[128] = 2 * EPG;
    }
    __syncthreads();
    if (tid < 128) e_cur[tid] = e_off[tid];
    __syncthreads();
    for (int e = tid; e < 2 * EPG; e += 256) {
        int g  = (e >= EPG);
        int eg = (g0 + g) * EPG + (e - g * EPG);
        int ls = (ei[eg] & 63) + g * 64;
        int ld = (ei[E + eg] & 63) + g * 64;
        int p  = atomicAdd(&e_cur[ld], 1);
        e_lsrc[p]  = ls;
        e_lcoef[p] = e_isq[ls] * e_isq[ld];
    }
    // (ordered before epilogue reads by the K-loop barriers)

    // ---- MFMA main loop (m97 structure) ----
    f32x4 acc[4][4] = {};
    for (int k0 = 0; k0 < K; k0 += 32) {
        #pragma unroll
        for (int t = 0; t < 2; ++t) {
            int ci  = t * 256 + w * 64 + lane;
            int row = ci >> 2, kc = ci & 3;
            char* la = (char*)As + (size_t)(t * 256 + w * 64) * 16;
            char* lb = (char*)Bs + (size_t)(t * 256 + w * 64) * 16;
            llds16(A  + (size_t)(m0 + row) * lda + k0 + kc * 8, la);
            llds16(Bt + (size_t)(n0 + row) * ldb + k0 + kc * 8, lb);
        }
        asm volatile("s_waitcnt vmcnt(0)" ::: "memory");
        __syncthreads();

        bf16x8 af[4], bg[4];
        #pragma unroll
        for (int i = 0; i < 4; ++i)
            af[i] = *(bf16x8*)(As + (wm + i * 16 + l15) * 32 + lhi * 8);
        #pragma unroll
        for (int j = 0; j < 4; ++j)
            bg[j] = *(bf16x8*)(Bs + (wn + j * 16 + l15) * 32 + lhi * 8);
        #pragma unroll
        for (int i = 0; i < 4; ++i)
            #pragma unroll
            for (int j = 0; j < 4; ++j)
                acc[i][j] = __builtin_amdgcn_mfma_f32_16x16x32_bf16(
                    af[i], bg[j], acc[i][j], 0, 0, 0);
        __syncthreads();
    }

    // ---- spill H-tile to LDS (bf16) ----
    #pragma unroll
    for (int i = 0; i < 4; ++i)
        #pragma unroll
        for (int j = 0; j < 4; ++j)
            #pragma unroll
            for (int e = 0; e < 4; ++e) {
                int row = wm + i * 16 + lhi * 4 + e;
                int col = wn + j * 16 + l15;
                Ts[row * TSS + col] = (__bf16)acc[i][j][e];
            }
    __syncthreads();

    // ---- aggregation: 2048 tasks = 128 rows x 16 col-groups (8 cols) ----
    float psum0[8] = {}, psum1[8] = {};
    #pragma unroll
    for (int s = 0; s < 8; ++s) {
        int t   = tid + 256 * s;
        int row = t >> 4;
        int cg  = t & 15;
        bf16x8 sv = *(const bf16x8*)(Ts + row * TSS + cg * 8);
        float ivd = e_ivd[row];
        float av[8];
        #pragma unroll
        for (int k = 0; k < 8; ++k) av[k] = (float)sv[k] * ivd;
        int pe = e_off[row + 1];
        for (int p = e_off[row]; p < pe; ++p) {
            bf16x8 nv = *(const bf16x8*)(Ts + e_lsrc[p] * TSS + cg * 8);
            float cf = e_lcoef[p];
            #pragma unroll
            for (int k = 0; k < 8; ++k) av[k] += (float)nv[k] * cf;
        }
        #pragma unroll
        for (int k = 0; k < 8; ++k) {
            av[k] += e_bias[cg * 8 + k];
            if (RELU) av[k] = fmaxf(av[k], 0.f);
        }
        if (POOL) {
            float* ps = (s < 4) ? psum0 : psum1;
            #pragma unroll
            for (int k = 0; k < 8; ++k) ps[k] += av[k];
        } else {
            if (n0 + cg * 8 < FP) {
                bf16x8 ov;
                #pragma unroll
                for (int k = 0; k < 8; ++k) ov[k] = (__bf16)av[k];
                *(bf16x8*)((__bf16*)Xout + (size_t)(m0 + row) * FP + n0 + cg * 8) = ov;
            }
        }
    }

    if (POOL) {
        __syncthreads();                 // Ts reads done -> Rs may alias
        int grp = tid >> 4, cg = tid & 15;
        #pragma unroll
        for (int k = 0; k < 8; ++k) {
            Rs[grp * 256 +       cg * 8 + k] = psum0[k];
            Rs[grp * 256 + 128 + cg * 8 + k] = psum1[k];
        }
        __syncthreads();
        int g = tid >> 7, col = tid & 127;
        float tot = 0.f;
        #pragma unroll
        for (int q = 0; q < 16; ++q) tot += Rs[q * 256 + g * 128 + col];
        if (n0 + col < 600)
            G0[(size_t)(g0 + g) * FP + n0 + col] = __float2bfloat16(tot * (1.f / 64.f));
    }
}

// ===========================================================================
// Batched weight convert+transpose+pad: dst[n][k] = src[k][n] (fp32->bf16)
// ===========================================================================
struct WtJob  { const float* src; bf16* dst; int Ksrc, Nsrc, Kp, Np; };
struct WtJobs { WtJob j[9]; };

__global__ __launch_bounds__(256) void k_wt_all(WtJobs jobs)
{
    WtJob jb = jobs.j[blockIdx.y];
    int total = jb.Np * jb.Kp;
    for (int idx = blockIdx.x * 256 + threadIdx.x; idx < total; idx += gridDim.x * 256) {
        int n = idx / jb.Kp, k = idx - n * jb.Kp;
        float v = (n < jb.Nsrc && k < jb.Ksrc) ? jb.src[(size_t)k * jb.Nsrc + n] : 0.f;
        jb.dst[idx] = __float2bfloat16(v);
    }
}

// ---------------------------------------------------------------------------
__global__ void k_te(const float* __restrict__ ts, bf16* __restrict__ TE)
{
    int idx = blockIdx.x * 256 + threadIdx.x;
    if (idx >= B * 128) return;
    int b = idx >> 7, j = idx & 127;
    float t = ts[b];
    int h = j & 63;
    float freq = expf(-9.210340371976184f * (float)h / 64.f);  // ln(10000)
    float a = t * freq;
    TE[idx] = __float2bfloat16((j < 64) ? cosf(a) : sinf(a));
}

__global__ __launch_bounds__(256) void k_deg(const int* __restrict__ ei,
                                             float* __restrict__ invdeg,
                                             float* __restrict__ isq)
{
    int g = blockIdx.x;
    int tid = threadIdx.x;
    __shared__ int cnt[64];
    if (tid < 64) cnt[tid] = 0;
    __syncthreads();
    for (int e = tid; e < EPG; e += 256)
        atomicAdd(&cnt[ei[E + g * EPG + e] & 63], 1);
    __syncthreads();
    if (tid < 64) {
        float d = (float)cnt[tid] + 1.0f;
        invdeg[g * 64 + tid] = 1.f / d;
        isq[g * 64 + tid] = rsqrtf(d);
    }
}

// Node transform: X[node][0:300] = (x_in @ W_tr + b_tr)*mask ; cols 300..FP-1 = 0
__global__ __launch_bounds__(256) void k_xtr(const float* __restrict__ xin,
                                             const float* __restrict__ Wtr,
                                             const float* __restrict__ btr,
                                             const float* __restrict__ mask,
                                             bf16* __restrict__ X)
{
    int node = blockIdx.x;
    int tid = threadIdx.x;
    __shared__ float xr[19];
    if (tid < 19) xr[tid] = xin[node * 19 + tid];
    __syncthreads();
    float m = mask[node];
    for (int c = tid; c < FP; c += 256) {
        float v = 0.f;
        if (c < 300) {
            float acc = btr[c];
            #pragma unroll
            for (int k = 0; k < 19; ++k)
                acc += xr[k] * Wtr[k * 300 + c];
            v = acc * m;
        }
        X[(size_t)node * FP + c] = __float2bfloat16(v);
    }
}

// LayerNorm over 300 dims + affine, fp32 out
__global__ __launch_bounds__(256) void k_ln(const float* __restrict__ G,
                                            const float* __restrict__ lg,
                                            const float* __restrict__ lb,
                                            float* __restrict__ out)
{
    int r = blockIdx.x;
    int tid = threadIdx.x;
    __shared__ float red[4];
    __shared__ float smu, svar;

    float v0 = (tid < 300) ? G[r * 300 + tid] : 0.f;
    float v1 = (tid + 256 < 300) ? G[r * 300 + tid + 256] : 0.f;
    float s = v0 + v1;
    #pragma unroll
    for (int o = 32; o > 0; o >>= 1) s += __shfl_down(s, o, 64);
    if ((tid & 63) == 0) red[tid >> 6] = s;
    __syncthreads();
    if (tid == 0) smu = (red[0] + red[1] + red[2] + red[3]) * (1.f / 300.f);
    __syncthreads();
    float mu = smu;
    float d0 = (tid < 300) ? v0 - mu : 0.f;
    float d1 = (tid + 256 < 300) ? v1 - mu : 0.f;
    s = d0 * d0 + d1 * d1;
    #pragma unroll
    for (int o = 32; o > 0; o >>= 1) s += __shfl_down(s, o, 64);
    if ((tid & 63) == 0) red[tid >> 6] = s;
    __syncthreads();
    if (tid == 0) svar = (red[0] + red[1] + red[2] + red[3]) * (1.f / 300.f);
    __syncthreads();
    float rstd = rsqrtf(svar + 1e-5f);
    if (tid < 300)
        out[r * 300 + tid] = d0 * rstd * lg[tid] + lb[tid];
    if (tid + 256 < 300)
        out[r * 300 + tid + 256] = d1 * rstd * lg[tid + 256] + lb[tid + 256];
}

__global__ void k_copy(const uint4* __restrict__ src, uint4* __restrict__ dst, int n)
{
    int i = blockIdx.x * 256 + threadIdx.x;
    if (i < n) dst[i] = src[i];
}

// ---------------------------------------------------------------------------
extern "C" void kernel_launch(void* const* d_in, const int* in_sizes, int n_in,
                              void* d_out, int out_size, void* d_ws, size_t ws_size,
                              hipStream_t stream)
{
    const float* x_in  = (const float*)d_in[0];
    const int*   ei    = (const int*)d_in[1];
    const float* text  = (const float*)d_in[3];
    const float* tst   = (const float*)d_in[4];
    const float* mask  = (const float*)d_in[5];
    const float* W_tr  = (const float*)d_in[6];
    const float* b_tr  = (const float*)d_in[7];
    const float* W_c1  = (const float*)d_in[8];
    const float* b_c1  = (const float*)d_in[9];
    const float* W_c2  = (const float*)d_in[10];
    const float* b_c2  = (const float*)d_in[11];
    const float* W_c3  = (const float*)d_in[12];
    const float* b_c3  = (const float*)d_in[13];
    const float* W_h1  = (const float*)d_in[14];
    const float* b_h1  = (const float*)d_in[15];
    const float* W_h2  = (const float*)d_in[16];
    const float* b_h2  = (const float*)d_in[17];
    const float* W_h3  = (const float*)d_in[18];
    const float* b_h3  = (const float*)d_in[19];
    const float* ln_g  = (const float*)d_in[20];
    const float* ln_b  = (const float*)d_in[21];
    const float* W_t1  = (const float*)d_in[22];
    const float* b_t1  = (const float*)d_in[23];
    const float* W_t2  = (const float*)d_in[24];
    const float* b_t2  = (const float*)d_in[25];
    const float* W_e   = (const float*)d_in[26];
    const float* b_e   = (const float*)d_in[27];

    // workspace carve (256B aligned) — total ~98 MB
    char* w = (char*)d_ws;
    size_t off = 0;
    auto carve = [&](size_t bytes) {
        void* p = w + off;
        off += (bytes + 255) & ~(size_t)255;
        return p;
    };
    bf16*  XA     = (bf16*) carve((size_t)BN * FP * 2);      // 79.7 MB
    bf16*  Wb1    = (bf16*) carve((size_t)640 * 320 * 2);
    bf16*  Wb2    = (bf16*) carve((size_t)640 * FP * 2);
    bf16*  Wb3    = (bf16*) carve((size_t)640 * FP * 2);
    bf16*  Wt1t   = (bf16*) carve((size_t)512 * 128 * 2);
    bf16*  Wt2t   = (bf16*) carve((size_t)512 * 512 * 2);
    bf16*  Wet    = (bf16*) carve((size_t)3072 * 512 * 2);
    bf16*  Wh1t   = (bf16*) carve((size_t)640 * FP * 2);
    bf16*  Wh2t   = (bf16*) carve((size_t)640 * FP * 2);
    bf16*  Wh3t   = (bf16*) carve((size_t)384 * FP * 2);
    bf16*  TE     = (bf16*) carve((size_t)B * 128 * 2);
    bf16*  A1b    = (bf16*) carve((size_t)B * 512 * 2);
    bf16*  A2b    = (bf16*) carve((size_t)B * 512 * 2);
    bf16*  EO     = (bf16*) carve((size_t)B * 3000 * 2);
    bf16*  G0     = (bf16*) carve((size_t)B * FP * 2);
    bf16*  G1     = (bf16*) carve((size_t)B * FP * 2);
    bf16*  G2     = (bf16*) carve((size_t)B * FP * 2);
    float* G3     = (float*)carve((size_t)B * 300 * 4);
    float* invdeg = (float*)carve((size_t)BN * 4);
    float* isq    = (float*)carve((size_t)BN * 4);
    (void)ws_size; (void)in_sizes; (void)n_in; (void)out_size;

    float* out = (float*)d_out;

    // --- all weight transposes/conversions in one dispatch ---
    WtJobs jobs = {{
        { W_c1, Wb1,  300, 600, 320, 640 },
        { W_c2, Wb2,  600, 600, FP,  640 },
        { W_c3, Wb3,  600, 600, FP,  640 },
        { W_t1, Wt1t, 128, 512, 128, 512 },
        { W_t2, Wt2t, 512, 512, 512, 512 },
        { W_e,  Wet,  512, 3000, 512, 3072 },
        { W_h1, Wh1t, 600, 600, FP,  640 },
        { W_h2, Wh2t, 600, 600, FP,  640 },
        { W_h3, Wh3t, 600, 300, FP,  384 },
    }};
    k_wt_all<<<dim3(1024, 9), 256, 0, stream>>>(jobs);

    // --- timestep embedding MLP (all MFMA) ---
    k_te<<<(B * 128 + 255) / 256, 256, 0, stream>>>(tst, TE);
    gemm_ep<true, false, bf16><<<dim3(8, 4), 256, 0, stream>>>(
        TE, 128, Wt1t, 128, b_t1, A1b, 512, 512, nullptr, nullptr, 0, 128);
    gemm_ep<true, false, bf16><<<dim3(8, 4), 256, 0, stream>>>(
        A1b, 512, Wt2t, 512, b_t2, A2b, 512, 512, nullptr, nullptr, 0, 512);
    gemm_ep<false, false, bf16><<<dim3(8, 24), 256, 0, stream>>>(
        A2b, 512, Wet, 512, b_e, EO, 3000, 3000, nullptr, nullptr, 0, 512);

    // --- graph path ---
    k_deg<<<B, 256, 0, stream>>>(ei, invdeg, isq);
    k_xtr<<<BN, 256, 0, stream>>>(x_in, W_tr, b_tr, mask, XA);

    dim3 cg(BN / 128, 5);   // 512 m-tiles x 5 n-tiles (640 cols, guard 608/600)
    conv_fused<true,  false><<<cg, 256, 0, stream>>>(XA, FP, 320, Wb1, 320,
        ei, invdeg, isq, b_c1, XA, nullptr);
    conv_fused<true,  false><<<cg, 256, 0, stream>>>(XA, FP, FP, Wb2, FP,
        ei, invdeg, isq, b_c2, XA, nullptr);
    conv_fused<false, true ><<<cg, 256, 0, stream>>>(XA, FP, FP, Wb3, FP,
        ei, invdeg, isq, b_c3, nullptr, G0);

    // --- h-layers with FiLM (MFMA) ---
    gemm_ep<true, true, bf16><<<dim3(8, 5), 256, 0, stream>>>(
        G0, FP, Wh1t, FP, b_h1, G1, FP, 600, EO + 0, EO + 600, 3000, FP);
    gemm_ep<true, true, bf16><<<dim3(8, 5), 256, 0, stream>>>(
        G1, FP, Wh2t, FP, b_h2, G2, FP, 600, EO + 1200, EO + 1800, 3000, FP);
    gemm_ep<false, true, float><<<dim3(8, 3), 256, 0, stream>>>(
        G2, FP, Wh3t, FP, b_h3, G3, 300, 300, EO + 2400, EO + 2700, 3000, FP);

    // layer norm -> out[0 : 307200]
    k_ln<<<B, 256, 0, stream>>>(G3, ln_g, ln_b, out);

    // text passthrough -> out[307200 : 614400]
    k_copy<<<(B * 300 * 4 / 16 + 255) / 256, 256, 0, stream>>>(
        (const uint4*)text, (uint4*)(out + (size_t)B * 300), B * 300 * 4 / 16);
}

// Round 6
// 530.461 us; speedup vs baseline: 6.5583x; 1.2284x over previous
//
#include <hip/hip_runtime.h>
#include <hip/hip_bf16.h>
#include <cstdint>
#include <cstddef>

// Problem constants
static constexpr int B   = 1024;
static constexpr int N   = 64;
static constexpr int BN  = B * N;      // 65536 nodes
static constexpr int EPG = 192;
static constexpr int E   = B * EPG;    // 196608 edges
static constexpr int FP  = 608;        // padded feature dim (mult of 32)

typedef __hip_bfloat16 bf16;
typedef __bf16 bf16x8 __attribute__((ext_vector_type(8)));
typedef __bf16 bf16x4 __attribute__((ext_vector_type(4)));
typedef float  f32x4  __attribute__((ext_vector_type(4)));

__device__ __forceinline__ void storeC(float* p, float v) { *p = v; }
__device__ __forceinline__ void storeC(bf16* p, float v) { *p = __float2bfloat16(v); }

// async global->LDS, 16B per lane; LDS dest is wave-uniform base + lane*16
__device__ __forceinline__ void llds16(const void* g, void* l) {
    __builtin_amdgcn_global_load_lds(
        (const __attribute__((address_space(1))) unsigned int*)g,
        (__attribute__((address_space(3))) unsigned int*)l,
        16, 0, 0);
}

// ===========================================================================
// MFMA GEMM with bias/ReLU/FiLM epilogue.
// C[M x Ncap] = A[M x K] @ Bt^T (+bias)(relu)(film).  Bt is Np x K rows.
// M mult of 128 (grid.x = M/128), grid.y tiles N by 128, K mult of 32.
// ===========================================================================
template<bool RELU, bool FILM, typename CT>
__global__ __launch_bounds__(256) void gemm_ep(
    const bf16* __restrict__ A, int lda,
    const bf16* __restrict__ Bt, int ldb,
    const float* __restrict__ bias,
    CT* __restrict__ C, int ldc, int Ncap,
    const bf16* __restrict__ fS, const bf16* __restrict__ fT, int fstride,
    int K)
{
    __shared__ __align__(16) __bf16 As[128 * 32];
    __shared__ __align__(16) __bf16 Bs[128 * 32];

    const int tid  = threadIdx.x;
    const int lane = tid & 63;
    const int w    = tid >> 6;
    const int wm   = (w & 1) * 64;
    const int wn   = (w >> 1) * 64;
    const int m0   = blockIdx.x * 128;
    const int n0   = blockIdx.y * 128;
    const int l15  = lane & 15;
    const int lhi  = lane >> 4;

    f32x4 acc[4][4] = {};

    for (int k0 = 0; k0 < K; k0 += 32) {
        #pragma unroll
        for (int t = 0; t < 2; ++t) {
            int ci  = t * 256 + w * 64 + lane;
            int row = ci >> 2, kc = ci & 3;
            char* la = (char*)As + (size_t)(t * 256 + w * 64) * 16;
            char* lb = (char*)Bs + (size_t)(t * 256 + w * 64) * 16;
            llds16(A  + (size_t)(m0 + row) * lda + k0 + kc * 8, la);
            llds16(Bt + (size_t)(n0 + row) * ldb + k0 + kc * 8, lb);
        }
        asm volatile("s_waitcnt vmcnt(0)" ::: "memory");
        __syncthreads();

        bf16x8 af[4], bg[4];
        #pragma unroll
        for (int i = 0; i < 4; ++i)
            af[i] = *(bf16x8*)(As + (wm + i * 16 + l15) * 32 + lhi * 8);
        #pragma unroll
        for (int j = 0; j < 4; ++j)
            bg[j] = *(bf16x8*)(Bs + (wn + j * 16 + l15) * 32 + lhi * 8);
        #pragma unroll
        for (int i = 0; i < 4; ++i)
            #pragma unroll
            for (int j = 0; j < 4; ++j)
                acc[i][j] = __builtin_amdgcn_mfma_f32_16x16x32_bf16(
                    af[i], bg[j], acc[i][j], 0, 0, 0);
        __syncthreads();
    }

    #pragma unroll
    for (int i = 0; i < 4; ++i) {
        #pragma unroll
        for (int j = 0; j < 4; ++j) {
            int col = n0 + wn + j * 16 + l15;
            if (col < Ncap) {
                float bv = bias ? bias[col] : 0.f;
                #pragma unroll
                for (int e = 0; e < 4; ++e) {
                    int row = m0 + wm + i * 16 + lhi * 4 + e;
                    float v = acc[i][j][e] + bv;
                    if (RELU) v = fmaxf(v, 0.f);
                    if (FILM) {
                        float sv = __bfloat162float(fS[(size_t)row * fstride + col]);
                        float tv = __bfloat162float(fT[(size_t)row * fstride + col]);
                        v = v * (1.f + sv) + tv;
                    }
                    storeC(&C[(size_t)row * ldc + col], v);
                }
            }
        }
    }
}

// ===========================================================================
// Fused GCN conv (conv1/conv2): block = 128 node-rows (graphs 2t, 2t+1) x 128
// H-cols.  H = A @ Bt^T via MFMA; then out = P @ H via MFMA where P is the
// per-graph 64x64 normalized adjacency (built in LDS from edges).  ReLU+bias
// fused.  Grid: 1-D 2560, XCD-swizzled so the 5 n-tiles of one m-tile share
// an XCD's L2.
// ===========================================================================
__global__ __launch_bounds__(256) void conv_fused(
    const bf16* __restrict__ A, int lda, int K,
    const bf16* __restrict__ Bt, int ldb,
    const int* __restrict__ ei,
    const float* __restrict__ invdeg, const float* __restrict__ isq,
    const float* __restrict__ bias,
    bf16* __restrict__ Xout)
{
    // region A (32768 B): Pf32[2][64][64] -> As(8K)+Bs(8K) -> Ts[64][136] bf16
    __shared__ __align__(16) char regA[32768];
    __shared__ __align__(16) __bf16 Pm[128 * 72];   // 18432 B, A-operand layout
    __shared__ float s_isq[128];
    __shared__ float s_ivd[128];

    float*  Pf = (float*)regA;
    __bf16* As = (__bf16*)regA;
    __bf16* Bs = (__bf16*)(regA + 8192);
    __bf16* Ts = (__bf16*)regA;

    const int tid  = threadIdx.x;
    const int lane = tid & 63;
    const int w    = tid >> 6;
    const int wm   = (w & 1) * 64;
    const int wn   = (w >> 1) * 64;
    const int l15  = lane & 15;
    const int lhi  = lane >> 4;

    // XCD-aware decode: 2560 blocks = 8 XCDs x (64 m-tiles x 5 n-tiles)
    const int bid = blockIdx.x;
    const int lid = bid >> 3;              // 0..319
    const int mt  = (bid & 7) * 64 + lid / 5;
    const int nt  = lid % 5;
    const int m0  = mt * 128;
    const int n0  = nt * 128;
    const int g0  = mt * 2;                // first graph of this block

    // ---- build P (both graphs) in fp32, convert to bf16 A-operand rows ----
    for (int idx = tid; idx < 8192; idx += 256) Pf[idx] = 0.f;
    if (tid < 128) {
        s_isq[tid] = isq[m0 + tid];
        s_ivd[tid] = invdeg[m0 + tid];
    }
    __syncthreads();
    for (int e = tid; e < 2 * EPG; e += 256) {
        int g  = (e >= EPG);
        int eg = (g0 + g) * EPG + (e - g * EPG);
        int ls = ei[eg] & 63;
        int ld = ei[E + eg] & 63;
        atomicAdd(&Pf[g * 4096 + ld * 64 + ls],
                  s_isq[g * 64 + ls] * s_isq[g * 64 + ld]);
    }
    __syncthreads();
    if (tid < 128)
        Pf[(tid >> 6) * 4096 + (tid & 63) * 64 + (tid & 63)] += s_ivd[tid];
    __syncthreads();
    for (int idx = tid; idx < 128 * 72; idx += 256) {
        int r = idx / 72, k = idx - r * 72;
        float v = (k < 64) ? Pf[(r >> 6) * 4096 + (r & 63) * 64 + k] : 0.f;
        Pm[idx] = (__bf16)v;
    }
    __syncthreads();   // Pf dead; As/Bs may now use region A

    // ---- MFMA main loop ----
    f32x4 acc[4][4] = {};
    for (int k0 = 0; k0 < K; k0 += 32) {
        #pragma unroll
        for (int t = 0; t < 2; ++t) {
            int ci  = t * 256 + w * 64 + lane;
            int row = ci >> 2, kc = ci & 3;
            char* la = (char*)As + (size_t)(t * 256 + w * 64) * 16;
            char* lb = (char*)Bs + (size_t)(t * 256 + w * 64) * 16;
            llds16(A  + (size_t)(m0 + row) * lda + k0 + kc * 8, la);
            llds16(Bt + (size_t)(n0 + row) * ldb + k0 + kc * 8, lb);
        }
        asm volatile("s_waitcnt vmcnt(0)" ::: "memory");
        __syncthreads();

        bf16x8 af[4], bg[4];
        #pragma unroll
        for (int i = 0; i < 4; ++i)
            af[i] = *(bf16x8*)(As + (wm + i * 16 + l15) * 32 + lhi * 8);
        #pragma unroll
        for (int j = 0; j < 4; ++j)
            bg[j] = *(bf16x8*)(Bs + (wn + j * 16 + l15) * 32 + lhi * 8);
        #pragma unroll
        for (int i = 0; i < 4; ++i)
            #pragma unroll
            for (int j = 0; j < 4; ++j)
                acc[i][j] = __builtin_amdgcn_mfma_f32_16x16x32_bf16(
                    af[i], bg[j], acc[i][j], 0, 0, 0);
        __syncthreads();
    }

    // ---- out = P @ H, processed in two 64-col halves (Ts = H^T half) ----
    const int g  = w & 1;        // graph this wave computes in P@H
    const int nb = w >> 1;       // 32-col sub-block
    #pragma unroll
    for (int h = 0; h < 2; ++h) {
        // spill: the two waves whose acc covers this half's cols
        if (wn == h * 64) {
            #pragma unroll
            for (int i = 0; i < 4; ++i)
                #pragma unroll
                for (int j = 0; j < 4; ++j) {
                    int c_local = j * 16 + l15;
                    int rbase   = wm + i * 16 + lhi * 4;
                    bf16x4 pk;
                    #pragma unroll
                    for (int e = 0; e < 4; ++e) pk[e] = (__bf16)acc[i][j][e];
                    *(bf16x4*)(Ts + c_local * 136 + rbase) = pk;
                }
        }
        __syncthreads();

        f32x4 acc2[4][2] = {};
        #pragma unroll
        for (int k0 = 0; k0 < 64; k0 += 32) {
            bf16x8 pa[4], hb[2];
            #pragma unroll
            for (int i = 0; i < 4; ++i)
                pa[i] = *(bf16x8*)(Pm + (g * 64 + i * 16 + l15) * 72 + k0 + lhi * 8);
            #pragma unroll
            for (int j = 0; j < 2; ++j)
                hb[j] = *(bf16x8*)(Ts + (nb * 32 + j * 16 + l15) * 136
                                      + g * 64 + k0 + lhi * 8);
            #pragma unroll
            for (int i = 0; i < 4; ++i)
                #pragma unroll
                for (int j = 0; j < 2; ++j)
                    acc2[i][j] = __builtin_amdgcn_mfma_f32_16x16x32_bf16(
                        pa[i], hb[j], acc2[i][j], 0, 0, 0);
        }
        #pragma unroll
        for (int i = 0; i < 4; ++i)
            #pragma unroll
            for (int j = 0; j < 2; ++j) {
                int col = n0 + h * 64 + nb * 32 + j * 16 + l15;
                if (col < FP) {
                    float bv = (col < 600) ? bias[col] : 0.f;
                    #pragma unroll
                    for (int e = 0; e < 4; ++e) {
                        int row = m0 + g * 64 + i * 16 + lhi * 4 + e;
                        float v = fmaxf(acc2[i][j][e] + bv, 0.f);   // relu
                        Xout[(size_t)row * FP + col] = __float2bfloat16(v);
                    }
                }
            }
        __syncthreads();
    }
}

// ===========================================================================
// conv3+pool collapsed: Y[g] = q_g @ X_g  (1 x FP per graph), where
// q[s] = (1/64)(invdeg[s] + sum_{e: src=s} coef_e).  G0 = Y @ W3^T + b later.
// ===========================================================================
__global__ __launch_bounds__(256) void k_qx(const bf16* __restrict__ X,
                                            const int* __restrict__ ei,
                                            const float* __restrict__ invdeg,
                                            const float* __restrict__ isq,
                                            bf16* __restrict__ Y)
{
    __shared__ float sQ[64];
    __shared__ float sI[64];
    __shared__ float Yp[4][76][8];

    int g   = blockIdx.x;
    int tid = threadIdx.x;

    if (tid < 64) {
        sI[tid] = isq[g * 64 + tid];
        sQ[tid] = invdeg[g * 64 + tid];
    }
    __syncthreads();
    if (tid < EPG) {
        int s = ei[g * EPG + tid] & 63;
        int d = ei[E + g * EPG + tid] & 63;
        atomicAdd(&sQ[s], sI[s] * sI[d]);
    }
    __syncthreads();
    if (tid < 64) sQ[tid] *= (1.f / 64.f);
    __syncthreads();

    int rc = tid >> 6;        // row chunk (16 rows)
    int c  = tid & 63;
    for (int pass = 0; pass < 2; ++pass) {
        int cg = c + pass * 64;
        if (cg >= 76) break;
        float av[8] = {};
        for (int s = rc * 16; s < rc * 16 + 16; ++s) {
            float qs = sQ[s];
            bf16x8 xv = *(const bf16x8*)((const __bf16*)X
                          + (size_t)(g * 64 + s) * FP + cg * 8);
            #pragma unroll
            for (int k = 0; k < 8; ++k) av[k] += qs * (float)xv[k];
        }
        #pragma unroll
        for (int k = 0; k < 8; ++k) Yp[rc][cg][k] = av[k];
    }
    __syncthreads();
    for (int cc = tid; cc < FP; cc += 256) {
        float tot = Yp[0][cc >> 3][cc & 7] + Yp[1][cc >> 3][cc & 7]
                  + Yp[2][cc >> 3][cc & 7] + Yp[3][cc >> 3][cc & 7];
        Y[(size_t)g * FP + cc] = __float2bfloat16(tot);
    }
}

// ===========================================================================
// Batched weight convert+transpose+pad: dst[n][k] = src[k][n] (fp32->bf16)
// ===========================================================================
struct WtJob  { const float* src; bf16* dst; int Ksrc, Nsrc, Kp, Np; };
struct WtJobs { WtJob j[9]; };

__global__ __launch_bounds__(256) void k_wt_all(WtJobs jobs)
{
    WtJob jb = jobs.j[blockIdx.y];
    int total = jb.Np * jb.Kp;
    for (int idx = blockIdx.x * 256 + threadIdx.x; idx < total; idx += gridDim.x * 256) {
        int n = idx / jb.Kp, k = idx - n * jb.Kp;
        float v = (n < jb.Nsrc && k < jb.Ksrc) ? jb.src[(size_t)k * jb.Nsrc + n] : 0.f;
        jb.dst[idx] = __float2bfloat16(v);
    }
}

// ---------------------------------------------------------------------------
__global__ void k_te(const float* __restrict__ ts, bf16* __restrict__ TE)
{
    int idx = blockIdx.x * 256 + threadIdx.x;
    if (idx >= B * 128) return;
    int b = idx >> 7, j = idx & 127;
    float t = ts[b];
    int h = j & 63;
    float freq = expf(-9.210340371976184f * (float)h / 64.f);  // ln(10000)
    float a = t * freq;
    TE[idx] = __float2bfloat16((j < 64) ? cosf(a) : sinf(a));
}

__global__ __launch_bounds__(256) void k_deg(const int* __restrict__ ei,
                                             float* __restrict__ invdeg,
                                             float* __restrict__ isq)
{
    int g = blockIdx.x;
    int tid = threadIdx.x;
    __shared__ int cnt[64];
    if (tid < 64) cnt[tid] = 0;
    __syncthreads();
    for (int e = tid; e < EPG; e += 256)
        atomicAdd(&cnt[ei[E + g * EPG + e] & 63], 1);
    __syncthreads();
    if (tid < 64) {
        float d = (float)cnt[tid] + 1.0f;
        invdeg[g * 64 + tid] = 1.f / d;
        isq[g * 64 + tid] = rsqrtf(d);
    }
}

// ===========================================================================
// Node transform, per-graph block: X[n][c<300] = (x@W_tr + b)*mask, pads 0.
// W_tr staged once per block in LDS.
// ===========================================================================
__global__ __launch_bounds__(256) void k_xtr(const float* __restrict__ xin,
                                             const float* __restrict__ Wtr,
                                             const float* __restrict__ btr,
                                             const float* __restrict__ mask,
                                             bf16* __restrict__ X)
{
    __shared__ float Ws[19 * 304];
    __shared__ float xb[64 * 20];
    __shared__ float sb[304];
    __shared__ float sm[64];

    int g   = blockIdx.x;
    int tid = threadIdx.x;

    for (int idx = tid; idx < 19 * 304; idx += 256) {
        int k = idx / 304, c = idx - k * 304;
        Ws[idx] = (c < 300) ? Wtr[k * 300 + c] : 0.f;
    }
    for (int idx = tid; idx < 64 * 19; idx += 256) {
        int n = idx / 19, k = idx - n * 19;
        xb[n * 20 + k] = xin[(size_t)(g * 64 + n) * 19 + k];
    }
    for (int c = tid; c < 304; c += 256)           // FIX: was `if (tid < 304)` with 256 threads
        sb[c] = (c < 300) ? btr[c] : 0.f;
    if (tid < 64)  sm[tid] = mask[g * 64 + tid];
    __syncthreads();

    int n  = tid >> 2;
    int c0 = tid & 3;
    float m = sm[n];
    for (int c = c0; c < 304; c += 4) {
        float acc = sb[c];
        #pragma unroll
        for (int k = 0; k < 19; ++k)
            acc += xb[n * 20 + k] * Ws[k * 304 + c];
        X[(size_t)(g * 64 + n) * FP + c] = __float2bfloat16(acc * m);
    }
    // zero cols 304..607 (16B vector stores)
    bf16x8 z = {};
    for (int idx = tid; idx < 64 * 38; idx += 256) {
        int nn = idx / 38, j = idx - nn * 38;
        *(bf16x8*)((__bf16*)X + (size_t)(g * 64 + nn) * FP + 304 + j * 8) = z;
    }
}

// LayerNorm over 300 dims + affine, fp32 out
__global__ __launch_bounds__(256) void k_ln(const float* __restrict__ G,
                                            const float* __restrict__ lg,
                                            const float* __restrict__ lb,
                                            float* __restrict__ out)
{
    int r = blockIdx.x;
    int tid = threadIdx.x;
    __shared__ float red[4];
    __shared__ float smu, svar;

    float v0 = (tid < 300) ? G[r * 300 + tid] : 0.f;
    float v1 = (tid + 256 < 300) ? G[r * 300 + tid + 256] : 0.f;
    float s = v0 + v1;
    #pragma unroll
    for (int o = 32; o > 0; o >>= 1) s += __shfl_down(s, o, 64);
    if ((tid & 63) == 0) red[tid >> 6] = s;
    __syncthreads();
    if (tid == 0) smu = (red[0] + red[1] + red[2] + red[3]) * (1.f / 300.f);
    __syncthreads();
    float mu = smu;
    float d0 = (tid < 300) ? v0 - mu : 0.f;
    float d1 = (tid + 256 < 300) ? v1 - mu : 0.f;
    s = d0 * d0 + d1 * d1;
    #pragma unroll
    for (int o = 32; o > 0; o >>= 1) s += __shfl_down(s, o, 64);
    if ((tid & 63) == 0) red[tid >> 6] = s;
    __syncthreads();
    if (tid == 0) svar = (red[0] + red[1] + red[2] + red[3]) * (1.f / 300.f);
    __syncthreads();
    float rstd = rsqrtf(svar + 1e-5f);
    if (tid < 300)
        out[r * 300 + tid] = d0 * rstd * lg[tid] + lb[tid];
    if (tid + 256 < 300)
        out[r * 300 + tid + 256] = d1 * rstd * lg[tid + 256] + lb[tid + 256];
}

__global__ void k_copy(const uint4* __restrict__ src, uint4* __restrict__ dst, int n)
{
    int i = blockIdx.x * 256 + threadIdx.x;
    if (i < n) dst[i] = src[i];
}

// ---------------------------------------------------------------------------
extern "C" void kernel_launch(void* const* d_in, const int* in_sizes, int n_in,
                              void* d_out, int out_size, void* d_ws, size_t ws_size,
                              hipStream_t stream)
{
    const float* x_in  = (const float*)d_in[0];
    const int*   ei    = (const int*)d_in[1];
    const float* text  = (const float*)d_in[3];
    const float* tst   = (const float*)d_in[4];
    const float* mask  = (const float*)d_in[5];
    const float* W_tr  = (const float*)d_in[6];
    const float* b_tr  = (const float*)d_in[7];
    const float* W_c1  = (const float*)d_in[8];
    const float* b_c1  = (const float*)d_in[9];
    const float* W_c2  = (const float*)d_in[10];
    const float* b_c2  = (const float*)d_in[11];
    const float* W_c3  = (const float*)d_in[12];
    const float* b_c3  = (const float*)d_in[13];
    const float* W_h1  = (const float*)d_in[14];
    const float* b_h1  = (const float*)d_in[15];
    const float* W_h2  = (const float*)d_in[16];
    const float* b_h2  = (const float*)d_in[17];
    const float* W_h3  = (const float*)d_in[18];
    const float* b_h3  = (const float*)d_in[19];
    const float* ln_g  = (const float*)d_in[20];
    const float* ln_b  = (const float*)d_in[21];
    const float* W_t1  = (const float*)d_in[22];
    const float* b_t1  = (const float*)d_in[23];
    const float* W_t2  = (const float*)d_in[24];
    const float* b_t2  = (const float*)d_in[25];
    const float* W_e   = (const float*)d_in[26];
    const float* b_e   = (const float*)d_in[27];

    // workspace carve (256B aligned)
    char* w = (char*)d_ws;
    size_t off = 0;
    auto carve = [&](size_t bytes) {
        void* p = w + off;
        off += (bytes + 255) & ~(size_t)255;
        return p;
    };
    bf16*  XA     = (bf16*) carve((size_t)BN * FP * 2);      // 79.7 MB
    bf16*  Wb1    = (bf16*) carve((size_t)640 * 320 * 2);
    bf16*  Wb2    = (bf16*) carve((size_t)640 * FP * 2);
    bf16*  Wb3    = (bf16*) carve((size_t)640 * FP * 2);
    bf16*  Wt1t   = (bf16*) carve((size_t)512 * 128 * 2);
    bf16*  Wt2t   = (bf16*) carve((size_t)512 * 512 * 2);
    bf16*  Wet    = (bf16*) carve((size_t)3072 * 512 * 2);
    bf16*  Wh1t   = (bf16*) carve((size_t)640 * FP * 2);
    bf16*  Wh2t   = (bf16*) carve((size_t)640 * FP * 2);
    bf16*  Wh3t   = (bf16*) carve((size_t)384 * FP * 2);
    bf16*  TE     = (bf16*) carve((size_t)B * 128 * 2);
    bf16*  A1b    = (bf16*) carve((size_t)B * 512 * 2);
    bf16*  A2b    = (bf16*) carve((size_t)B * 512 * 2);
    bf16*  EO     = (bf16*) carve((size_t)B * 3000 * 2);
    bf16*  Yv     = (bf16*) carve((size_t)B * FP * 2);
    bf16*  G0     = (bf16*) carve((size_t)B * FP * 2);
    bf16*  G1     = (bf16*) carve((size_t)B * FP * 2);
    bf16*  G2     = (bf16*) carve((size_t)B * FP * 2);
    float* G3     = (float*)carve((size_t)B * 300 * 4);
    float* invdeg = (float*)carve((size_t)BN * 4);
    float* isq    = (float*)carve((size_t)BN * 4);
    (void)ws_size; (void)in_sizes; (void)n_in; (void)out_size;

    float* out = (float*)d_out;

    // --- all weight transposes/conversions in one dispatch ---
    WtJobs jobs = {{
        { W_c1, Wb1,  300, 600, 320, 640 },
        { W_c2, Wb2,  600, 600, FP,  640 },
        { W_c3, Wb3,  600, 600, FP,  640 },
        { W_t1, Wt1t, 128, 512, 128, 512 },
        { W_t2, Wt2t, 512, 512, 512, 512 },
        { W_e,  Wet,  512, 3000, 512, 3072 },
        { W_h1, Wh1t, 600, 600, FP,  640 },
        { W_h2, Wh2t, 600, 600, FP,  640 },
        { W_h3, Wh3t, 600, 300, FP,  384 },
    }};
    k_wt_all<<<dim3(1024, 9), 256, 0, stream>>>(jobs);

    // --- timestep embedding MLP (all MFMA) ---
    k_te<<<(B * 128 + 255) / 256, 256, 0, stream>>>(tst, TE);
    gemm_ep<true, false, bf16><<<dim3(8, 4), 256, 0, stream>>>(
        TE, 128, Wt1t, 128, b_t1, A1b, 512, 512, nullptr, nullptr, 0, 128);
    gemm_ep<true, false, bf16><<<dim3(8, 4), 256, 0, stream>>>(
        A1b, 512, Wt2t, 512, b_t2, A2b, 512, 512, nullptr, nullptr, 0, 512);
    gemm_ep<false, false, bf16><<<dim3(8, 24), 256, 0, stream>>>(
        A2b, 512, Wet, 512, b_e, EO, 3000, 3000, nullptr, nullptr, 0, 512);

    // --- graph path ---
    k_deg<<<B, 256, 0, stream>>>(ei, invdeg, isq);
    k_xtr<<<B, 256, 0, stream>>>(x_in, W_tr, b_tr, mask, XA);

    // conv1 (K=320) and conv2 (K=608), fused MFMA aggregation, XCD-swizzled
    conv_fused<<<2560, 256, 0, stream>>>(XA, FP, 320, Wb1, 320,
        ei, invdeg, isq, b_c1, XA);
    conv_fused<<<2560, 256, 0, stream>>>(XA, FP, FP, Wb2, FP,
        ei, invdeg, isq, b_c2, XA);

    // conv3+pool collapsed: Y = q @ X, then G0 = Y @ W3^T + b_c3
    k_qx<<<B, 256, 0, stream>>>(XA, ei, invdeg, isq, Yv);
    gemm_ep<false, false, bf16><<<dim3(8, 5), 256, 0, stream>>>(
        Yv, FP, Wb3, FP, b_c3, G0, FP, 600, nullptr, nullptr, 0, FP);

    // --- h-layers with FiLM (MFMA) ---
    gemm_ep<true, true, bf16><<<dim3(8, 5), 256, 0, stream>>>(
        G0, FP, Wh1t, FP, b_h1, G1, FP, 600, EO + 0, EO + 600, 3000, FP);
    gemm_ep<true, true, bf16><<<dim3(8, 5), 256, 0, stream>>>(
        G1, FP, Wh2t, FP, b_h2, G2, FP, 600, EO + 1200, EO + 1800, 3000, FP);
    gemm_ep<false, true, float><<<dim3(8, 3), 256, 0, stream>>>(
        G2, FP, Wh3t, FP, b_h3, G3, 300, 300, EO + 2400, EO + 2700, 3000, FP);

    // layer norm -> out[0 : 307200]
    k_ln<<<B, 256, 0, stream>>>(G3, ln_g, ln_b, out);

    // text passthrough -> out[307200 : 614400]
    k_copy<<<(B * 300 * 4 / 16 + 255) / 256, 256, 0, stream>>>(
        (const uint4*)text, (uint4*)(out + (size_t)B * 300), B * 300 * 4 / 16);
}

// Round 7
// 475.850 us; speedup vs baseline: 7.3109x; 1.1148x over previous
//
#include <hip/hip_runtime.h>
#include <hip/hip_bf16.h>
#include <cstdint>
#include <cstddef>

// Problem constants
static constexpr int B   = 1024;
static constexpr int N   = 64;
static constexpr int BN  = B * N;      // 65536 nodes
static constexpr int EPG = 192;
static constexpr int E   = B * EPG;    // 196608 edges
static constexpr int FP  = 608;        // padded feature dim (mult of 32)
static constexpr int PMS = 80;         // Pm row stride (bf16); 128*80*2 = 20480 B

typedef __hip_bfloat16 bf16;
typedef __bf16 bf16x8 __attribute__((ext_vector_type(8)));
typedef __bf16 bf16x4 __attribute__((ext_vector_type(4)));
typedef float  f32x4  __attribute__((ext_vector_type(4)));

__device__ __forceinline__ void storeC(float* p, float v) { *p = v; }
__device__ __forceinline__ void storeC(bf16* p, float v) { *p = __float2bfloat16(v); }

// async global->LDS, 16B per lane; LDS dest is wave-uniform base + lane*16
__device__ __forceinline__ void llds16(const void* g, void* l) {
    __builtin_amdgcn_global_load_lds(
        (const __attribute__((address_space(1))) unsigned int*)g,
        (__attribute__((address_space(3))) unsigned int*)l,
        16, 0, 0);
}

// ===========================================================================
// MFMA GEMM with bias/ReLU/FiLM epilogue.
// C[M x Ncap] = A[M x K] @ Bt^T (+bias)(relu)(film).  Bt is Np x K rows.
// ===========================================================================
template<bool RELU, bool FILM, typename CT>
__global__ __launch_bounds__(256) void gemm_ep(
    const bf16* __restrict__ A, int lda,
    const bf16* __restrict__ Bt, int ldb,
    const float* __restrict__ bias,
    CT* __restrict__ C, int ldc, int Ncap,
    const bf16* __restrict__ fS, const bf16* __restrict__ fT, int fstride,
    int K)
{
    __shared__ __align__(16) __bf16 As[128 * 32];
    __shared__ __align__(16) __bf16 Bs[128 * 32];

    const int tid  = threadIdx.x;
    const int lane = tid & 63;
    const int w    = tid >> 6;
    const int wm   = (w & 1) * 64;
    const int wn   = (w >> 1) * 64;
    const int m0   = blockIdx.x * 128;
    const int n0   = blockIdx.y * 128;
    const int l15  = lane & 15;
    const int lhi  = lane >> 4;

    f32x4 acc[4][4] = {};

    for (int k0 = 0; k0 < K; k0 += 32) {
        #pragma unroll
        for (int t = 0; t < 2; ++t) {
            int ci  = t * 256 + w * 64 + lane;
            int row = ci >> 2, kc = ci & 3;
            char* la = (char*)As + (size_t)(t * 256 + w * 64) * 16;
            char* lb = (char*)Bs + (size_t)(t * 256 + w * 64) * 16;
            llds16(A  + (size_t)(m0 + row) * lda + k0 + kc * 8, la);
            llds16(Bt + (size_t)(n0 + row) * ldb + k0 + kc * 8, lb);
        }
        asm volatile("s_waitcnt vmcnt(0)" ::: "memory");
        __syncthreads();

        bf16x8 af[4], bg[4];
        #pragma unroll
        for (int i = 0; i < 4; ++i)
            af[i] = *(bf16x8*)(As + (wm + i * 16 + l15) * 32 + lhi * 8);
        #pragma unroll
        for (int j = 0; j < 4; ++j)
            bg[j] = *(bf16x8*)(Bs + (wn + j * 16 + l15) * 32 + lhi * 8);
        #pragma unroll
        for (int i = 0; i < 4; ++i)
            #pragma unroll
            for (int j = 0; j < 4; ++j)
                acc[i][j] = __builtin_amdgcn_mfma_f32_16x16x32_bf16(
                    af[i], bg[j], acc[i][j], 0, 0, 0);
        __syncthreads();
    }

    #pragma unroll
    for (int i = 0; i < 4; ++i) {
        #pragma unroll
        for (int j = 0; j < 4; ++j) {
            int col = n0 + wn + j * 16 + l15;
            if (col < Ncap) {
                float bv = bias ? bias[col] : 0.f;
                #pragma unroll
                for (int e = 0; e < 4; ++e) {
                    int row = m0 + wm + i * 16 + lhi * 4 + e;
                    float v = acc[i][j][e] + bv;
                    if (RELU) v = fmaxf(v, 0.f);
                    if (FILM) {
                        float sv = __bfloat162float(fS[(size_t)row * fstride + col]);
                        float tv = __bfloat162float(fT[(size_t)row * fstride + col]);
                        v = v * (1.f + sv) + tv;
                    }
                    storeC(&C[(size_t)row * ldc + col], v);
                }
            }
        }
    }
}

// ===========================================================================
// Fused GCN conv (conv1/conv2): block = 128 node-rows (pair mt) x 128 H-cols.
// H = A @ Bt^T via MFMA; out = P @ H via MFMA, P staged from precomputed Pmg.
// ReLU+bias fused.  Grid: 2560 1-D, XCD-swizzled.
// ===========================================================================
__global__ __launch_bounds__(256) void conv_fused(
    const bf16* __restrict__ A, int lda, int K,
    const bf16* __restrict__ Bt, int ldb,
    const bf16* __restrict__ Pmg,
    const float* __restrict__ bias,
    bf16* __restrict__ Xout)
{
    // region A (17408 B): As(8K)+Bs(8K) during K-loop -> Ts[64][136] bf16 after
    __shared__ __align__(16) char regA[17408];
    __shared__ __align__(16) __bf16 Pm[128 * PMS];   // 20480 B

    __bf16* As = (__bf16*)regA;
    __bf16* Bs = (__bf16*)(regA + 8192);
    __bf16* Ts = (__bf16*)regA;

    const int tid  = threadIdx.x;
    const int lane = tid & 63;
    const int w    = tid >> 6;
    const int wm   = (w & 1) * 64;
    const int wn   = (w >> 1) * 64;
    const int l15  = lane & 15;
    const int lhi  = lane >> 4;

    // XCD-aware decode: 2560 blocks = 8 XCDs x (64 m-tiles x 5 n-tiles)
    const int bid = blockIdx.x;
    const int lid = bid >> 3;              // 0..319
    const int mt  = (bid & 7) * 64 + lid / 5;   // pair index 0..511
    const int nt  = lid % 5;
    const int m0  = mt * 128;
    const int n0  = nt * 128;

    // ---- stage Pm (precomputed): 1280 16B-chunks, 5 per lane ----
    #pragma unroll
    for (int i = 0; i < 5; ++i) {
        int cbase = w * 320 + i * 64;      // wave-uniform chunk base
        llds16(Pmg + (size_t)mt * (128 * PMS) + (size_t)(cbase + lane) * 8,
               (char*)Pm + (size_t)cbase * 16);
    }
    // completion covered by the first K-iteration's vmcnt(0)+barrier

    // ---- MFMA main loop ----
    f32x4 acc[4][4] = {};
    for (int k0 = 0; k0 < K; k0 += 32) {
        #pragma unroll
        for (int t = 0; t < 2; ++t) {
            int ci  = t * 256 + w * 64 + lane;
            int row = ci >> 2, kc = ci & 3;
            char* la = (char*)As + (size_t)(t * 256 + w * 64) * 16;
            char* lb = (char*)Bs + (size_t)(t * 256 + w * 64) * 16;
            llds16(A  + (size_t)(m0 + row) * lda + k0 + kc * 8, la);
            llds16(Bt + (size_t)(n0 + row) * ldb + k0 + kc * 8, lb);
        }
        asm volatile("s_waitcnt vmcnt(0)" ::: "memory");
        __syncthreads();

        bf16x8 af[4], bg[4];
        #pragma unroll
        for (int i = 0; i < 4; ++i)
            af[i] = *(bf16x8*)(As + (wm + i * 16 + l15) * 32 + lhi * 8);
        #pragma unroll
        for (int j = 0; j < 4; ++j)
            bg[j] = *(bf16x8*)(Bs + (wn + j * 16 + l15) * 32 + lhi * 8);
        #pragma unroll
        for (int i = 0; i < 4; ++i)
            #pragma unroll
            for (int j = 0; j < 4; ++j)
                acc[i][j] = __builtin_amdgcn_mfma_f32_16x16x32_bf16(
                    af[i], bg[j], acc[i][j], 0, 0, 0);
        __syncthreads();
    }

    // ---- out = P @ H, two 64-col halves (Ts = H^T half) ----
    const int g  = w & 1;        // graph this wave computes in P@H
    const int nb = w >> 1;       // 32-col sub-block
    #pragma unroll
    for (int h = 0; h < 2; ++h) {
        if (wn == h * 64) {
            #pragma unroll
            for (int i = 0; i < 4; ++i)
                #pragma unroll
                for (int j = 0; j < 4; ++j) {
                    int c_local = j * 16 + l15;
                    int rbase   = wm + i * 16 + lhi * 4;
                    bf16x4 pk;
                    #pragma unroll
                    for (int e = 0; e < 4; ++e) pk[e] = (__bf16)acc[i][j][e];
                    *(bf16x4*)(Ts + c_local * 136 + rbase) = pk;
                }
        }
        __syncthreads();

        f32x4 acc2[4][2] = {};
        #pragma unroll
        for (int k0 = 0; k0 < 64; k0 += 32) {
            bf16x8 pa[4], hb[2];
            #pragma unroll
            for (int i = 0; i < 4; ++i)
                pa[i] = *(bf16x8*)(Pm + (g * 64 + i * 16 + l15) * PMS + k0 + lhi * 8);
            #pragma unroll
            for (int j = 0; j < 2; ++j)
                hb[j] = *(bf16x8*)(Ts + (nb * 32 + j * 16 + l15) * 136
                                      + g * 64 + k0 + lhi * 8);
            #pragma unroll
            for (int i = 0; i < 4; ++i)
                #pragma unroll
                for (int j = 0; j < 2; ++j)
                    acc2[i][j] = __builtin_amdgcn_mfma_f32_16x16x32_bf16(
                        pa[i], hb[j], acc2[i][j], 0, 0, 0);
        }
        #pragma unroll
        for (int i = 0; i < 4; ++i)
            #pragma unroll
            for (int j = 0; j < 2; ++j) {
                int col = n0 + h * 64 + nb * 32 + j * 16 + l15;
                if (col < FP) {
                    float bv = (col < 600) ? bias[col] : 0.f;
                    #pragma unroll
                    for (int e = 0; e < 4; ++e) {
                        int row = m0 + g * 64 + i * 16 + lhi * 4 + e;
                        float v = fmaxf(acc2[i][j][e] + bv, 0.f);   // relu
                        Xout[(size_t)row * FP + col] = __float2bfloat16(v);
                    }
                }
            }
        __syncthreads();
    }
}

// ===========================================================================
// Mega prep kernel: [WT transposes | timestep emb | pair prep | node xform]
// ===========================================================================
struct WtJob  { const float* src; bf16* dst; int Ksrc, Nsrc, Kp, Np, blk0; };
struct PrepArgs {
    WtJob j[9];
    int nwt, te0, pp0, xtr0;                 // block-range starts
    const int*   ei;
    const float* ts;
    const float* xin; const float* Wtr; const float* btr; const float* mask;
    bf16* TE; bf16* Pmg; float* qv; bf16* X;
};

__global__ __launch_bounds__(256) void k_prep(PrepArgs a)
{
    __shared__ __align__(16) char sm[35840];
    const int bx  = blockIdx.x;
    const int tid = threadIdx.x;

    if (bx < a.nwt) {
        // ---------- LDS-tiled transpose: dst[n][k] = src[k][n] ----------
        int ji = 0;
        while (ji < 8 && bx >= a.j[ji + 1].blk0) ++ji;
        WtJob jb = a.j[ji];
        int t  = bx - jb.blk0;
        int kt = (jb.Kp + 63) >> 6;
        int ti = t % kt, tj = t / kt;
        int kg0 = ti * 64, ng0 = tj * 64;
        float (*T)[65] = (float(*)[65])sm;
        #pragma unroll 4
        for (int r = 0; r < 16; ++r) {
            int kl = (tid >> 6) + r * 4, nl = tid & 63;
            int kg = kg0 + kl, ng = ng0 + nl;
            T[kl][nl] = (kg < jb.Ksrc && ng < jb.Nsrc)
                        ? jb.src[(size_t)kg * jb.Nsrc + ng] : 0.f;
        }
        __syncthreads();
        #pragma unroll 4
        for (int r = 0; r < 16; ++r) {
            int nl = (tid >> 6) + r * 4, kl = tid & 63;
            int ng = ng0 + nl, kg = kg0 + kl;
            if (ng < jb.Np && kg < jb.Kp)
                jb.dst[(size_t)ng * jb.Kp + kg] = __float2bfloat16(T[kl][nl]);
        }
    } else if (bx < a.pp0) {
        // ---------- timestep embedding ----------
        int idx = (bx - a.te0) * 256 + tid;      // < 131072 exactly
        int b = idx >> 7, jj = idx & 127;
        float tt = a.ts[b];
        int h = jj & 63;
        float freq = expf(-9.210340371976184f * (float)h / 64.f);  // ln(10000)
        float ang = tt * freq;
        a.TE[idx] = __float2bfloat16((jj < 64) ? cosf(ang) : sinf(ang));
    } else if (bx < a.xtr0) {
        // ---------- pair prep: P matrix (bf16, PMS stride) + q vector ----------
        int pr = bx - a.pp0;                     // pair 0..511
        float* Pf   = (float*)sm;                // 128 x 64 fp32 (32768 B)
        int*   cnt  = (int*)(sm + 32768);        // 128
        float* sQ   = (float*)(sm + 33280);      // 128
        float* sI   = (float*)(sm + 33792);      // 128
        float* sIvd = (float*)(sm + 34304);      // 128

        for (int idx = tid; idx < 8192; idx += 256) Pf[idx] = 0.f;
        if (tid < 128) cnt[tid] = 0;
        __syncthreads();
        for (int e = tid; e < 2 * EPG; e += 256) {
            int g  = (e >= EPG);
            int eg = (2 * pr + g) * EPG + (e - g * EPG);
            int ld = (a.ei[E + eg] & 63) + g * 64;
            atomicAdd(&cnt[ld], 1);
        }
        __syncthreads();
        if (tid < 128) {
            float d = (float)cnt[tid] + 1.0f;
            float iv = 1.f / d;
            sIvd[tid] = iv;
            sI[tid]   = rsqrtf(d);
            sQ[tid]   = iv;
        }
        __syncthreads();
        for (int e = tid; e < 2 * EPG; e += 256) {
            int g   = (e >= EPG);
            int eg  = (2 * pr + g) * EPG + (e - g * EPG);
            int lsl = a.ei[eg] & 63;
            int ldl = a.ei[E + eg] & 63;
            float cf = sI[g * 64 + lsl] * sI[g * 64 + ldl];
            atomicAdd(&Pf[(g * 64 + ldl) * 64 + lsl], cf);
            atomicAdd(&sQ[g * 64 + lsl], cf);
        }
        __syncthreads();
        if (tid < 128) {
            Pf[tid * 64 + (tid & 63)] += sIvd[tid];
            a.qv[pr * 128 + tid] = sQ[tid] * (1.f / 64.f);
        }
        __syncthreads();
        for (int idx = tid; idx < 128 * PMS; idx += 256) {
            int r = idx / PMS, k = idx - r * PMS;
            float v = (k < 64) ? Pf[r * 64 + k] : 0.f;
            a.Pmg[(size_t)pr * (128 * PMS) + idx] = __float2bfloat16(v);
        }
    } else {
        // ---------- node transform (per graph) ----------
        int g = bx - a.xtr0;
        float* Ws = (float*)sm;                  // 19*304 (23104 B)
        float* xb = (float*)(sm + 23104);        // 64*20
        float* sb = (float*)(sm + 28224);        // 304
        float* smk= (float*)(sm + 29440);        // 64

        for (int idx = tid; idx < 19 * 304; idx += 256) {
            int k = idx / 304, c = idx - k * 304;
            Ws[idx] = (c < 300) ? a.Wtr[k * 300 + c] : 0.f;
        }
        for (int idx = tid; idx < 64 * 19; idx += 256) {
            int n = idx / 19, k = idx - n * 19;
            xb[n * 20 + k] = a.xin[(size_t)(g * 64 + n) * 19 + k];
        }
        for (int c = tid; c < 304; c += 256)
            sb[c] = (c < 300) ? a.btr[c] : 0.f;
        if (tid < 64) smk[tid] = a.mask[g * 64 + tid];
        __syncthreads();

        int n  = tid >> 2;
        int c0 = tid & 3;
        float m = smk[n];
        for (int c = c0; c < 304; c += 4) {
            float acc = sb[c];
            #pragma unroll
            for (int k = 0; k < 19; ++k)
                acc += xb[n * 20 + k] * Ws[k * 304 + c];
            a.X[(size_t)(g * 64 + n) * FP + c] = __float2bfloat16(acc * m);
        }
        bf16x8 z = {};
        for (int idx = tid; idx < 64 * 38; idx += 256) {
            int nn = idx / 38, jv = idx - nn * 38;
            *(bf16x8*)((__bf16*)a.X + (size_t)(g * 64 + nn) * FP + 304 + jv * 8) = z;
        }
    }
}

// ===========================================================================
// conv3+pool collapsed: Y[g] = q_g @ X_g (q precomputed in k_prep)
// ===========================================================================
__global__ __launch_bounds__(256) void k_qx(const bf16* __restrict__ X,
                                            const float* __restrict__ qv,
                                            bf16* __restrict__ Y)
{
    __shared__ float sQ[64];
    __shared__ float Yp[4][76][8];

    int g   = blockIdx.x;
    int tid = threadIdx.x;

    if (tid < 64) sQ[tid] = qv[g * 64 + tid];
    __syncthreads();

    int rc = tid >> 6;        // row chunk (16 rows)
    int c  = tid & 63;
    for (int pass = 0; pass < 2; ++pass) {
        int cg = c + pass * 64;
        if (cg >= 76) break;
        float av[8] = {};
        for (int s = rc * 16; s < rc * 16 + 16; ++s) {
            float qs = sQ[s];
            bf16x8 xv = *(const bf16x8*)((const __bf16*)X
                          + (size_t)(g * 64 + s) * FP + cg * 8);
            #pragma unroll
            for (int k = 0; k < 8; ++k) av[k] += qs * (float)xv[k];
        }
        #pragma unroll
        for (int k = 0; k < 8; ++k) Yp[rc][cg][k] = av[k];
    }
    __syncthreads();
    for (int cc = tid; cc < FP; cc += 256) {
        float tot = Yp[0][cc >> 3][cc & 7] + Yp[1][cc >> 3][cc & 7]
                  + Yp[2][cc >> 3][cc & 7] + Yp[3][cc >> 3][cc & 7];
        Y[(size_t)g * FP + cc] = __float2bfloat16(tot);
    }
}

// LayerNorm over 300 dims + affine, fp32 out; fused text passthrough copy
__global__ __launch_bounds__(256) void k_ln_copy(const float* __restrict__ G,
                                                 const float* __restrict__ lg,
                                                 const float* __restrict__ lb,
                                                 const float* __restrict__ text,
                                                 float* __restrict__ out)
{
    int r = blockIdx.x;
    int tid = threadIdx.x;
    __shared__ float red[4];
    __shared__ float smu, svar;

    float v0 = (tid < 300) ? G[r * 300 + tid] : 0.f;
    float v1 = (tid + 256 < 300) ? G[r * 300 + tid + 256] : 0.f;
    float s = v0 + v1;
    #pragma unroll
    for (int o = 32; o > 0; o >>= 1) s += __shfl_down(s, o, 64);
    if ((tid & 63) == 0) red[tid >> 6] = s;
    __syncthreads();
    if (tid == 0) smu = (red[0] + red[1] + red[2] + red[3]) * (1.f / 300.f);
    __syncthreads();
    float mu = smu;
    float d0 = (tid < 300) ? v0 - mu : 0.f;
    float d1 = (tid + 256 < 300) ? v1 - mu : 0.f;
    s = d0 * d0 + d1 * d1;
    #pragma unroll
    for (int o = 32; o > 0; o >>= 1) s += __shfl_down(s, o, 64);
    if ((tid & 63) == 0) red[tid >> 6] = s;
    __syncthreads();
    if (tid == 0) svar = (red[0] + red[1] + red[2] + red[3]) * (1.f / 300.f);
    __syncthreads();
    float rstd = rsqrtf(svar + 1e-5f);
    if (tid < 300)
        out[r * 300 + tid] = d0 * rstd * lg[tid] + lb[tid];
    if (tid + 256 < 300)
        out[r * 300 + tid + 256] = d1 * rstd * lg[tid + 256] + lb[tid + 256];
    // text passthrough
    float* o2 = out + (size_t)B * 300;
    for (int c = tid; c < 300; c += 256)
        o2[(size_t)r * 300 + c] = text[(size_t)r * 300 + c];
}

// ---------------------------------------------------------------------------
extern "C" void kernel_launch(void* const* d_in, const int* in_sizes, int n_in,
                              void* d_out, int out_size, void* d_ws, size_t ws_size,
                              hipStream_t stream)
{
    const float* x_in  = (const float*)d_in[0];
    const int*   ei    = (const int*)d_in[1];
    const float* text  = (const float*)d_in[3];
    const float* tst   = (const float*)d_in[4];
    const float* mask  = (const float*)d_in[5];
    const float* W_tr  = (const float*)d_in[6];
    const float* b_tr  = (const float*)d_in[7];
    const float* W_c1  = (const float*)d_in[8];
    const float* b_c1  = (const float*)d_in[9];
    const float* W_c2  = (const float*)d_in[10];
    const float* b_c2  = (const float*)d_in[11];
    const float* W_c3  = (const float*)d_in[12];
    const float* b_c3  = (const float*)d_in[13];
    const float* W_h1  = (const float*)d_in[14];
    const float* b_h1  = (const float*)d_in[15];
    const float* W_h2  = (const float*)d_in[16];
    const float* b_h2  = (const float*)d_in[17];
    const float* W_h3  = (const float*)d_in[18];
    const float* b_h3  = (const float*)d_in[19];
    const float* ln_g  = (const float*)d_in[20];
    const float* ln_b  = (const float*)d_in[21];
    const float* W_t1  = (const float*)d_in[22];
    const float* b_t1  = (const float*)d_in[23];
    const float* W_t2  = (const float*)d_in[24];
    const float* b_t2  = (const float*)d_in[25];
    const float* W_e   = (const float*)d_in[26];
    const float* b_e   = (const float*)d_in[27];

    // workspace carve (256B aligned) — ~110 MB total
    char* w = (char*)d_ws;
    size_t off = 0;
    auto carve = [&](size_t bytes) {
        void* p = w + off;
        off += (bytes + 255) & ~(size_t)255;
        return p;
    };
    bf16*  XA     = (bf16*) carve((size_t)BN * FP * 2);      // 79.7 MB
    bf16*  Wb1    = (bf16*) carve((size_t)640 * 320 * 2);
    bf16*  Wb2    = (bf16*) carve((size_t)640 * FP * 2);
    bf16*  Wb3    = (bf16*) carve((size_t)640 * FP * 2);
    bf16*  Wt1t   = (bf16*) carve((size_t)512 * 128 * 2);
    bf16*  Wt2t   = (bf16*) carve((size_t)512 * 512 * 2);
    bf16*  Wet    = (bf16*) carve((size_t)3072 * 512 * 2);
    bf16*  Wh1t   = (bf16*) carve((size_t)640 * FP * 2);
    bf16*  Wh2t   = (bf16*) carve((size_t)640 * FP * 2);
    bf16*  Wh3t   = (bf16*) carve((size_t)384 * FP * 2);
    bf16*  TE     = (bf16*) carve((size_t)B * 128 * 2);
    bf16*  A1b    = (bf16*) carve((size_t)B * 512 * 2);
    bf16*  A2b    = (bf16*) carve((size_t)B * 512 * 2);
    bf16*  EO     = (bf16*) carve((size_t)B * 3000 * 2);
    bf16*  Yv     = (bf16*) carve((size_t)B * FP * 2);
    bf16*  G0     = (bf16*) carve((size_t)B * FP * 2);
    bf16*  G1     = (bf16*) carve((size_t)B * FP * 2);
    bf16*  G2     = (bf16*) carve((size_t)B * FP * 2);
    float* G3     = (float*)carve((size_t)B * 300 * 4);
    bf16*  Pmg    = (bf16*) carve((size_t)512 * 128 * PMS * 2);  // 10.5 MB
    float* qv     = (float*)carve((size_t)BN * 4);
    (void)ws_size; (void)in_sizes; (void)n_in; (void)out_size;

    float* out = (float*)d_out;

    // --- phase A: one mega prep launch ---
    PrepArgs pa;
    struct JD { const float* s; bf16* d; int Ks, Ns, Kp, Np; };
    JD jd[9] = {
        { W_c1, Wb1,  300, 600,  320, 640 },
        { W_c2, Wb2,  600, 600,  FP,  640 },
        { W_c3, Wb3,  600, 600,  FP,  640 },
        { W_t1, Wt1t, 128, 512,  128, 512 },
        { W_t2, Wt2t, 512, 512,  512, 512 },
        { W_e,  Wet,  512, 3000, 512, 3072 },
        { W_h1, Wh1t, 600, 600,  FP,  640 },
        { W_h2, Wh2t, 600, 600,  FP,  640 },
        { W_h3, Wh3t, 600, 300,  FP,  384 },
    };
    int cum = 0;
    for (int i = 0; i < 9; ++i) {
        int kt = (jd[i].Kp + 63) >> 6, nt = (jd[i].Np + 63) >> 6;
        pa.j[i] = { jd[i].s, jd[i].d, jd[i].Ks, jd[i].Ns, jd[i].Kp, jd[i].Np, cum };
        cum += kt * nt;
    }
    pa.nwt  = cum;                 // 974
    pa.te0  = cum;       cum += (B * 128) / 256;    // 512 blocks
    pa.pp0  = cum;       cum += B / 2;              // 512 pair blocks
    pa.xtr0 = cum;       cum += B;                  // 1024 xtr blocks
    pa.ei = ei; pa.ts = tst;
    pa.xin = x_in; pa.Wtr = W_tr; pa.btr = b_tr; pa.mask = mask;
    pa.TE = TE; pa.Pmg = Pmg; pa.qv = qv; pa.X = XA;
    k_prep<<<cum, 256, 0, stream>>>(pa);

    // --- timestep embedding MLP (MFMA) ---
    gemm_ep<true, false, bf16><<<dim3(8, 4), 256, 0, stream>>>(
        TE, 128, Wt1t, 128, b_t1, A1b, 512, 512, nullptr, nullptr, 0, 128);
    gemm_ep<true, false, bf16><<<dim3(8, 4), 256, 0, stream>>>(
        A1b, 512, Wt2t, 512, b_t2, A2b, 512, 512, nullptr, nullptr, 0, 512);
    gemm_ep<false, false, bf16><<<dim3(8, 24), 256, 0, stream>>>(
        A2b, 512, Wet, 512, b_e, EO, 3000, 3000, nullptr, nullptr, 0, 512);

    // --- conv1 (K=320) and conv2 (K=608), fused MFMA aggregation ---
    conv_fused<<<2560, 256, 0, stream>>>(XA, FP, 320, Wb1, 320, Pmg, b_c1, XA);
    conv_fused<<<2560, 256, 0, stream>>>(XA, FP, FP,  Wb2, FP,  Pmg, b_c2, XA);

    // --- conv3+pool collapsed: Y = q @ X, then G0 = Y @ W3^T + b_c3 ---
    k_qx<<<B, 256, 0, stream>>>(XA, qv, Yv);
    gemm_ep<false, false, bf16><<<dim3(8, 5), 256, 0, stream>>>(
        Yv, FP, Wb3, FP, b_c3, G0, FP, 600, nullptr, nullptr, 0, FP);

    // --- h-layers with FiLM (MFMA) ---
    gemm_ep<true, true, bf16><<<dim3(8, 5), 256, 0, stream>>>(
        G0, FP, Wh1t, FP, b_h1, G1, FP, 600, EO + 0, EO + 600, 3000, FP);
    gemm_ep<true, true, bf16><<<dim3(8, 5), 256, 0, stream>>>(
        G1, FP, Wh2t, FP, b_h2, G2, FP, 600, EO + 1200, EO + 1800, 3000, FP);
    gemm_ep<false, true, float><<<dim3(8, 3), 256, 0, stream>>>(
        G2, FP, Wh3t, FP, b_h3, G3, 300, 300, EO + 2400, EO + 2700, 3000, FP);

    // --- layer norm + text passthrough ---
    k_ln_copy<<<B, 256, 0, stream>>>(G3, ln_g, ln_b, text, out);
}

// Round 8
// 446.966 us; speedup vs baseline: 7.7834x; 1.0646x over previous
//
#include <hip/hip_runtime.h>
#include <hip/hip_bf16.h>
#include <cstdint>
#include <cstddef>

// Problem constants
static constexpr int B   = 1024;
static constexpr int N   = 64;
static constexpr int BN  = B * N;      // 65536 nodes
static constexpr int EPG = 192;
static constexpr int E   = B * EPG;    // 196608 edges
static constexpr int FP  = 608;        // padded feature dim (mult of 32)
static constexpr int PMS = 80;         // Pm row stride (bf16); 128*80*2 = 20480 B

typedef __hip_bfloat16 bf16;
typedef __bf16 bf16x8 __attribute__((ext_vector_type(8)));
typedef __bf16 bf16x4 __attribute__((ext_vector_type(4)));
typedef float  f32x4  __attribute__((ext_vector_type(4)));

__device__ __forceinline__ void storeC(float* p, float v) { *p = v; }
__device__ __forceinline__ void storeC(bf16* p, float v) { *p = __float2bfloat16(v); }

// async global->LDS, 16B per lane; LDS dest is wave-uniform base + lane*16
__device__ __forceinline__ void llds16(const void* g, void* l) {
    __builtin_amdgcn_global_load_lds(
        (const __attribute__((address_space(1))) unsigned int*)g,
        (__attribute__((address_space(3))) unsigned int*)l,
        16, 0, 0);
}

// ===========================================================================
// MFMA GEMM with bias/ReLU/FiLM epilogue.
// C[M x Ncap] = A[M x K] @ Bt^T (+bias)(relu)(film).  Bt is Np x K rows.
// ===========================================================================
template<bool RELU, bool FILM, typename CT>
__global__ __launch_bounds__(256) void gemm_ep(
    const bf16* __restrict__ A, int lda,
    const bf16* __restrict__ Bt, int ldb,
    const float* __restrict__ bias,
    CT* __restrict__ C, int ldc, int Ncap,
    const bf16* __restrict__ fS, const bf16* __restrict__ fT, int fstride,
    int K)
{
    __shared__ __align__(16) __bf16 As[128 * 32];
    __shared__ __align__(16) __bf16 Bs[128 * 32];

    const int tid  = threadIdx.x;
    const int lane = tid & 63;
    const int w    = tid >> 6;
    const int wm   = (w & 1) * 64;
    const int wn   = (w >> 1) * 64;
    const int m0   = blockIdx.x * 128;
    const int n0   = blockIdx.y * 128;
    const int l15  = lane & 15;
    const int lhi  = lane >> 4;

    f32x4 acc[4][4] = {};

    for (int k0 = 0; k0 < K; k0 += 32) {
        #pragma unroll
        for (int t = 0; t < 2; ++t) {
            int ci  = t * 256 + w * 64 + lane;
            int row = ci >> 2, kc = ci & 3;
            char* la = (char*)As + (size_t)(t * 256 + w * 64) * 16;
            char* lb = (char*)Bs + (size_t)(t * 256 + w * 64) * 16;
            llds16(A  + (size_t)(m0 + row) * lda + k0 + kc * 8, la);
            llds16(Bt + (size_t)(n0 + row) * ldb + k0 + kc * 8, lb);
        }
        asm volatile("s_waitcnt vmcnt(0)" ::: "memory");
        __syncthreads();

        bf16x8 af[4], bg[4];
        #pragma unroll
        for (int i = 0; i < 4; ++i)
            af[i] = *(bf16x8*)(As + (wm + i * 16 + l15) * 32 + lhi * 8);
        #pragma unroll
        for (int j = 0; j < 4; ++j)
            bg[j] = *(bf16x8*)(Bs + (wn + j * 16 + l15) * 32 + lhi * 8);
        #pragma unroll
        for (int i = 0; i < 4; ++i)
            #pragma unroll
            for (int j = 0; j < 4; ++j)
                acc[i][j] = __builtin_amdgcn_mfma_f32_16x16x32_bf16(
                    af[i], bg[j], acc[i][j], 0, 0, 0);
        __syncthreads();
    }

    #pragma unroll
    for (int i = 0; i < 4; ++i) {
        #pragma unroll
        for (int j = 0; j < 4; ++j) {
            int col = n0 + wn + j * 16 + l15;
            if (col < Ncap) {
                float bv = bias ? bias[col] : 0.f;
                #pragma unroll
                for (int e = 0; e < 4; ++e) {
                    int row = m0 + wm + i * 16 + lhi * 4 + e;
                    float v = acc[i][j][e] + bv;
                    if (RELU) v = fmaxf(v, 0.f);
                    if (FILM) {
                        float sv = __bfloat162float(fS[(size_t)row * fstride + col]);
                        float tv = __bfloat162float(fT[(size_t)row * fstride + col]);
                        v = v * (1.f + sv) + tv;
                    }
                    storeC(&C[(size_t)row * ldc + col], v);
                }
            }
        }
    }
}

// ===========================================================================
// Fused GCN conv (conv1): block = 128 node-rows (pair mt) x 128 H-cols.
// H = A @ Bt^T via MFMA; out = relu(P @ H + b) via MFMA, P from Pmg.
// ===========================================================================
__global__ __launch_bounds__(256) void conv_fused(
    const bf16* __restrict__ A, int lda, int K,
    const bf16* __restrict__ Bt, int ldb,
    const bf16* __restrict__ Pmg,
    const float* __restrict__ bias,
    bf16* __restrict__ Xout)
{
    __shared__ __align__(16) char regA[17408];
    __shared__ __align__(16) __bf16 Pm[128 * PMS];   // 20480 B

    __bf16* As = (__bf16*)regA;
    __bf16* Bs = (__bf16*)(regA + 8192);
    __bf16* Ts = (__bf16*)regA;

    const int tid  = threadIdx.x;
    const int lane = tid & 63;
    const int w    = tid >> 6;
    const int wm   = (w & 1) * 64;
    const int wn   = (w >> 1) * 64;
    const int l15  = lane & 15;
    const int lhi  = lane >> 4;

    const int bid = blockIdx.x;
    const int lid = bid >> 3;
    const int mt  = (bid & 7) * 64 + lid / 5;
    const int nt  = lid % 5;
    const int m0  = mt * 128;
    const int n0  = nt * 128;

    #pragma unroll
    for (int i = 0; i < 5; ++i) {
        int cbase = w * 320 + i * 64;
        llds16(Pmg + (size_t)mt * (128 * PMS) + (size_t)(cbase + lane) * 8,
               (char*)Pm + (size_t)cbase * 16);
    }

    f32x4 acc[4][4] = {};
    for (int k0 = 0; k0 < K; k0 += 32) {
        #pragma unroll
        for (int t = 0; t < 2; ++t) {
            int ci  = t * 256 + w * 64 + lane;
            int row = ci >> 2, kc = ci & 3;
            char* la = (char*)As + (size_t)(t * 256 + w * 64) * 16;
            char* lb = (char*)Bs + (size_t)(t * 256 + w * 64) * 16;
            llds16(A  + (size_t)(m0 + row) * lda + k0 + kc * 8, la);
            llds16(Bt + (size_t)(n0 + row) * ldb + k0 + kc * 8, lb);
        }
        asm volatile("s_waitcnt vmcnt(0)" ::: "memory");
        __syncthreads();

        bf16x8 af[4], bg[4];
        #pragma unroll
        for (int i = 0; i < 4; ++i)
            af[i] = *(bf16x8*)(As + (wm + i * 16 + l15) * 32 + lhi * 8);
        #pragma unroll
        for (int j = 0; j < 4; ++j)
            bg[j] = *(bf16x8*)(Bs + (wn + j * 16 + l15) * 32 + lhi * 8);
        #pragma unroll
        for (int i = 0; i < 4; ++i)
            #pragma unroll
            for (int j = 0; j < 4; ++j)
                acc[i][j] = __builtin_amdgcn_mfma_f32_16x16x32_bf16(
                    af[i], bg[j], acc[i][j], 0, 0, 0);
        __syncthreads();
    }

    const int g  = w & 1;
    const int nb = w >> 1;
    #pragma unroll
    for (int h = 0; h < 2; ++h) {
        if (wn == h * 64) {
            #pragma unroll
            for (int i = 0; i < 4; ++i)
                #pragma unroll
                for (int j = 0; j < 4; ++j) {
                    int c_local = j * 16 + l15;
                    int rbase   = wm + i * 16 + lhi * 4;
                    bf16x4 pk;
                    #pragma unroll
                    for (int e = 0; e < 4; ++e) pk[e] = (__bf16)acc[i][j][e];
                    *(bf16x4*)(Ts + c_local * 136 + rbase) = pk;
                }
        }
        __syncthreads();

        f32x4 acc2[4][2] = {};
        #pragma unroll
        for (int k0 = 0; k0 < 64; k0 += 32) {
            bf16x8 pa[4], hb[2];
            #pragma unroll
            for (int i = 0; i < 4; ++i)
                pa[i] = *(bf16x8*)(Pm + (g * 64 + i * 16 + l15) * PMS + k0 + lhi * 8);
            #pragma unroll
            for (int j = 0; j < 2; ++j)
                hb[j] = *(bf16x8*)(Ts + (nb * 32 + j * 16 + l15) * 136
                                      + g * 64 + k0 + lhi * 8);
            #pragma unroll
            for (int i = 0; i < 4; ++i)
                #pragma unroll
                for (int j = 0; j < 2; ++j)
                    acc2[i][j] = __builtin_amdgcn_mfma_f32_16x16x32_bf16(
                        pa[i], hb[j], acc2[i][j], 0, 0, 0);
        }
        #pragma unroll
        for (int i = 0; i < 4; ++i)
            #pragma unroll
            for (int j = 0; j < 2; ++j) {
                int col = n0 + h * 64 + nb * 32 + j * 16 + l15;
                if (col < FP) {
                    float bv = (col < 600) ? bias[col] : 0.f;
                    #pragma unroll
                    for (int e = 0; e < 4; ++e) {
                        int row = m0 + g * 64 + i * 16 + lhi * 4 + e;
                        float v = fmaxf(acc2[i][j][e] + bv, 0.f);   // relu
                        Xout[(size_t)row * FP + col] = __float2bfloat16(v);
                    }
                }
            }
        __syncthreads();
    }
}

// ===========================================================================
// conv2 + conv3 + pool fully fused: same as conv_fused, but instead of
// writing X2 = relu(P@H + b), contracts it with the precomputed q-vector:
// Y[g][col] = sum_row q[row] * X2[row][col].  Writes only Y (1.2 MB total).
// Each (pair, n-tile) block holds ALL 128 rows for its cols -> no atomics.
// ===========================================================================
__global__ __launch_bounds__(256) void conv_fused_q(
    const bf16* __restrict__ A, int lda, int K,
    const bf16* __restrict__ Bt, int ldb,
    const bf16* __restrict__ Pmg,
    const float* __restrict__ bias,
    const float* __restrict__ qv,
    bf16* __restrict__ Y)
{
    __shared__ __align__(16) char regA[17408];
    __shared__ __align__(16) __bf16 Pm[128 * PMS];
    __shared__ float s_q[128];

    __bf16* As = (__bf16*)regA;
    __bf16* Bs = (__bf16*)(regA + 8192);
    __bf16* Ts = (__bf16*)regA;

    const int tid  = threadIdx.x;
    const int lane = tid & 63;
    const int w    = tid >> 6;
    const int wm   = (w & 1) * 64;
    const int wn   = (w >> 1) * 64;
    const int l15  = lane & 15;
    const int lhi  = lane >> 4;

    const int bid = blockIdx.x;
    const int lid = bid >> 3;
    const int mt  = (bid & 7) * 64 + lid / 5;
    const int nt  = lid % 5;
    const int m0  = mt * 128;
    const int n0  = nt * 128;

    #pragma unroll
    for (int i = 0; i < 5; ++i) {
        int cbase = w * 320 + i * 64;
        llds16(Pmg + (size_t)mt * (128 * PMS) + (size_t)(cbase + lane) * 8,
               (char*)Pm + (size_t)cbase * 16);
    }
    if (tid < 128) s_q[tid] = qv[mt * 128 + tid];

    f32x4 acc[4][4] = {};
    for (int k0 = 0; k0 < K; k0 += 32) {
        #pragma unroll
        for (int t = 0; t < 2; ++t) {
            int ci  = t * 256 + w * 64 + lane;
            int row = ci >> 2, kc = ci & 3;
            char* la = (char*)As + (size_t)(t * 256 + w * 64) * 16;
            char* lb = (char*)Bs + (size_t)(t * 256 + w * 64) * 16;
            llds16(A  + (size_t)(m0 + row) * lda + k0 + kc * 8, la);
            llds16(Bt + (size_t)(n0 + row) * ldb + k0 + kc * 8, lb);
        }
        asm volatile("s_waitcnt vmcnt(0)" ::: "memory");
        __syncthreads();

        bf16x8 af[4], bg[4];
        #pragma unroll
        for (int i = 0; i < 4; ++i)
            af[i] = *(bf16x8*)(As + (wm + i * 16 + l15) * 32 + lhi * 8);
        #pragma unroll
        for (int j = 0; j < 4; ++j)
            bg[j] = *(bf16x8*)(Bs + (wn + j * 16 + l15) * 32 + lhi * 8);
        #pragma unroll
        for (int i = 0; i < 4; ++i)
            #pragma unroll
            for (int j = 0; j < 4; ++j)
                acc[i][j] = __builtin_amdgcn_mfma_f32_16x16x32_bf16(
                    af[i], bg[j], acc[i][j], 0, 0, 0);
        __syncthreads();
    }

    const int g  = w & 1;
    const int nb = w >> 1;
    #pragma unroll
    for (int h = 0; h < 2; ++h) {
        if (wn == h * 64) {
            #pragma unroll
            for (int i = 0; i < 4; ++i)
                #pragma unroll
                for (int j = 0; j < 4; ++j) {
                    int c_local = j * 16 + l15;
                    int rbase   = wm + i * 16 + lhi * 4;
                    bf16x4 pk;
                    #pragma unroll
                    for (int e = 0; e < 4; ++e) pk[e] = (__bf16)acc[i][j][e];
                    *(bf16x4*)(Ts + c_local * 136 + rbase) = pk;
                }
        }
        __syncthreads();

        f32x4 acc2[4][2] = {};
        #pragma unroll
        for (int k0 = 0; k0 < 64; k0 += 32) {
            bf16x8 pa[4], hb[2];
            #pragma unroll
            for (int i = 0; i < 4; ++i)
                pa[i] = *(bf16x8*)(Pm + (g * 64 + i * 16 + l15) * PMS + k0 + lhi * 8);
            #pragma unroll
            for (int j = 0; j < 2; ++j)
                hb[j] = *(bf16x8*)(Ts + (nb * 32 + j * 16 + l15) * 136
                                      + g * 64 + k0 + lhi * 8);
            #pragma unroll
            for (int i = 0; i < 4; ++i)
                #pragma unroll
                for (int j = 0; j < 2; ++j)
                    acc2[i][j] = __builtin_amdgcn_mfma_f32_16x16x32_bf16(
                        pa[i], hb[j], acc2[i][j], 0, 0, 0);
        }
        // q-contraction: yp[j] = sum over this lane's 16 rows, then 4-lane reduce
        #pragma unroll
        for (int j = 0; j < 2; ++j) {
            int col = n0 + h * 64 + nb * 32 + j * 16 + l15;
            float bv = (col < 600) ? bias[col] : 0.f;
            float yp = 0.f;
            #pragma unroll
            for (int i = 0; i < 4; ++i)
                #pragma unroll
                for (int e = 0; e < 4; ++e) {
                    float v = fmaxf(acc2[i][j][e] + bv, 0.f);   // relu
                    yp += s_q[g * 64 + i * 16 + lhi * 4 + e] * v;
                }
            yp += __shfl_xor(yp, 16, 64);
            yp += __shfl_xor(yp, 32, 64);
            if (lhi == 0 && col < FP)
                Y[(size_t)(mt * 2 + g) * FP + col] = __float2bfloat16(yp);
        }
        __syncthreads();
    }
}

// ===========================================================================
// Mega prep kernel: [WT transposes | timestep emb | pair prep | node xform]
// ===========================================================================
struct WtJob  { const float* src; bf16* dst; int Ksrc, Nsrc, Kp, Np, blk0; };
struct PrepArgs {
    WtJob j[9];
    int nwt, te0, pp0, xtr0;                 // block-range starts
    const int*   ei;
    const float* ts;
    const float* xin; const float* Wtr; const float* btr; const float* mask;
    bf16* TE; bf16* Pmg; float* qv; bf16* X;
};

__global__ __launch_bounds__(256) void k_prep(PrepArgs a)
{
    __shared__ __align__(16) char sm[35840];
    const int bx  = blockIdx.x;
    const int tid = threadIdx.x;

    if (bx < a.nwt) {
        // ---------- LDS-tiled transpose: dst[n][k] = src[k][n] ----------
        int ji = 0;
        while (ji < 8 && bx >= a.j[ji + 1].blk0) ++ji;
        WtJob jb = a.j[ji];
        int t  = bx - jb.blk0;
        int kt = (jb.Kp + 63) >> 6;
        int ti = t % kt, tj = t / kt;
        int kg0 = ti * 64, ng0 = tj * 64;
        float (*T)[65] = (float(*)[65])sm;
        #pragma unroll 4
        for (int r = 0; r < 16; ++r) {
            int kl = (tid >> 6) + r * 4, nl = tid & 63;
            int kg = kg0 + kl, ng = ng0 + nl;
            T[kl][nl] = (kg < jb.Ksrc && ng < jb.Nsrc)
                        ? jb.src[(size_t)kg * jb.Nsrc + ng] : 0.f;
        }
        __syncthreads();
        #pragma unroll 4
        for (int r = 0; r < 16; ++r) {
            int nl = (tid >> 6) + r * 4, kl = tid & 63;
            int ng = ng0 + nl, kg = kg0 + kl;
            if (ng < jb.Np && kg < jb.Kp)
                jb.dst[(size_t)ng * jb.Kp + kg] = __float2bfloat16(T[kl][nl]);
        }
    } else if (bx < a.pp0) {
        // ---------- timestep embedding ----------
        int idx = (bx - a.te0) * 256 + tid;
        int b = idx >> 7, jj = idx & 127;
        float tt = a.ts[b];
        int h = jj & 63;
        float freq = expf(-9.210340371976184f * (float)h / 64.f);  // ln(10000)
        float ang = tt * freq;
        a.TE[idx] = __float2bfloat16((jj < 64) ? cosf(ang) : sinf(ang));
    } else if (bx < a.xtr0) {
        // ---------- pair prep: P matrix (bf16, PMS stride) + q vector ----------
        int pr = bx - a.pp0;                     // pair 0..511
        float* Pf   = (float*)sm;                // 128 x 64 fp32
        int*   cnt  = (int*)(sm + 32768);
        float* sQ   = (float*)(sm + 33280);
        float* sI   = (float*)(sm + 33792);
        float* sIvd = (float*)(sm + 34304);

        for (int idx = tid; idx < 8192; idx += 256) Pf[idx] = 0.f;
        if (tid < 128) cnt[tid] = 0;
        __syncthreads();
        for (int e = tid; e < 2 * EPG; e += 256) {
            int g  = (e >= EPG);
            int eg = (2 * pr + g) * EPG + (e - g * EPG);
            int ld = (a.ei[E + eg] & 63) + g * 64;
            atomicAdd(&cnt[ld], 1);
        }
        __syncthreads();
        if (tid < 128) {
            float d = (float)cnt[tid] + 1.0f;
            float iv = 1.f / d;
            sIvd[tid] = iv;
            sI[tid]   = rsqrtf(d);
            sQ[tid]   = iv;
        }
        __syncthreads();
        for (int e = tid; e < 2 * EPG; e += 256) {
            int g   = (e >= EPG);
            int eg  = (2 * pr + g) * EPG + (e - g * EPG);
            int lsl = a.ei[eg] & 63;
            int ldl = a.ei[E + eg] & 63;
            float cf = sI[g * 64 + lsl] * sI[g * 64 + ldl];
            atomicAdd(&Pf[(g * 64 + ldl) * 64 + lsl], cf);
            atomicAdd(&sQ[g * 64 + lsl], cf);
        }
        __syncthreads();
        if (tid < 128) {
            Pf[tid * 64 + (tid & 63)] += sIvd[tid];
            a.qv[pr * 128 + tid] = sQ[tid] * (1.f / 64.f);
        }
        __syncthreads();
        for (int idx = tid; idx < 128 * PMS; idx += 256) {
            int r = idx / PMS, k = idx - r * PMS;
            float v = (k < 64) ? Pf[r * 64 + k] : 0.f;
            a.Pmg[(size_t)pr * (128 * PMS) + idx] = __float2bfloat16(v);
        }
    } else {
        // ---------- node transform (per graph) ----------
        int g = bx - a.xtr0;
        float* Ws = (float*)sm;
        float* xb = (float*)(sm + 23104);
        float* sb = (float*)(sm + 28224);
        float* smk= (float*)(sm + 29440);

        for (int idx = tid; idx < 19 * 304; idx += 256) {
            int k = idx / 304, c = idx - k * 304;
            Ws[idx] = (c < 300) ? a.Wtr[k * 300 + c] : 0.f;
        }
        for (int idx = tid; idx < 64 * 19; idx += 256) {
            int n = idx / 19, k = idx - n * 19;
            xb[n * 20 + k] = a.xin[(size_t)(g * 64 + n) * 19 + k];
        }
        for (int c = tid; c < 304; c += 256)
            sb[c] = (c < 300) ? a.btr[c] : 0.f;
        if (tid < 64) smk[tid] = a.mask[g * 64 + tid];
        __syncthreads();

        int n  = tid >> 2;
        int c0 = tid & 3;
        float m = smk[n];
        for (int c = c0; c < 304; c += 4) {
            float acc = sb[c];
            #pragma unroll
            for (int k = 0; k < 19; ++k)
                acc += xb[n * 20 + k] * Ws[k * 304 + c];
            a.X[(size_t)(g * 64 + n) * FP + c] = __float2bfloat16(acc * m);
        }
        bf16x8 z = {};
        for (int idx = tid; idx < 64 * 38; idx += 256) {
            int nn = idx / 38, jv = idx - nn * 38;
            *(bf16x8*)((__bf16*)a.X + (size_t)(g * 64 + nn) * FP + 304 + jv * 8) = z;
        }
    }
}

// LayerNorm over 300 dims + affine, fp32 out; fused text passthrough copy
__global__ __launch_bounds__(256) void k_ln_copy(const float* __restrict__ G,
                                                 const float* __restrict__ lg,
                                                 const float* __restrict__ lb,
                                                 const float* __restrict__ text,
                                                 float* __restrict__ out)
{
    int r = blockIdx.x;
    int tid = threadIdx.x;
    __shared__ float red[4];
    __shared__ float smu, svar;

    float v0 = (tid < 300) ? G[r * 300 + tid] : 0.f;
    float v1 = (tid + 256 < 300) ? G[r * 300 + tid + 256] : 0.f;
    float s = v0 + v1;
    #pragma unroll
    for (int o = 32; o > 0; o >>= 1) s += __shfl_down(s, o, 64);
    if ((tid & 63) == 0) red[tid >> 6] = s;
    __syncthreads();
    if (tid == 0) smu = (red[0] + red[1] + red[2] + red[3]) * (1.f / 300.f);
    __syncthreads();
    float mu = smu;
    float d0 = (tid < 300) ? v0 - mu : 0.f;
    float d1 = (tid + 256 < 300) ? v1 - mu : 0.f;
    s = d0 * d0 + d1 * d1;
    #pragma unroll
    for (int o = 32; o > 0; o >>= 1) s += __shfl_down(s, o, 64);
    if ((tid & 63) == 0) red[tid >> 6] = s;
    __syncthreads();
    if (tid == 0) svar = (red[0] + red[1] + red[2] + red[3]) * (1.f / 300.f);
    __syncthreads();
    float rstd = rsqrtf(svar + 1e-5f);
    if (tid < 300)
        out[r * 300 + tid] = d0 * rstd * lg[tid] + lb[tid];
    if (tid + 256 < 300)
        out[r * 300 + tid + 256] = d1 * rstd * lg[tid + 256] + lb[tid + 256];
    float* o2 = out + (size_t)B * 300;
    for (int c = tid; c < 300; c += 256)
        o2[(size_t)r * 300 + c] = text[(size_t)r * 300 + c];
}

// ---------------------------------------------------------------------------
extern "C" void kernel_launch(void* const* d_in, const int* in_sizes, int n_in,
                              void* d_out, int out_size, void* d_ws, size_t ws_size,
                              hipStream_t stream)
{
    const float* x_in  = (const float*)d_in[0];
    const int*   ei    = (const int*)d_in[1];
    const float* text  = (const float*)d_in[3];
    const float* tst   = (const float*)d_in[4];
    const float* mask  = (const float*)d_in[5];
    const float* W_tr  = (const float*)d_in[6];
    const float* b_tr  = (const float*)d_in[7];
    const float* W_c1  = (const float*)d_in[8];
    const float* b_c1  = (const float*)d_in[9];
    const float* W_c2  = (const float*)d_in[10];
    const float* b_c2  = (const float*)d_in[11];
    const float* W_c3  = (const float*)d_in[12];
    const float* b_c3  = (const float*)d_in[13];
    const float* W_h1  = (const float*)d_in[14];
    const float* b_h1  = (const float*)d_in[15];
    const float* W_h2  = (const float*)d_in[16];
    const float* b_h2  = (const float*)d_in[17];
    const float* W_h3  = (const float*)d_in[18];
    const float* b_h3  = (const float*)d_in[19];
    const float* ln_g  = (const float*)d_in[20];
    const float* ln_b  = (const float*)d_in[21];
    const float* W_t1  = (const float*)d_in[22];
    const float* b_t1  = (const float*)d_in[23];
    const float* W_t2  = (const float*)d_in[24];
    const float* b_t2  = (const float*)d_in[25];
    const float* W_e   = (const float*)d_in[26];
    const float* b_e   = (const float*)d_in[27];

    // workspace carve (256B aligned)
    char* w = (char*)d_ws;
    size_t off = 0;
    auto carve = [&](size_t bytes) {
        void* p = w + off;
        off += (bytes + 255) & ~(size_t)255;
        return p;
    };
    bf16*  XA     = (bf16*) carve((size_t)BN * FP * 2);      // 79.7 MB
    bf16*  Wb1    = (bf16*) carve((size_t)640 * 320 * 2);
    bf16*  Wb2    = (bf16*) carve((size_t)640 * FP * 2);
    bf16*  Wb3    = (bf16*) carve((size_t)640 * FP * 2);
    bf16*  Wt1t   = (bf16*) carve((size_t)512 * 128 * 2);
    bf16*  Wt2t   = (bf16*) carve((size_t)512 * 512 * 2);
    bf16*  Wet    = (bf16*) carve((size_t)3072 * 512 * 2);
    bf16*  Wh1t   = (bf16*) carve((size_t)640 * FP * 2);
    bf16*  Wh2t   = (bf16*) carve((size_t)640 * FP * 2);
    bf16*  Wh3t   = (bf16*) carve((size_t)384 * FP * 2);
    bf16*  TE     = (bf16*) carve((size_t)B * 128 * 2);
    bf16*  A1b    = (bf16*) carve((size_t)B * 512 * 2);
    bf16*  A2b    = (bf16*) carve((size_t)B * 512 * 2);
    bf16*  EO     = (bf16*) carve((size_t)B * 3000 * 2);
    bf16*  Yv     = (bf16*) carve((size_t)B * FP * 2);
    bf16*  G0     = (bf16*) carve((size_t)B * FP * 2);
    bf16*  G1     = (bf16*) carve((size_t)B * FP * 2);
    bf16*  G2     = (bf16*) carve((size_t)B * FP * 2);
    float* G3     = (float*)carve((size_t)B * 300 * 4);
    bf16*  Pmg    = (bf16*) carve((size_t)512 * 128 * PMS * 2);  // 10.5 MB
    float* qv     = (float*)carve((size_t)BN * 4);
    (void)ws_size; (void)in_sizes; (void)n_in; (void)out_size;

    float* out = (float*)d_out;

    // --- phase A: one mega prep launch ---
    PrepArgs pa;
    struct JD { const float* s; bf16* d; int Ks, Ns, Kp, Np; };
    JD jd[9] = {
        { W_c1, Wb1,  300, 600,  320, 640 },
        { W_c2, Wb2,  600, 600,  FP,  640 },
        { W_c3, Wb3,  600, 600,  FP,  640 },
        { W_t1, Wt1t, 128, 512,  128, 512 },
        { W_t2, Wt2t, 512, 512,  512, 512 },
        { W_e,  Wet,  512, 3000, 512, 3072 },
        { W_h1, Wh1t, 600, 600,  FP,  640 },
        { W_h2, Wh2t, 600, 600,  FP,  640 },
        { W_h3, Wh3t, 600, 300,  FP,  384 },
    };
    int cum = 0;
    for (int i = 0; i < 9; ++i) {
        int kt = (jd[i].Kp + 63) >> 6, nt = (jd[i].Np + 63) >> 6;
        pa.j[i] = { jd[i].s, jd[i].d, jd[i].Ks, jd[i].Ns, jd[i].Kp, jd[i].Np, cum };
        cum += kt * nt;
    }
    pa.nwt  = cum;
    pa.te0  = cum;       cum += (B * 128) / 256;
    pa.pp0  = cum;       cum += B / 2;
    pa.xtr0 = cum;       cum += B;
    pa.ei = ei; pa.ts = tst;
    pa.xin = x_in; pa.Wtr = W_tr; pa.btr = b_tr; pa.mask = mask;
    pa.TE = TE; pa.Pmg = Pmg; pa.qv = qv; pa.X = XA;
    k_prep<<<cum, 256, 0, stream>>>(pa);

    // --- timestep embedding MLP (MFMA) ---
    gemm_ep<true, false, bf16><<<dim3(8, 4), 256, 0, stream>>>(
        TE, 128, Wt1t, 128, b_t1, A1b, 512, 512, nullptr, nullptr, 0, 128);
    gemm_ep<true, false, bf16><<<dim3(8, 4), 256, 0, stream>>>(
        A1b, 512, Wt2t, 512, b_t2, A2b, 512, 512, nullptr, nullptr, 0, 512);
    gemm_ep<false, false, bf16><<<dim3(8, 24), 256, 0, stream>>>(
        A2b, 512, Wet, 512, b_e, EO, 3000, 3000, nullptr, nullptr, 0, 512);

    // --- conv1 (writes X1), conv2+conv3+pool (writes Y only) ---
    conv_fused<<<2560, 256, 0, stream>>>(XA, FP, 320, Wb1, 320, Pmg, b_c1, XA);
    conv_fused_q<<<2560, 256, 0, stream>>>(XA, FP, FP, Wb2, FP, Pmg, b_c2, qv, Yv);

    // --- G0 = Y @ W3^T + b_c3 ---
    gemm_ep<false, false, bf16><<<dim3(8, 5), 256, 0, stream>>>(
        Yv, FP, Wb3, FP, b_c3, G0, FP, 600, nullptr, nullptr, 0, FP);

    // --- h-layers with FiLM (MFMA) ---
    gemm_ep<true, true, bf16><<<dim3(8, 5), 256, 0, stream>>>(
        G0, FP, Wh1t, FP, b_h1, G1, FP, 600, EO + 0, EO + 600, 3000, FP);
    gemm_ep<true, true, bf16><<<dim3(8, 5), 256, 0, stream>>>(
        G1, FP, Wh2t, FP, b_h2, G2, FP, 600, EO + 1200, EO + 1800, 3000, FP);
    gemm_ep<false, true, float><<<dim3(8, 3), 256, 0, stream>>>(
        G2, FP, Wh3t, FP, b_h3, G3, 300, 300, EO + 2400, EO + 2700, 3000, FP);

    // --- layer norm + text passthrough ---
    k_ln_copy<<<B, 256, 0, stream>>>(G3, ln_g, ln_b, text, out);
}

// Round 9
// 408.029 us; speedup vs baseline: 8.5261x; 1.0954x over previous
//
#include <hip/hip_runtime.h>
#include <hip/hip_bf16.h>
#include <cstdint>
#include <cstddef>

// Problem constants
static constexpr int B   = 1024;
static constexpr int N   = 64;
static constexpr int BN  = B * N;      // 65536 nodes
static constexpr int EPG = 192;
static constexpr int E   = B * EPG;    // 196608 edges
static constexpr int FP  = 608;        // padded feature dim (mult of 32)
static constexpr int PMS = 80;         // Pm row stride (bf16)
static constexpr int NCONV = 2560;     // conv blocks per conv dispatch

typedef __hip_bfloat16 bf16;
typedef __bf16 bf16x8 __attribute__((ext_vector_type(8)));
typedef __bf16 bf16x4 __attribute__((ext_vector_type(4)));
typedef float  f32x4  __attribute__((ext_vector_type(4)));

__device__ __forceinline__ void storeC(float* p, float v) { *p = v; }
__device__ __forceinline__ void storeC(bf16* p, float v) { *p = __float2bfloat16(v); }

// async global->LDS, 16B per lane; LDS dest is wave-uniform base + lane*16
__device__ __forceinline__ void llds16(const void* g, void* l) {
    __builtin_amdgcn_global_load_lds(
        (const __attribute__((address_space(1))) unsigned int*)g,
        (__attribute__((address_space(3))) unsigned int*)l,
        16, 0, 0);
}

// ===========================================================================
// 64x128 MFMA GEMM tile body (device fn): C[64 x 128 at (m0,n0)] =
// A[m0:m0+64, 0:K] @ Bt^T (+bias)(relu)(film).  4 waves, each 64x32.
// As: 64*32 bf16 (4KB), Bs: 128*32 bf16 (8KB).
// ===========================================================================
template<bool RELU, bool FILM, typename CT>
__device__ __forceinline__ void g64_tile(
    const bf16* __restrict__ A, int lda,
    const bf16* __restrict__ Bt, int ldb,
    const float* __restrict__ bias,
    CT* __restrict__ C, int ldc, int Ncap,
    const bf16* __restrict__ fS, const bf16* __restrict__ fT, int fstride,
    int K, int m0, int n0, __bf16* As, __bf16* Bs, int tid)
{
    const int lane = tid & 63;
    const int w    = tid >> 6;
    const int wn   = w * 32;
    const int l15  = lane & 15;
    const int lhi  = lane >> 4;

    f32x4 acc[4][2] = {};

    for (int k0 = 0; k0 < K; k0 += 32) {
        {   // A tile: 256 chunks of 16B, one per thread
            int row = tid >> 2, kc = tid & 3;
            char* la = (char*)As + (size_t)(w * 64) * 16;
            llds16(A + (size_t)(m0 + row) * lda + k0 + kc * 8, la);
        }
        #pragma unroll
        for (int t = 0; t < 2; ++t) {   // B tile: 512 chunks
            int ci  = t * 256 + tid;
            int row = ci >> 2, kc = ci & 3;
            char* lb = (char*)Bs + (size_t)(t * 256 + w * 64) * 16;
            llds16(Bt + (size_t)(n0 + row) * ldb + k0 + kc * 8, lb);
        }
        asm volatile("s_waitcnt vmcnt(0)" ::: "memory");
        __syncthreads();

        bf16x8 af[4], bg[2];
        #pragma unroll
        for (int i = 0; i < 4; ++i)
            af[i] = *(bf16x8*)(As + (i * 16 + l15) * 32 + lhi * 8);
        #pragma unroll
        for (int j = 0; j < 2; ++j)
            bg[j] = *(bf16x8*)(Bs + (wn + j * 16 + l15) * 32 + lhi * 8);
        #pragma unroll
        for (int i = 0; i < 4; ++i)
            #pragma unroll
            for (int j = 0; j < 2; ++j)
                acc[i][j] = __builtin_amdgcn_mfma_f32_16x16x32_bf16(
                    af[i], bg[j], acc[i][j], 0, 0, 0);
        __syncthreads();
    }

    #pragma unroll
    for (int i = 0; i < 4; ++i) {
        #pragma unroll
        for (int j = 0; j < 2; ++j) {
            int col = n0 + wn + j * 16 + l15;
            if (col < Ncap) {
                float bv = bias ? bias[col] : 0.f;
                #pragma unroll
                for (int e = 0; e < 4; ++e) {
                    int row = m0 + i * 16 + lhi * 4 + e;
                    float v = acc[i][j][e] + bv;
                    if (RELU) v = fmaxf(v, 0.f);
                    if (FILM) {
                        float sv = __bfloat162float(fS[(size_t)row * fstride + col]);
                        float tv = __bfloat162float(fT[(size_t)row * fstride + col]);
                        v = v * (1.f + sv) + tv;
                    }
                    storeC(&C[(size_t)row * ldc + col], v);
                }
            }
        }
    }
}

// standalone 64-row-tile GEMM (h-layers)
template<bool RELU, bool FILM, typename CT>
__global__ __launch_bounds__(256) void gemm64(
    const bf16* __restrict__ A, int lda,
    const bf16* __restrict__ Bt, int ldb,
    const float* __restrict__ bias,
    CT* __restrict__ C, int ldc, int Ncap,
    const bf16* __restrict__ fS, const bf16* __restrict__ fT, int fstride,
    int K)
{
    __shared__ __align__(16) __bf16 As[64 * 32];
    __shared__ __align__(16) __bf16 Bs[128 * 32];
    g64_tile<RELU, FILM, CT>(A, lda, Bt, ldb, bias, C, ldc, Ncap,
                             fS, fT, fstride, K,
                             blockIdx.x * 64, blockIdx.y * 128, As, Bs,
                             threadIdx.x);
}

// two independent small GEMMs in one dispatch: EO (384 blocks) + W3 (80)
__global__ __launch_bounds__(256) void k_two_gemms(
    const bf16* __restrict__ A2b, const bf16* __restrict__ Wet,
    const float* __restrict__ b_e, bf16* __restrict__ EO,
    const bf16* __restrict__ Yv, const bf16* __restrict__ Wb3,
    const float* __restrict__ b_c3, bf16* __restrict__ G0)
{
    __shared__ __align__(16) __bf16 As[64 * 32];
    __shared__ __align__(16) __bf16 Bs[128 * 32];
    int bid = blockIdx.x;
    if (bid < 384) {
        int mt = bid / 24, nt = bid % 24;
        g64_tile<false, false, bf16>(A2b, 512, Wet, 512, b_e, EO, 3000, 3000,
                                     nullptr, nullptr, 0, 512,
                                     mt * 64, nt * 128, As, Bs, threadIdx.x);
    } else {
        int t = bid - 384;
        int mt = t / 5, nt = t % 5;
        g64_tile<false, false, bf16>(Yv, FP, Wb3, FP, b_c3, G0, FP, 600,
                                     nullptr, nullptr, 0, FP,
                                     mt * 64, nt * 128, As, Bs, threadIdx.x);
    }
}

// ===========================================================================
// Fused GCN conv (conv1) + hidden t1-GEMM blocks.
// conv blocks [0, NCONV): H = A @ Bt^T via MFMA; out = relu(P@H + b) via MFMA.
// blocks [NCONV, NCONV+gnt*16): g64 tile of gA @ gBt^T (+gbias, relu).
// ===========================================================================
__global__ __launch_bounds__(256) void conv_fused(
    const bf16* __restrict__ A, int lda, int K,
    const bf16* __restrict__ Bt, int ldb,
    const bf16* __restrict__ Pmg,
    const float* __restrict__ bias,
    bf16* __restrict__ Xout,
    const bf16* __restrict__ gA, int glda,
    const bf16* __restrict__ gBt, int gldb,
    const float* __restrict__ gbias,
    bf16* __restrict__ gC, int gldc, int gNcap, int gK, int gnt)
{
    __shared__ __align__(16) char regA[17408];
    __shared__ __align__(16) __bf16 Pm[128 * PMS];   // 20480 B

    const int tid = threadIdx.x;
    const int bid = blockIdx.x;

    if (bid >= NCONV) {
        int t = bid - NCONV;
        int mt2 = t / gnt, nt2 = t % gnt;
        g64_tile<true, false, bf16>(gA, glda, gBt, gldb, gbias, gC, gldc, gNcap,
                                    nullptr, nullptr, 0, gK,
                                    mt2 * 64, nt2 * 128,
                                    (__bf16*)regA, (__bf16*)(regA + 4096), tid);
        return;
    }

    __bf16* As = (__bf16*)regA;
    __bf16* Bs = (__bf16*)(regA + 8192);
    __bf16* Ts = (__bf16*)regA;

    const int lane = tid & 63;
    const int w    = tid >> 6;
    const int wm   = (w & 1) * 64;
    const int wn   = (w >> 1) * 64;
    const int l15  = lane & 15;
    const int lhi  = lane >> 4;

    const int lid = bid >> 3;
    const int mt  = (bid & 7) * 64 + lid / 5;
    const int nt  = lid % 5;
    const int m0  = mt * 128;
    const int n0  = nt * 128;

    #pragma unroll
    for (int i = 0; i < 5; ++i) {
        int cbase = w * 320 + i * 64;
        llds16(Pmg + (size_t)mt * (128 * PMS) + (size_t)(cbase + lane) * 8,
               (char*)Pm + (size_t)cbase * 16);
    }

    f32x4 acc[4][4] = {};
    for (int k0 = 0; k0 < K; k0 += 32) {
        #pragma unroll
        for (int t = 0; t < 2; ++t) {
            int ci  = t * 256 + w * 64 + lane;
            int row = ci >> 2, kc = ci & 3;
            char* la = (char*)As + (size_t)(t * 256 + w * 64) * 16;
            char* lb = (char*)Bs + (size_t)(t * 256 + w * 64) * 16;
            llds16(A  + (size_t)(m0 + row) * lda + k0 + kc * 8, la);
            llds16(Bt + (size_t)(n0 + row) * ldb + k0 + kc * 8, lb);
        }
        asm volatile("s_waitcnt vmcnt(0)" ::: "memory");
        __syncthreads();

        bf16x8 af[4], bg[4];
        #pragma unroll
        for (int i = 0; i < 4; ++i)
            af[i] = *(bf16x8*)(As + (wm + i * 16 + l15) * 32 + lhi * 8);
        #pragma unroll
        for (int j = 0; j < 4; ++j)
            bg[j] = *(bf16x8*)(Bs + (wn + j * 16 + l15) * 32 + lhi * 8);
        #pragma unroll
        for (int i = 0; i < 4; ++i)
            #pragma unroll
            for (int j = 0; j < 4; ++j)
                acc[i][j] = __builtin_amdgcn_mfma_f32_16x16x32_bf16(
                    af[i], bg[j], acc[i][j], 0, 0, 0);
        __syncthreads();
    }

    const int g  = w & 1;
    const int nb = w >> 1;
    #pragma unroll
    for (int h = 0; h < 2; ++h) {
        if (wn == h * 64) {
            #pragma unroll
            for (int i = 0; i < 4; ++i)
                #pragma unroll
                for (int j = 0; j < 4; ++j) {
                    int c_local = j * 16 + l15;
                    int rbase   = wm + i * 16 + lhi * 4;
                    bf16x4 pk;
                    #pragma unroll
                    for (int e = 0; e < 4; ++e) pk[e] = (__bf16)acc[i][j][e];
                    *(bf16x4*)(Ts + c_local * 136 + rbase) = pk;
                }
        }
        __syncthreads();

        f32x4 acc2[4][2] = {};
        #pragma unroll
        for (int k0 = 0; k0 < 64; k0 += 32) {
            bf16x8 pa[4], hb[2];
            #pragma unroll
            for (int i = 0; i < 4; ++i)
                pa[i] = *(bf16x8*)(Pm + (g * 64 + i * 16 + l15) * PMS + k0 + lhi * 8);
            #pragma unroll
            for (int j = 0; j < 2; ++j)
                hb[j] = *(bf16x8*)(Ts + (nb * 32 + j * 16 + l15) * 136
                                      + g * 64 + k0 + lhi * 8);
            #pragma unroll
            for (int i = 0; i < 4; ++i)
                #pragma unroll
                for (int j = 0; j < 2; ++j)
                    acc2[i][j] = __builtin_amdgcn_mfma_f32_16x16x32_bf16(
                        pa[i], hb[j], acc2[i][j], 0, 0, 0);
        }
        #pragma unroll
        for (int i = 0; i < 4; ++i)
            #pragma unroll
            for (int j = 0; j < 2; ++j) {
                int col = n0 + h * 64 + nb * 32 + j * 16 + l15;
                if (col < FP) {
                    float bv = (col < 600) ? bias[col] : 0.f;
                    #pragma unroll
                    for (int e = 0; e < 4; ++e) {
                        int row = m0 + g * 64 + i * 16 + lhi * 4 + e;
                        float v = fmaxf(acc2[i][j][e] + bv, 0.f);   // relu
                        Xout[(size_t)row * FP + col] = __float2bfloat16(v);
                    }
                }
            }
        __syncthreads();
    }
}

// ===========================================================================
// conv2+conv3+pool fused (+ hidden t2-GEMM blocks).  Writes only Y.
// ===========================================================================
__global__ __launch_bounds__(256) void conv_fused_q(
    const bf16* __restrict__ A, int lda, int K,
    const bf16* __restrict__ Bt, int ldb,
    const bf16* __restrict__ Pmg,
    const float* __restrict__ bias,
    const float* __restrict__ qv,
    bf16* __restrict__ Y,
    const bf16* __restrict__ gA, int glda,
    const bf16* __restrict__ gBt, int gldb,
    const float* __restrict__ gbias,
    bf16* __restrict__ gC, int gldc, int gNcap, int gK, int gnt)
{
    __shared__ __align__(16) char regA[17408];
    __shared__ __align__(16) __bf16 Pm[128 * PMS];
    __shared__ float s_q[128];

    const int tid = threadIdx.x;
    const int bid = blockIdx.x;

    if (bid >= NCONV) {
        int t = bid - NCONV;
        int mt2 = t / gnt, nt2 = t % gnt;
        g64_tile<true, false, bf16>(gA, glda, gBt, gldb, gbias, gC, gldc, gNcap,
                                    nullptr, nullptr, 0, gK,
                                    mt2 * 64, nt2 * 128,
                                    (__bf16*)regA, (__bf16*)(regA + 4096), tid);
        return;
    }

    __bf16* As = (__bf16*)regA;
    __bf16* Bs = (__bf16*)(regA + 8192);
    __bf16* Ts = (__bf16*)regA;

    const int lane = tid & 63;
    const int w    = tid >> 6;
    const int wm   = (w & 1) * 64;
    const int wn   = (w >> 1) * 64;
    const int l15  = lane & 15;
    const int lhi  = lane >> 4;

    const int lid = bid >> 3;
    const int mt  = (bid & 7) * 64 + lid / 5;
    const int nt  = lid % 5;
    const int m0  = mt * 128;
    const int n0  = nt * 128;

    #pragma unroll
    for (int i = 0; i < 5; ++i) {
        int cbase = w * 320 + i * 64;
        llds16(Pmg + (size_t)mt * (128 * PMS) + (size_t)(cbase + lane) * 8,
               (char*)Pm + (size_t)cbase * 16);
    }
    if (tid < 128) s_q[tid] = qv[mt * 128 + tid];

    f32x4 acc[4][4] = {};
    for (int k0 = 0; k0 < K; k0 += 32) {
        #pragma unroll
        for (int t = 0; t < 2; ++t) {
            int ci  = t * 256 + w * 64 + lane;
            int row = ci >> 2, kc = ci & 3;
            char* la = (char*)As + (size_t)(t * 256 + w * 64) * 16;
            char* lb = (char*)Bs + (size_t)(t * 256 + w * 64) * 16;
            llds16(A  + (size_t)(m0 + row) * lda + k0 + kc * 8, la);
            llds16(Bt + (size_t)(n0 + row) * ldb + k0 + kc * 8, lb);
        }
        asm volatile("s_waitcnt vmcnt(0)" ::: "memory");
        __syncthreads();

        bf16x8 af[4], bg[4];
        #pragma unroll
        for (int i = 0; i < 4; ++i)
            af[i] = *(bf16x8*)(As + (wm + i * 16 + l15) * 32 + lhi * 8);
        #pragma unroll
        for (int j = 0; j < 4; ++j)
            bg[j] = *(bf16x8*)(Bs + (wn + j * 16 + l15) * 32 + lhi * 8);
        #pragma unroll
        for (int i = 0; i < 4; ++i)
            #pragma unroll
            for (int j = 0; j < 4; ++j)
                acc[i][j] = __builtin_amdgcn_mfma_f32_16x16x32_bf16(
                    af[i], bg[j], acc[i][j], 0, 0, 0);
        __syncthreads();
    }

    const int g  = w & 1;
    const int nb = w >> 1;
    #pragma unroll
    for (int h = 0; h < 2; ++h) {
        if (wn == h * 64) {
            #pragma unroll
            for (int i = 0; i < 4; ++i)
                #pragma unroll
                for (int j = 0; j < 4; ++j) {
                    int c_local = j * 16 + l15;
                    int rbase   = wm + i * 16 + lhi * 4;
                    bf16x4 pk;
                    #pragma unroll
                    for (int e = 0; e < 4; ++e) pk[e] = (__bf16)acc[i][j][e];
                    *(bf16x4*)(Ts + c_local * 136 + rbase) = pk;
                }
        }
        __syncthreads();

        f32x4 acc2[4][2] = {};
        #pragma unroll
        for (int k0 = 0; k0 < 64; k0 += 32) {
            bf16x8 pa[4], hb[2];
            #pragma unroll
            for (int i = 0; i < 4; ++i)
                pa[i] = *(bf16x8*)(Pm + (g * 64 + i * 16 + l15) * PMS + k0 + lhi * 8);
            #pragma unroll
            for (int j = 0; j < 2; ++j)
                hb[j] = *(bf16x8*)(Ts + (nb * 32 + j * 16 + l15) * 136
                                      + g * 64 + k0 + lhi * 8);
            #pragma unroll
            for (int i = 0; i < 4; ++i)
                #pragma unroll
                for (int j = 0; j < 2; ++j)
                    acc2[i][j] = __builtin_amdgcn_mfma_f32_16x16x32_bf16(
                        pa[i], hb[j], acc2[i][j], 0, 0, 0);
        }
        #pragma unroll
        for (int j = 0; j < 2; ++j) {
            int col = n0 + h * 64 + nb * 32 + j * 16 + l15;
            float bv = (col < 600) ? bias[col] : 0.f;
            float yp = 0.f;
            #pragma unroll
            for (int i = 0; i < 4; ++i)
                #pragma unroll
                for (int e = 0; e < 4; ++e) {
                    float v = fmaxf(acc2[i][j][e] + bv, 0.f);   // relu
                    yp += s_q[g * 64 + i * 16 + lhi * 4 + e] * v;
                }
            yp += __shfl_xor(yp, 16, 64);
            yp += __shfl_xor(yp, 32, 64);
            if (lhi == 0 && col < FP)
                Y[(size_t)(mt * 2 + g) * FP + col] = __float2bfloat16(yp);
        }
        __syncthreads();
    }
}

// ===========================================================================
// Mega prep kernel: [WT transposes | timestep emb | pair prep | node xform]
// ===========================================================================
struct WtJob  { const float* src; bf16* dst; int Ksrc, Nsrc, Kp, Np, blk0; };
struct PrepArgs {
    WtJob j[9];
    int nwt, te0, pp0, xtr0;
    const int*   ei;
    const float* ts;
    const float* xin; const float* Wtr; const float* btr; const float* mask;
    bf16* TE; bf16* Pmg; float* qv; bf16* X;
};

__global__ __launch_bounds__(256) void k_prep(PrepArgs a)
{
    __shared__ __align__(16) char sm[35840];
    const int bx  = blockIdx.x;
    const int tid = threadIdx.x;

    if (bx < a.nwt) {
        int ji = 0;
        while (ji < 8 && bx >= a.j[ji + 1].blk0) ++ji;
        WtJob jb = a.j[ji];
        int t  = bx - jb.blk0;
        int kt = (jb.Kp + 63) >> 6;
        int ti = t % kt, tj = t / kt;
        int kg0 = ti * 64, ng0 = tj * 64;
        float (*T)[65] = (float(*)[65])sm;
        #pragma unroll 4
        for (int r = 0; r < 16; ++r) {
            int kl = (tid >> 6) + r * 4, nl = tid & 63;
            int kg = kg0 + kl, ng = ng0 + nl;
            T[kl][nl] = (kg < jb.Ksrc && ng < jb.Nsrc)
                        ? jb.src[(size_t)kg * jb.Nsrc + ng] : 0.f;
        }
        __syncthreads();
        #pragma unroll 4
        for (int r = 0; r < 16; ++r) {
            int nl = (tid >> 6) + r * 4, kl = tid & 63;
            int ng = ng0 + nl, kg = kg0 + kl;
            if (ng < jb.Np && kg < jb.Kp)
                jb.dst[(size_t)ng * jb.Kp + kg] = __float2bfloat16(T[kl][nl]);
        }
    } else if (bx < a.pp0) {
        int idx = (bx - a.te0) * 256 + tid;
        int b = idx >> 7, jj = idx & 127;
        float tt = a.ts[b];
        int h = jj & 63;
        float freq = expf(-9.210340371976184f * (float)h / 64.f);  // ln(10000)
        float ang = tt * freq;
        a.TE[idx] = __float2bfloat16((jj < 64) ? cosf(ang) : sinf(ang));
    } else if (bx < a.xtr0) {
        int pr = bx - a.pp0;
        float* Pf   = (float*)sm;
        int*   cnt  = (int*)(sm + 32768);
        float* sQ   = (float*)(sm + 33280);
        float* sI   = (float*)(sm + 33792);
        float* sIvd = (float*)(sm + 34304);

        for (int idx = tid; idx < 8192; idx += 256) Pf[idx] = 0.f;
        if (tid < 128) cnt[tid] = 0;
        __syncthreads();
        for (int e = tid; e < 2 * EPG; e += 256) {
            int g  = (e >= EPG);
            int eg = (2 * pr + g) * EPG + (e - g * EPG);
            int ld = (a.ei[E + eg] & 63) + g * 64;
            atomicAdd(&cnt[ld], 1);
        }
        __syncthreads();
        if (tid < 128) {
            float d = (float)cnt[tid] + 1.0f;
            float iv = 1.f / d;
            sIvd[tid] = iv;
            sI[tid]   = rsqrtf(d);
            sQ[tid]   = iv;
        }
        __syncthreads();
        for (int e = tid; e < 2 * EPG; e += 256) {
            int g   = (e >= EPG);
            int eg  = (2 * pr + g) * EPG + (e - g * EPG);
            int lsl = a.ei[eg] & 63;
            int ldl = a.ei[E + eg] & 63;
            float cf = sI[g * 64 + lsl] * sI[g * 64 + ldl];
            atomicAdd(&Pf[(g * 64 + ldl) * 64 + lsl], cf);
            atomicAdd(&sQ[g * 64 + lsl], cf);
        }
        __syncthreads();
        if (tid < 128) {
            Pf[tid * 64 + (tid & 63)] += sIvd[tid];
            a.qv[pr * 128 + tid] = sQ[tid] * (1.f / 64.f);
        }
        __syncthreads();
        for (int idx = tid; idx < 128 * PMS; idx += 256) {
            int r = idx / PMS, k = idx - r * PMS;
            float v = (k < 64) ? Pf[r * 64 + k] : 0.f;
            a.Pmg[(size_t)pr * (128 * PMS) + idx] = __float2bfloat16(v);
        }
    } else {
        int g = bx - a.xtr0;
        float* Ws = (float*)sm;
        float* xb = (float*)(sm + 23104);
        float* sb = (float*)(sm + 28224);
        float* smk= (float*)(sm + 29440);

        for (int idx = tid; idx < 19 * 304; idx += 256) {
            int k = idx / 304, c = idx - k * 304;
            Ws[idx] = (c < 300) ? a.Wtr[k * 300 + c] : 0.f;
        }
        for (int idx = tid; idx < 64 * 19; idx += 256) {
            int n = idx / 19, k = idx - n * 19;
            xb[n * 20 + k] = a.xin[(size_t)(g * 64 + n) * 19 + k];
        }
        for (int c = tid; c < 304; c += 256)
            sb[c] = (c < 300) ? a.btr[c] : 0.f;
        if (tid < 64) smk[tid] = a.mask[g * 64 + tid];
        __syncthreads();

        int n  = tid >> 2;
        int c0 = tid & 3;
        float m = smk[n];
        for (int c = c0; c < 304; c += 4) {
            float acc = sb[c];
            #pragma unroll
            for (int k = 0; k < 19; ++k)
                acc += xb[n * 20 + k] * Ws[k * 304 + c];
            a.X[(size_t)(g * 64 + n) * FP + c] = __float2bfloat16(acc * m);
        }
        bf16x8 z = {};
        for (int idx = tid; idx < 64 * 38; idx += 256) {
            int nn = idx / 38, jv = idx - nn * 38;
            *(bf16x8*)((__bf16*)a.X + (size_t)(g * 64 + nn) * FP + 304 + jv * 8) = z;
        }
    }
}

// LayerNorm over 300 dims + affine, fp32 out; fused text passthrough copy
__global__ __launch_bounds__(256) void k_ln_copy(const float* __restrict__ G,
                                                 const float* __restrict__ lg,
                                                 const float* __restrict__ lb,
                                                 const float* __restrict__ text,
                                                 float* __restrict__ out)
{
    int r = blockIdx.x;
    int tid = threadIdx.x;
    __shared__ float red[4];
    __shared__ float smu, svar;

    float v0 = (tid < 300) ? G[r * 300 + tid] : 0.f;
    float v1 = (tid + 256 < 300) ? G[r * 300 + tid + 256] : 0.f;
    float s = v0 + v1;
    #pragma unroll
    for (int o = 32; o > 0; o >>= 1) s += __shfl_down(s, o, 64);
    if ((tid & 63) == 0) red[tid >> 6] = s;
    __syncthreads();
    if (tid == 0) smu = (red[0] + red[1] + red[2] + red[3]) * (1.f / 300.f);
    __syncthreads();
    float mu = smu;
    float d0 = (tid < 300) ? v0 - mu : 0.f;
    float d1 = (tid + 256 < 300) ? v1 - mu : 0.f;
    s = d0 * d0 + d1 * d1;
    #pragma unroll
    for (int o = 32; o > 0; o >>= 1) s += __shfl_down(s, o, 64);
    if ((tid & 63) == 0) red[tid >> 6] = s;
    __syncthreads();
    if (tid == 0) svar = (red[0] + red[1] + red[2] + red[3]) * (1.f / 300.f);
    __syncthreads();
    float rstd = rsqrtf(svar + 1e-5f);
    if (tid < 300)
        out[r * 300 + tid] = d0 * rstd * lg[tid] + lb[tid];
    if (tid + 256 < 300)
        out[r * 300 + tid + 256] = d1 * rstd * lg[tid + 256] + lb[tid + 256];
    float* o2 = out + (size_t)B * 300;
    for (int c = tid; c < 300; c += 256)
        o2[(size_t)r * 300 + c] = text[(size_t)r * 300 + c];
}

// ---------------------------------------------------------------------------
extern "C" void kernel_launch(void* const* d_in, const int* in_sizes, int n_in,
                              void* d_out, int out_size, void* d_ws, size_t ws_size,
                              hipStream_t stream)
{
    const float* x_in  = (const float*)d_in[0];
    const int*   ei    = (const int*)d_in[1];
    const float* text  = (const float*)d_in[3];
    const float* tst   = (const float*)d_in[4];
    const float* mask  = (const float*)d_in[5];
    const float* W_tr  = (const float*)d_in[6];
    const float* b_tr  = (const float*)d_in[7];
    const float* W_c1  = (const float*)d_in[8];
    const float* b_c1  = (const float*)d_in[9];
    const float* W_c2  = (const float*)d_in[10];
    const float* b_c2  = (const float*)d_in[11];
    const float* W_c3  = (const float*)d_in[12];
    const float* b_c3  = (const float*)d_in[13];
    const float* W_h1  = (const float*)d_in[14];
    const float* b_h1  = (const float*)d_in[15];
    const float* W_h2  = (const float*)d_in[16];
    const float* b_h2  = (const float*)d_in[17];
    const float* W_h3  = (const float*)d_in[18];
    const float* b_h3  = (const float*)d_in[19];
    const float* ln_g  = (const float*)d_in[20];
    const float* ln_b  = (const float*)d_in[21];
    const float* W_t1  = (const float*)d_in[22];
    const float* b_t1  = (const float*)d_in[23];
    const float* W_t2  = (const float*)d_in[24];
    const float* b_t2  = (const float*)d_in[25];
    const float* W_e   = (const float*)d_in[26];
    const float* b_e   = (const float*)d_in[27];

    // workspace carve (256B aligned)
    char* w = (char*)d_ws;
    size_t off = 0;
    auto carve = [&](size_t bytes) {
        void* p = w + off;
        off += (bytes + 255) & ~(size_t)255;
        return p;
    };
    bf16*  XA     = (bf16*) carve((size_t)BN * FP * 2);      // 79.7 MB
    bf16*  Wb1    = (bf16*) carve((size_t)640 * 320 * 2);
    bf16*  Wb2    = (bf16*) carve((size_t)640 * FP * 2);
    bf16*  Wb3    = (bf16*) carve((size_t)640 * FP * 2);
    bf16*  Wt1t   = (bf16*) carve((size_t)512 * 128 * 2);
    bf16*  Wt2t   = (bf16*) carve((size_t)512 * 512 * 2);
    bf16*  Wet    = (bf16*) carve((size_t)3072 * 512 * 2);
    bf16*  Wh1t   = (bf16*) carve((size_t)640 * FP * 2);
    bf16*  Wh2t   = (bf16*) carve((size_t)640 * FP * 2);
    bf16*  Wh3t   = (bf16*) carve((size_t)384 * FP * 2);
    bf16*  TE     = (bf16*) carve((size_t)B * 128 * 2);
    bf16*  A1b    = (bf16*) carve((size_t)B * 512 * 2);
    bf16*  A2b    = (bf16*) carve((size_t)B * 512 * 2);
    bf16*  EO     = (bf16*) carve((size_t)B * 3000 * 2);
    bf16*  Yv     = (bf16*) carve((size_t)B * FP * 2);
    bf16*  G0     = (bf16*) carve((size_t)B * FP * 2);
    bf16*  G1     = (bf16*) carve((size_t)B * FP * 2);
    bf16*  G2     = (bf16*) carve((size_t)B * FP * 2);
    float* G3     = (float*)carve((size_t)B * 300 * 4);
    bf16*  Pmg    = (bf16*) carve((size_t)512 * 128 * PMS * 2);  // 10.5 MB
    float* qv     = (float*)carve((size_t)BN * 4);
    (void)ws_size; (void)in_sizes; (void)n_in; (void)out_size;

    float* out = (float*)d_out;

    // --- phase A: one mega prep launch ---
    PrepArgs pa;
    struct JD { const float* s; bf16* d; int Ks, Ns, Kp, Np; };
    JD jd[9] = {
        { W_c1, Wb1,  300, 600,  320, 640 },
        { W_c2, Wb2,  600, 600,  FP,  640 },
        { W_c3, Wb3,  600, 600,  FP,  640 },
        { W_t1, Wt1t, 128, 512,  128, 512 },
        { W_t2, Wt2t, 512, 512,  512, 512 },
        { W_e,  Wet,  512, 3000, 512, 3072 },
        { W_h1, Wh1t, 600, 600,  FP,  640 },
        { W_h2, Wh2t, 600, 600,  FP,  640 },
        { W_h3, Wh3t, 600, 300,  FP,  384 },
    };
    int cum = 0;
    for (int i = 0; i < 9; ++i) {
        int kt = (jd[i].Kp + 63) >> 6, nt = (jd[i].Np + 63) >> 6;
        pa.j[i] = { jd[i].s, jd[i].d, jd[i].Ks, jd[i].Ns, jd[i].Kp, jd[i].Np, cum };
        cum += kt * nt;
    }
    pa.nwt  = cum;
    pa.te0  = cum;       cum += (B * 128) / 256;
    pa.pp0  = cum;       cum += B / 2;
    pa.xtr0 = cum;       cum += B;
    pa.ei = ei; pa.ts = tst;
    pa.xin = x_in; pa.Wtr = W_tr; pa.btr = b_tr; pa.mask = mask;
    pa.TE = TE; pa.Pmg = Pmg; pa.qv = qv; pa.X = XA;
    k_prep<<<cum, 256, 0, stream>>>(pa);

    // --- conv1 (+hidden t1: A1b = relu(TE @ Wt1t^T + b_t1), 16x4 tiles) ---
    conv_fused<<<NCONV + 64, 256, 0, stream>>>(
        XA, FP, 320, Wb1, 320, Pmg, b_c1, XA,
        TE, 128, Wt1t, 128, b_t1, A1b, 512, 512, 128, 4);

    // --- conv2+conv3+pool (+hidden t2: A2b = relu(A1b @ Wt2t^T + b_t2)) ---
    conv_fused_q<<<NCONV + 64, 256, 0, stream>>>(
        XA, FP, FP, Wb2, FP, Pmg, b_c2, qv, Yv,
        A1b, 512, Wt2t, 512, b_t2, A2b, 512, 512, 512, 4);

    // --- EO = A2b @ Wet^T + b_e  (384 blocks)  ||  G0 = Yv @ Wb3^T + b_c3 (80) ---
    k_two_gemms<<<464, 256, 0, stream>>>(A2b, Wet, b_e, EO, Yv, Wb3, b_c3, G0);

    // --- h-layers with FiLM (64-row tiles) ---
    gemm64<true, true, bf16><<<dim3(16, 5), 256, 0, stream>>>(
        G0, FP, Wh1t, FP, b_h1, G1, FP, 600, EO + 0, EO + 600, 3000, FP);
    gemm64<true, true, bf16><<<dim3(16, 5), 256, 0, stream>>>(
        G1, FP, Wh2t, FP, b_h2, G2, FP, 600, EO + 1200, EO + 1800, 3000, FP);
    gemm64<false, true, float><<<dim3(16, 3), 256, 0, stream>>>(
        G2, FP, Wh3t, FP, b_h3, G3, 300, 300, EO + 2400, EO + 2700, 3000, FP);

    // --- layer norm + text passthrough ---
    k_ln_copy<<<B, 256, 0, stream>>>(G3, ln_g, ln_b, text, out);
}

// Round 10
// 366.997 us; speedup vs baseline: 9.4794x; 1.1118x over previous
//
#include <hip/hip_runtime.h>
#include <hip/hip_bf16.h>
#include <cstdint>
#include <cstddef>

// Problem constants
static constexpr int B   = 1024;
static constexpr int N   = 64;
static constexpr int BN  = B * N;      // 65536 nodes
static constexpr int EPG = 192;
static constexpr int E   = B * EPG;    // 196608 edges
static constexpr int FP  = 608;        // padded feature dim (mult of 32)
static constexpr int KP1 = 320;        // conv1 K (PX0 cols, padded)
static constexpr int PMS = 80;         // Pm row stride (bf16)
static constexpr int NCONV = 2560;     // conv blocks per conv dispatch

typedef __hip_bfloat16 bf16;
typedef __bf16 bf16x8 __attribute__((ext_vector_type(8)));
typedef __bf16 bf16x4 __attribute__((ext_vector_type(4)));
typedef float  f32x4  __attribute__((ext_vector_type(4)));

__device__ __forceinline__ void storeC(float* p, float v) { *p = v; }
__device__ __forceinline__ void storeC(bf16* p, float v) { *p = __float2bfloat16(v); }

// async global->LDS, 16B per lane; LDS dest is wave-uniform base + lane*16
__device__ __forceinline__ void llds16(const void* g, void* l) {
    __builtin_amdgcn_global_load_lds(
        (const __attribute__((address_space(1))) unsigned int*)g,
        (__attribute__((address_space(3))) unsigned int*)l,
        16, 0, 0);
}

// ===========================================================================
// 64x128 MFMA GEMM tile body: C[64 x 128 at (m0,n0)] = A @ Bt^T (+bias)(relu)
// (film).  4 waves each 64x32.  As: 4KB, Bs: 8KB.
// ===========================================================================
template<bool RELU, bool FILM, typename CT>
__device__ __forceinline__ void g64_tile(
    const bf16* __restrict__ A, int lda,
    const bf16* __restrict__ Bt, int ldb,
    const float* __restrict__ bias,
    CT* __restrict__ C, int ldc, int Ncap,
    const bf16* __restrict__ fS, const bf16* __restrict__ fT, int fstride,
    int K, int m0, int n0, __bf16* As, __bf16* Bs, int tid)
{
    const int lane = tid & 63;
    const int w    = tid >> 6;
    const int wn   = w * 32;
    const int l15  = lane & 15;
    const int lhi  = lane >> 4;

    f32x4 acc[4][2] = {};

    for (int k0 = 0; k0 < K; k0 += 32) {
        {   // A tile: 256 chunks of 16B
            int row = tid >> 2, kc = tid & 3;
            char* la = (char*)As + (size_t)(w * 64) * 16;
            llds16(A + (size_t)(m0 + row) * lda + k0 + kc * 8, la);
        }
        #pragma unroll
        for (int t = 0; t < 2; ++t) {   // B tile: 512 chunks
            int ci  = t * 256 + tid;
            int row = ci >> 2, kc = ci & 3;
            char* lb = (char*)Bs + (size_t)(t * 256 + w * 64) * 16;
            llds16(Bt + (size_t)(n0 + row) * ldb + k0 + kc * 8, lb);
        }
        asm volatile("s_waitcnt vmcnt(0)" ::: "memory");
        __syncthreads();

        bf16x8 af[4], bg[2];
        #pragma unroll
        for (int i = 0; i < 4; ++i)
            af[i] = *(bf16x8*)(As + (i * 16 + l15) * 32 + lhi * 8);
        #pragma unroll
        for (int j = 0; j < 2; ++j)
            bg[j] = *(bf16x8*)(Bs + (wn + j * 16 + l15) * 32 + lhi * 8);
        #pragma unroll
        for (int i = 0; i < 4; ++i)
            #pragma unroll
            for (int j = 0; j < 2; ++j)
                acc[i][j] = __builtin_amdgcn_mfma_f32_16x16x32_bf16(
                    af[i], bg[j], acc[i][j], 0, 0, 0);
        __syncthreads();
    }

    #pragma unroll
    for (int i = 0; i < 4; ++i) {
        #pragma unroll
        for (int j = 0; j < 2; ++j) {
            int col = n0 + wn + j * 16 + l15;
            if (col < Ncap) {
                float bv = bias ? bias[col] : 0.f;
                #pragma unroll
                for (int e = 0; e < 4; ++e) {
                    int row = m0 + i * 16 + lhi * 4 + e;
                    float v = acc[i][j][e] + bv;
                    if (RELU) v = fmaxf(v, 0.f);
                    if (FILM) {
                        float sv = __bfloat162float(fS[(size_t)row * fstride + col]);
                        float tv = __bfloat162float(fT[(size_t)row * fstride + col]);
                        v = v * (1.f + sv) + tv;
                    }
                    storeC(&C[(size_t)row * ldc + col], v);
                }
            }
        }
    }
}

// noinline guest wrapper: keeps guest register usage from inflating the host
// conv kernel's VGPR allocation (R9 post-mortem: inline guest cost 80->96 VGPR)
__device__ __attribute__((noinline)) void guest_g64(
    const bf16* gA, int glda, const bf16* gBt, int gldb,
    const float* gbias, bf16* gC, int gldc, int gNcap, int gK, int gnt,
    int t, char* lds, int tid)
{
    int mt2 = t / gnt, nt2 = t % gnt;
    g64_tile<true, false, bf16>(gA, glda, gBt, gldb, gbias, gC, gldc, gNcap,
                                nullptr, nullptr, 0, gK, mt2 * 64, nt2 * 128,
                                (__bf16*)lds, (__bf16*)(lds + 4096), tid);
}

// standalone 64-row-tile GEMM (h-layers)
template<bool RELU, bool FILM, typename CT>
__global__ __launch_bounds__(256) void gemm64(
    const bf16* __restrict__ A, int lda,
    const bf16* __restrict__ Bt, int ldb,
    const float* __restrict__ bias,
    CT* __restrict__ C, int ldc, int Ncap,
    const bf16* __restrict__ fS, const bf16* __restrict__ fT, int fstride,
    int K)
{
    __shared__ __align__(16) __bf16 As[64 * 32];
    __shared__ __align__(16) __bf16 Bs[128 * 32];
    g64_tile<RELU, FILM, CT>(A, lda, Bt, ldb, bias, C, ldc, Ncap,
                             fS, fT, fstride, K,
                             blockIdx.x * 64, blockIdx.y * 128, As, Bs,
                             threadIdx.x);
}

// two independent small GEMMs in one dispatch: EO (384 blocks) + W3 (80)
__global__ __launch_bounds__(256) void k_two_gemms(
    const bf16* __restrict__ A2b, const bf16* __restrict__ Wet,
    const float* __restrict__ b_e, bf16* __restrict__ EO,
    const bf16* __restrict__ Yv, const bf16* __restrict__ Wb3,
    const float* __restrict__ b_c3, bf16* __restrict__ G0)
{
    __shared__ __align__(16) __bf16 As[64 * 32];
    __shared__ __align__(16) __bf16 Bs[128 * 32];
    int bid = blockIdx.x;
    if (bid < 384) {
        int mt = bid / 24, nt = bid % 24;
        g64_tile<false, false, bf16>(A2b, 512, Wet, 512, b_e, EO, 3000, 3000,
                                     nullptr, nullptr, 0, 512,
                                     mt * 64, nt * 128, As, Bs, threadIdx.x);
    } else {
        int t = bid - 384;
        int mt = t / 5, nt = t % 5;
        g64_tile<false, false, bf16>(Yv, FP, Wb3, FP, b_c3, G0, FP, 600,
                                     nullptr, nullptr, 0, FP,
                                     mt * 64, nt * 128, As, Bs, threadIdx.x);
    }
}

// ===========================================================================
// conv1 as a PLAIN GEMM (aggregation pre-commuted into PX0):
// X1 = relu(PX0 @ Wb1^T + b_c1).  128x128 tiles, XCD-swizzled. + hidden t1.
// ===========================================================================
__global__ __launch_bounds__(256) void conv1_gemm(
    const bf16* __restrict__ A,        // PX0, lda = KP1
    const bf16* __restrict__ Bt,       // Wb1, ldb = KP1
    const float* __restrict__ bias,
    bf16* __restrict__ X1,
    const bf16* __restrict__ gA, int glda,
    const bf16* __restrict__ gBt, int gldb,
    const float* __restrict__ gbias,
    bf16* __restrict__ gC, int gldc, int gNcap, int gK, int gnt)
{
    __shared__ __align__(16) char regA[17408];
    const int tid = threadIdx.x;
    const int bid = blockIdx.x;

    if (bid >= NCONV) {
        guest_g64(gA, glda, gBt, gldb, gbias, gC, gldc, gNcap, gK, gnt,
                  bid - NCONV, regA, tid);
        return;
    }

    __bf16* As = (__bf16*)regA;
    __bf16* Bs = (__bf16*)(regA + 8192);

    const int lane = tid & 63;
    const int w    = tid >> 6;
    const int wm   = (w & 1) * 64;
    const int wn   = (w >> 1) * 64;
    const int l15  = lane & 15;
    const int lhi  = lane >> 4;

    const int lid = bid >> 3;
    const int mt  = (bid & 7) * 64 + lid / 5;
    const int nt  = lid % 5;
    const int m0  = mt * 128;
    const int n0  = nt * 128;

    f32x4 acc[4][4] = {};
    for (int k0 = 0; k0 < KP1; k0 += 32) {
        #pragma unroll
        for (int t = 0; t < 2; ++t) {
            int ci  = t * 256 + w * 64 + lane;
            int row = ci >> 2, kc = ci & 3;
            char* la = (char*)As + (size_t)(t * 256 + w * 64) * 16;
            char* lb = (char*)Bs + (size_t)(t * 256 + w * 64) * 16;
            llds16(A  + (size_t)(m0 + row) * KP1 + k0 + kc * 8, la);
            llds16(Bt + (size_t)(n0 + row) * KP1 + k0 + kc * 8, lb);
        }
        asm volatile("s_waitcnt vmcnt(0)" ::: "memory");
        __syncthreads();

        bf16x8 af[4], bg[4];
        #pragma unroll
        for (int i = 0; i < 4; ++i)
            af[i] = *(bf16x8*)(As + (wm + i * 16 + l15) * 32 + lhi * 8);
        #pragma unroll
        for (int j = 0; j < 4; ++j)
            bg[j] = *(bf16x8*)(Bs + (wn + j * 16 + l15) * 32 + lhi * 8);
        #pragma unroll
        for (int i = 0; i < 4; ++i)
            #pragma unroll
            for (int j = 0; j < 4; ++j)
                acc[i][j] = __builtin_amdgcn_mfma_f32_16x16x32_bf16(
                    af[i], bg[j], acc[i][j], 0, 0, 0);
        __syncthreads();
    }

    #pragma unroll
    for (int i = 0; i < 4; ++i)
        #pragma unroll
        for (int j = 0; j < 4; ++j) {
            int col = n0 + wn + j * 16 + l15;
            if (col < FP) {
                float bv = (col < 600) ? bias[col] : 0.f;
                #pragma unroll
                for (int e = 0; e < 4; ++e) {
                    int row = m0 + wm + i * 16 + lhi * 4 + e;
                    float v = fmaxf(acc[i][j][e] + bv, 0.f);
                    X1[(size_t)row * FP + col] = __float2bfloat16(v);
                }
            }
        }
}

// ===========================================================================
// conv2+conv3+pool fused (+ hidden t2 via noinline guest).  Writes only Y.
// ===========================================================================
__global__ __launch_bounds__(256) void conv_fused_q(
    const bf16* __restrict__ A, int lda, int K,
    const bf16* __restrict__ Bt, int ldb,
    const bf16* __restrict__ Pmg,
    const float* __restrict__ bias,
    const float* __restrict__ qv,
    bf16* __restrict__ Y,
    const bf16* __restrict__ gA, int glda,
    const bf16* __restrict__ gBt, int gldb,
    const float* __restrict__ gbias,
    bf16* __restrict__ gC, int gldc, int gNcap, int gK, int gnt)
{
    __shared__ __align__(16) char regA[17408];
    __shared__ __align__(16) __bf16 Pm[128 * PMS];
    __shared__ float s_q[128];

    const int tid = threadIdx.x;
    const int bid = blockIdx.x;

    if (bid >= NCONV) {
        guest_g64(gA, glda, gBt, gldb, gbias, gC, gldc, gNcap, gK, gnt,
                  bid - NCONV, regA, tid);
        return;
    }

    __bf16* As = (__bf16*)regA;
    __bf16* Bs = (__bf16*)(regA + 8192);
    __bf16* Ts = (__bf16*)regA;

    const int lane = tid & 63;
    const int w    = tid >> 6;
    const int wm   = (w & 1) * 64;
    const int wn   = (w >> 1) * 64;
    const int l15  = lane & 15;
    const int lhi  = lane >> 4;

    const int lid = bid >> 3;
    const int mt  = (bid & 7) * 64 + lid / 5;
    const int nt  = lid % 5;
    const int m0  = mt * 128;
    const int n0  = nt * 128;

    #pragma unroll
    for (int i = 0; i < 5; ++i) {
        int cbase = w * 320 + i * 64;
        llds16(Pmg + (size_t)mt * (128 * PMS) + (size_t)(cbase + lane) * 8,
               (char*)Pm + (size_t)cbase * 16);
    }
    if (tid < 128) s_q[tid] = qv[mt * 128 + tid];

    f32x4 acc[4][4] = {};
    for (int k0 = 0; k0 < K; k0 += 32) {
        #pragma unroll
        for (int t = 0; t < 2; ++t) {
            int ci  = t * 256 + w * 64 + lane;
            int row = ci >> 2, kc = ci & 3;
            char* la = (char*)As + (size_t)(t * 256 + w * 64) * 16;
            char* lb = (char*)Bs + (size_t)(t * 256 + w * 64) * 16;
            llds16(A  + (size_t)(m0 + row) * lda + k0 + kc * 8, la);
            llds16(Bt + (size_t)(n0 + row) * ldb + k0 + kc * 8, lb);
        }
        asm volatile("s_waitcnt vmcnt(0)" ::: "memory");
        __syncthreads();

        bf16x8 af[4], bg[4];
        #pragma unroll
        for (int i = 0; i < 4; ++i)
            af[i] = *(bf16x8*)(As + (wm + i * 16 + l15) * 32 + lhi * 8);
        #pragma unroll
        for (int j = 0; j < 4; ++j)
            bg[j] = *(bf16x8*)(Bs + (wn + j * 16 + l15) * 32 + lhi * 8);
        #pragma unroll
        for (int i = 0; i < 4; ++i)
            #pragma unroll
            for (int j = 0; j < 4; ++j)
                acc[i][j] = __builtin_amdgcn_mfma_f32_16x16x32_bf16(
                    af[i], bg[j], acc[i][j], 0, 0, 0);
        __syncthreads();
    }

    const int g  = w & 1;
    const int nb = w >> 1;
    #pragma unroll
    for (int h = 0; h < 2; ++h) {
        if (wn == h * 64) {
            #pragma unroll
            for (int i = 0; i < 4; ++i)
                #pragma unroll
                for (int j = 0; j < 4; ++j) {
                    int c_local = j * 16 + l15;
                    int rbase   = wm + i * 16 + lhi * 4;
                    bf16x4 pk;
                    #pragma unroll
                    for (int e = 0; e < 4; ++e) pk[e] = (__bf16)acc[i][j][e];
                    *(bf16x4*)(Ts + c_local * 136 + rbase) = pk;
                }
        }
        __syncthreads();

        f32x4 acc2[4][2] = {};
        #pragma unroll
        for (int k0 = 0; k0 < 64; k0 += 32) {
            bf16x8 pa[4], hb[2];
            #pragma unroll
            for (int i = 0; i < 4; ++i)
                pa[i] = *(bf16x8*)(Pm + (g * 64 + i * 16 + l15) * PMS + k0 + lhi * 8);
            #pragma unroll
            for (int j = 0; j < 2; ++j)
                hb[j] = *(bf16x8*)(Ts + (nb * 32 + j * 16 + l15) * 136
                                      + g * 64 + k0 + lhi * 8);
            #pragma unroll
            for (int i = 0; i < 4; ++i)
                #pragma unroll
                for (int j = 0; j < 2; ++j)
                    acc2[i][j] = __builtin_amdgcn_mfma_f32_16x16x32_bf16(
                        pa[i], hb[j], acc2[i][j], 0, 0, 0);
        }
        #pragma unroll
        for (int j = 0; j < 2; ++j) {
            int col = n0 + h * 64 + nb * 32 + j * 16 + l15;
            float bv = (col < 600) ? bias[col] : 0.f;
            float yp = 0.f;
            #pragma unroll
            for (int i = 0; i < 4; ++i)
                #pragma unroll
                for (int e = 0; e < 4; ++e) {
                    float v = fmaxf(acc2[i][j][e] + bv, 0.f);   // relu
                    yp += s_q[g * 64 + i * 16 + lhi * 4 + e] * v;
                }
            yp += __shfl_xor(yp, 16, 64);
            yp += __shfl_xor(yp, 32, 64);
            if (lhi == 0 && col < FP)
                Y[(size_t)(mt * 2 + g) * FP + col] = __float2bfloat16(yp);
        }
        __syncthreads();
    }
}

// ===========================================================================
// Mega prep: [WT transposes | timestep emb | pair prep (Pmg,qv) | PX0 branch]
// PX0 branch (per graph): PX0 = P @ ((x@Wtr + b)*mask), via the commute
// PX0 = xa @ Wtr + ba*b^T with xa = P@(m*x), ba = P@m.  fp32 throughout.
// ===========================================================================
struct WtJob  { const float* src; bf16* dst; int Ksrc, Nsrc, Kp, Np, blk0; };
struct PrepArgs {
    WtJob j[9];
    int nwt, te0, pp0, xtr0;
    const int*   ei;
    const float* ts;
    const float* xin; const float* Wtr; const float* btr; const float* mask;
    bf16* TE; bf16* Pmg; float* qv; bf16* PX0;
};

__global__ __launch_bounds__(256) void k_prep(PrepArgs a)
{
    __shared__ __align__(16) char sm[35840];
    const int bx  = blockIdx.x;
    const int tid = threadIdx.x;

    if (bx < a.nwt) {
        int ji = 0;
        while (ji < 8 && bx >= a.j[ji + 1].blk0) ++ji;
        WtJob jb = a.j[ji];
        int t  = bx - jb.blk0;
        int kt = (jb.Kp + 63) >> 6;
        int ti = t % kt, tj = t / kt;
        int kg0 = ti * 64, ng0 = tj * 64;
        float (*T)[65] = (float(*)[65])sm;
        #pragma unroll 4
        for (int r = 0; r < 16; ++r) {
            int kl = (tid >> 6) + r * 4, nl = tid & 63;
            int kg = kg0 + kl, ng = ng0 + nl;
            T[kl][nl] = (kg < jb.Ksrc && ng < jb.Nsrc)
                        ? jb.src[(size_t)kg * jb.Nsrc + ng] : 0.f;
        }
        __syncthreads();
        #pragma unroll 4
        for (int r = 0; r < 16; ++r) {
            int nl = (tid >> 6) + r * 4, kl = tid & 63;
            int ng = ng0 + nl, kg = kg0 + kl;
            if (ng < jb.Np && kg < jb.Kp)
                jb.dst[(size_t)ng * jb.Kp + kg] = __float2bfloat16(T[kl][nl]);
        }
    } else if (bx < a.pp0) {
        int idx = (bx - a.te0) * 256 + tid;
        int b = idx >> 7, jj = idx & 127;
        float tt = a.ts[b];
        int h = jj & 63;
        float freq = expf(-9.210340371976184f * (float)h / 64.f);  // ln(10000)
        float ang = tt * freq;
        a.TE[idx] = __float2bfloat16((jj < 64) ? cosf(ang) : sinf(ang));
    } else if (bx < a.xtr0) {
        // ---------- pair prep: P matrix (bf16, PMS stride) + q vector ----------
        int pr = bx - a.pp0;
        float* Pf   = (float*)sm;
        int*   cnt  = (int*)(sm + 32768);
        float* sQ   = (float*)(sm + 33280);
        float* sI   = (float*)(sm + 33792);
        float* sIvd = (float*)(sm + 34304);

        for (int idx = tid; idx < 8192; idx += 256) Pf[idx] = 0.f;
        if (tid < 128) cnt[tid] = 0;
        __syncthreads();
        for (int e = tid; e < 2 * EPG; e += 256) {
            int g  = (e >= EPG);
            int eg = (2 * pr + g) * EPG + (e - g * EPG);
            int ld = (a.ei[E + eg] & 63) + g * 64;
            atomicAdd(&cnt[ld], 1);
        }
        __syncthreads();
        if (tid < 128) {
            float d = (float)cnt[tid] + 1.0f;
            float iv = 1.f / d;
            sIvd[tid] = iv;
            sI[tid]   = rsqrtf(d);
            sQ[tid]   = iv;
        }
        __syncthreads();
        for (int e = tid; e < 2 * EPG; e += 256) {
            int g   = (e >= EPG);
            int eg  = (2 * pr + g) * EPG + (e - g * EPG);
            int lsl = a.ei[eg] & 63;
            int ldl = a.ei[E + eg] & 63;
            float cf = sI[g * 64 + lsl] * sI[g * 64 + ldl];
            atomicAdd(&Pf[(g * 64 + ldl) * 64 + lsl], cf);
            atomicAdd(&sQ[g * 64 + lsl], cf);
        }
        __syncthreads();
        if (tid < 128) {
            Pf[tid * 64 + (tid & 63)] += sIvd[tid];
            a.qv[pr * 128 + tid] = sQ[tid] * (1.f / 64.f);
        }
        __syncthreads();
        for (int idx = tid; idx < 128 * PMS; idx += 256) {
            int r = idx / PMS, k = idx - r * PMS;
            float v = (k < 64) ? Pf[r * 64 + k] : 0.f;
            a.Pmg[(size_t)pr * (128 * PMS) + idx] = __float2bfloat16(v);
        }
    } else {
        // ---------- PX0 branch (per graph) ----------
        int g = bx - a.xtr0;
        float* Pf  = (float*)sm;                 // 64*64 fp32 [0,16384); Ws overlays later
        float* Ws  = (float*)sm;                 // 19*304 fp32 [0,23104)
        float* xm  = (float*)(sm + 23104);       // 64*20 (col 19 = mask)
        float* xa  = (float*)(sm + 28224);       // 64*20 (col 19 = ba)
        float* isqv= (float*)(sm + 33344);       // 64
        float* ivdv= (float*)(sm + 33600);       // 64
        int*   cnt = (int*)  (sm + 33856);       // 64
        float* sb  = (float*)(sm + 34112);       // 304 fp32 -> ends 35328

        for (int idx = tid; idx < 4096; idx += 256) Pf[idx] = 0.f;
        if (tid < 64) cnt[tid] = 0;
        __syncthreads();
        for (int e = tid; e < EPG; e += 256)
            atomicAdd(&cnt[a.ei[E + g * EPG + e] & 63], 1);
        __syncthreads();
        if (tid < 64) {
            float d = (float)cnt[tid] + 1.0f;
            ivdv[tid] = 1.f / d;
            isqv[tid] = rsqrtf(d);
        }
        __syncthreads();
        for (int e = tid; e < EPG; e += 256) {
            int ls = a.ei[g * EPG + e] & 63;
            int ld = a.ei[E + g * EPG + e] & 63;
            atomicAdd(&Pf[ld * 64 + ls], isqv[ls] * isqv[ld]);
        }
        // xm load (independent of P)
        for (int idx = tid; idx < 64 * 20; idx += 256) {
            int n = idx / 20, j = idx - n * 20;
            float mv = a.mask[g * 64 + n];
            xm[idx] = (j < 19) ? mv * a.xin[(size_t)(g * 64 + n) * 19 + j] : mv;
        }
        __syncthreads();
        if (tid < 64) Pf[tid * 64 + tid] += ivdv[tid];
        __syncthreads();
        // xa[r][j] = sum_s Pf[r][s] * xm[s][j]  (j=19 gives ba)
        for (int idx = tid; idx < 64 * 20; idx += 256) {
            int r = idx / 20, j = idx - r * 20;
            float s = 0.f;
            #pragma unroll 8
            for (int s2 = 0; s2 < 64; ++s2)
                s += Pf[r * 64 + s2] * xm[s2 * 20 + j];
            xa[idx] = s;
        }
        __syncthreads();
        // Ws/sb load (Pf dead)
        for (int idx = tid; idx < 19 * 304; idx += 256) {
            int k = idx / 304, c = idx - k * 304;
            Ws[idx] = (c < 300) ? a.Wtr[k * 300 + c] : 0.f;
        }
        for (int c = tid; c < 304; c += 256)
            sb[c] = (c < 300) ? a.btr[c] : 0.f;
        __syncthreads();
        // PX0[r][c] = sum_j xa[r][j]*Ws[j][c] + ba[r]*sb[c]
        int n  = tid >> 2;
        int c0 = tid & 3;
        float ba = xa[n * 20 + 19];
        for (int c = c0; c < 304; c += 4) {
            float acc = ba * sb[c];
            #pragma unroll
            for (int k = 0; k < 19; ++k)
                acc += xa[n * 20 + k] * Ws[k * 304 + c];
            a.PX0[(size_t)(g * 64 + n) * KP1 + c] = __float2bfloat16(acc);
        }
        // zero cols 304..319
        bf16x8 z = {};
        for (int idx = tid; idx < 64 * 2; idx += 256) {
            int nn = idx >> 1, jv = idx & 1;
            *(bf16x8*)((__bf16*)a.PX0 + (size_t)(g * 64 + nn) * KP1 + 304 + jv * 8) = z;
        }
    }
}

// LayerNorm over 300 dims + affine, fp32 out; fused text passthrough copy
__global__ __launch_bounds__(256) void k_ln_copy(const float* __restrict__ G,
                                                 const float* __restrict__ lg,
                                                 const float* __restrict__ lb,
                                                 const float* __restrict__ text,
                                                 float* __restrict__ out)
{
    int r = blockIdx.x;
    int tid = threadIdx.x;
    __shared__ float red[4];
    __shared__ float smu, svar;

    float v0 = (tid < 300) ? G[r * 300 + tid] : 0.f;
    float v1 = (tid + 256 < 300) ? G[r * 300 + tid + 256] : 0.f;
    float s = v0 + v1;
    #pragma unroll
    for (int o = 32; o > 0; o >>= 1) s += __shfl_down(s, o, 64);
    if ((tid & 63) == 0) red[tid >> 6] = s;
    __syncthreads();
    if (tid == 0) smu = (red[0] + red[1] + red[2] + red[3]) * (1.f / 300.f);
    __syncthreads();
    float mu = smu;
    float d0 = (tid < 300) ? v0 - mu : 0.f;
    float d1 = (tid + 256 < 300) ? v1 - mu : 0.f;
    s = d0 * d0 + d1 * d1;
    #pragma unroll
    for (int o = 32; o > 0; o >>= 1) s += __shfl_down(s, o, 64);
    if ((tid & 63) == 0) red[tid >> 6] = s;
    __syncthreads();
    if (tid == 0) svar = (red[0] + red[1] + red[2] + red[3]) * (1.f / 300.f);
    __syncthreads();
    float rstd = rsqrtf(svar + 1e-5f);
    if (tid < 300)
        out[r * 300 + tid] = d0 * rstd * lg[tid] + lb[tid];
    if (tid + 256 < 300)
        out[r * 300 + tid + 256] = d1 * rstd * lg[tid + 256] + lb[tid + 256];
    float* o2 = out + (size_t)B * 300;
    for (int c = tid; c < 300; c += 256)
        o2[(size_t)r * 300 + c] = text[(size_t)r * 300 + c];
}

// ---------------------------------------------------------------------------
extern "C" void kernel_launch(void* const* d_in, const int* in_sizes, int n_in,
                              void* d_out, int out_size, void* d_ws, size_t ws_size,
                              hipStream_t stream)
{
    const float* x_in  = (const float*)d_in[0];
    const int*   ei    = (const int*)d_in[1];
    const float* text  = (const float*)d_in[3];
    const float* tst   = (const float*)d_in[4];
    const float* mask  = (const float*)d_in[5];
    const float* W_tr  = (const float*)d_in[6];
    const float* b_tr  = (const float*)d_in[7];
    const float* W_c1  = (const float*)d_in[8];
    const float* b_c1  = (const float*)d_in[9];
    const float* W_c2  = (const float*)d_in[10];
    const float* b_c2  = (const float*)d_in[11];
    const float* W_c3  = (const float*)d_in[12];
    const float* b_c3  = (const float*)d_in[13];
    const float* W_h1  = (const float*)d_in[14];
    const float* b_h1  = (const float*)d_in[15];
    const float* W_h2  = (const float*)d_in[16];
    const float* b_h2  = (const float*)d_in[17];
    const float* W_h3  = (const float*)d_in[18];
    const float* b_h3  = (const float*)d_in[19];
    const float* ln_g  = (const float*)d_in[20];
    const float* ln_b  = (const float*)d_in[21];
    const float* W_t1  = (const float*)d_in[22];
    const float* b_t1  = (const float*)d_in[23];
    const float* W_t2  = (const float*)d_in[24];
    const float* b_t2  = (const float*)d_in[25];
    const float* W_e   = (const float*)d_in[26];
    const float* b_e   = (const float*)d_in[27];

    // workspace carve (256B aligned) — ~155 MB (race-free split PX0/X1)
    char* w = (char*)d_ws;
    size_t off = 0;
    auto carve = [&](size_t bytes) {
        void* p = w + off;
        off += (bytes + 255) & ~(size_t)255;
        return p;
    };
    bf16*  PX0    = (bf16*) carve((size_t)BN * KP1 * 2);     // 42 MB
    bf16*  X1     = (bf16*) carve((size_t)BN * FP * 2);      // 79.7 MB
    bf16*  Wb1    = (bf16*) carve((size_t)640 * KP1 * 2);
    bf16*  Wb2    = (bf16*) carve((size_t)640 * FP * 2);
    bf16*  Wb3    = (bf16*) carve((size_t)640 * FP * 2);
    bf16*  Wt1t   = (bf16*) carve((size_t)512 * 128 * 2);
    bf16*  Wt2t   = (bf16*) carve((size_t)512 * 512 * 2);
    bf16*  Wet    = (bf16*) carve((size_t)3072 * 512 * 2);
    bf16*  Wh1t   = (bf16*) carve((size_t)640 * FP * 2);
    bf16*  Wh2t   = (bf16*) carve((size_t)640 * FP * 2);
    bf16*  Wh3t   = (bf16*) carve((size_t)384 * FP * 2);
    bf16*  TE     = (bf16*) carve((size_t)B * 128 * 2);
    bf16*  A1b    = (bf16*) carve((size_t)B * 512 * 2);
    bf16*  A2b    = (bf16*) carve((size_t)B * 512 * 2);
    bf16*  EO     = (bf16*) carve((size_t)B * 3000 * 2);
    bf16*  Yv     = (bf16*) carve((size_t)B * FP * 2);
    bf16*  G0     = (bf16*) carve((size_t)B * FP * 2);
    bf16*  G1     = (bf16*) carve((size_t)B * FP * 2);
    bf16*  G2     = (bf16*) carve((size_t)B * FP * 2);
    float* G3     = (float*)carve((size_t)B * 300 * 4);
    bf16*  Pmg    = (bf16*) carve((size_t)512 * 128 * PMS * 2);  // 10.5 MB
    float* qv     = (float*)carve((size_t)BN * 4);
    (void)ws_size; (void)in_sizes; (void)n_in; (void)out_size;

    float* out = (float*)d_out;

    // --- phase A: one mega prep launch ---
    PrepArgs pa;
    struct JD { const float* s; bf16* d; int Ks, Ns, Kp, Np; };
    JD jd[9] = {
        { W_c1, Wb1,  300, 600,  KP1, 640 },
        { W_c2, Wb2,  600, 600,  FP,  640 },
        { W_c3, Wb3,  600, 600,  FP,  640 },
        { W_t1, Wt1t, 128, 512,  128, 512 },
        { W_t2, Wt2t, 512, 512,  512, 512 },
        { W_e,  Wet,  512, 3000, 512, 3072 },
        { W_h1, Wh1t, 600, 600,  FP,  640 },
        { W_h2, Wh2t, 600, 600,  FP,  640 },
        { W_h3, Wh3t, 600, 300,  FP,  384 },
    };
    int cum = 0;
    for (int i = 0; i < 9; ++i) {
        int kt = (jd[i].Kp + 63) >> 6, nt = (jd[i].Np + 63) >> 6;
        pa.j[i] = { jd[i].s, jd[i].d, jd[i].Ks, jd[i].Ns, jd[i].Kp, jd[i].Np, cum };
        cum += kt * nt;
    }
    pa.nwt  = cum;
    pa.te0  = cum;       cum += (B * 128) / 256;
    pa.pp0  = cum;       cum += B / 2;
    pa.xtr0 = cum;       cum += B;
    pa.ei = ei; pa.ts = tst;
    pa.xin = x_in; pa.Wtr = W_tr; pa.btr = b_tr; pa.mask = mask;
    pa.TE = TE; pa.Pmg = Pmg; pa.qv = qv; pa.PX0 = PX0;
    k_prep<<<cum, 256, 0, stream>>>(pa);

    // --- conv1 as plain GEMM (+hidden t1: A1b = relu(TE @ Wt1t^T + b_t1)) ---
    conv1_gemm<<<NCONV + 64, 256, 0, stream>>>(
        PX0, Wb1, b_c1, X1,
        TE, 128, Wt1t, 128, b_t1, A1b, 512, 512, 128, 4);

    // --- conv2+conv3+pool (+hidden t2: A2b = relu(A1b @ Wt2t^T + b_t2)) ---
    conv_fused_q<<<NCONV + 64, 256, 0, stream>>>(
        X1, FP, FP, Wb2, FP, Pmg, b_c2, qv, Yv,
        A1b, 512, Wt2t, 512, b_t2, A2b, 512, 512, 512, 4);

    // --- EO = A2b @ Wet^T + b_e (384 blocks) || G0 = Yv @ Wb3^T + b_c3 (80) ---
    k_two_gemms<<<464, 256, 0, stream>>>(A2b, Wet, b_e, EO, Yv, Wb3, b_c3, G0);

    // --- h-layers with FiLM (64-row tiles) ---
    gemm64<true, true, bf16><<<dim3(16, 5), 256, 0, stream>>>(
        G0, FP, Wh1t, FP, b_h1, G1, FP, 600, EO + 0, EO + 600, 3000, FP);
    gemm64<true, true, bf16><<<dim3(16, 5), 256, 0, stream>>>(
        G1, FP, Wh2t, FP, b_h2, G2, FP, 600, EO + 1200, EO + 1800, 3000, FP);
    gemm64<false, true, float><<<dim3(16, 3), 256, 0, stream>>>(
        G2, FP, Wh3t, FP, b_h3, G3, 300, 300, EO + 2400, EO + 2700, 3000, FP);

    // --- layer norm + text passthrough ---
    k_ln_copy<<<B, 256, 0, stream>>>(G3, ln_g, ln_b, text, out);
}